// Round 14
// baseline (243.110 us; speedup 1.0000x reference)
//
#include <hip/hip_runtime.h>
#include <hip/hip_bf16.h>

#define HH  56
#define WWC 56
#define HWP 3136   // 56*56 = 49*64
#define CC  256
#define NSPLIT 4

typedef unsigned short u16;
typedef __attribute__((ext_vector_type(8))) u16 u16x8;
typedef __attribute__((ext_vector_type(4))) u16 u16x4;
typedef __attribute__((ext_vector_type(8))) short s16x8;   // bf16x8 MFMA frag
typedef __attribute__((ext_vector_type(4))) float f32x4;

__device__ __forceinline__ u16 f2b(float f) {
  unsigned int x = __float_as_uint(f);
  return (u16)((x + 0x7fffu + ((x >> 16) & 1u)) >> 16);
}
__device__ __forceinline__ float b2f(u16 u) {
  return __uint_as_float(((unsigned int)u) << 16);
}
__device__ __forceinline__ f32x4 mfma16(s16x8 a, s16x8 b, f32x4 c) {
  return __builtin_amdgcn_mfma_f32_16x16x32_bf16(a, b, c, 0, 0, 0);
}

// ---------- dtype-flexible load/store (flag decided on device) ----------
__device__ __forceinline__ float ldsel(const void* p, int i, bool bf) {
  if (bf) return __bfloat162float(((const __hip_bfloat16*)p)[i]);
  return ((const float*)p)[i];
}
__device__ __forceinline__ void stsel(void* p, int i, float v, bool bf) {
  if (bf) ((__hip_bfloat16*)p)[i] = __float2bfloat16(v);
  else ((float*)p)[i] = v;
}

__global__ void detect_dtype_k(const void* x, float* flag) {
  __shared__ int sh[256];
  int tid = threadIdx.x;
  const __hip_bfloat16* xb = (const __hip_bfloat16*)x;
  int ok = 0;
  for (int i = tid; i < 1024; i += 256) {
    float v = fabsf(__bfloat162float(xb[2 * i]));
    if (v > 9.5e-7f && v < 1.05e6f) ok++;
  }
  sh[tid] = ok;
  __syncthreads();
  for (int s = 128; s > 0; s >>= 1) {
    if (tid < s) sh[tid] += sh[tid + s];
    __syncthreads();
  }
  if (tid == 0) flag[0] = (sh[0] > 512) ? 1.f : 0.f;
}

// ---------- pack 1x1 weights -> bf16 [O*Cin] (k-contiguous, coalesced) ----------
__global__ __launch_bounds__(256)
void pack_w_k(const void* __restrict__ src, u16* __restrict__ dst,
              int OCin, const float* __restrict__ dflag) {
  bool bf = dflag[0] > 0.5f;
  int gid = blockIdx.x * 256 + threadIdx.x;
  if (gid >= OCin) return;
  dst[gid] = f2b(ldsel(src, gid, bf));
}

// ---------- pack 3x3 weights (O,Ci,3,3) -> bf16 [t][O][Cin] ----------
__global__ __launch_bounds__(256)
void pack9_w_k(const void* __restrict__ src, u16* __restrict__ dst,
               int OCin, const float* __restrict__ dflag) {
  bool bf = dflag[0] > 0.5f;
  int gid = blockIdx.x * 256 + threadIdx.x;
  if (gid >= OCin) return;
  #pragma unroll
  for (int t = 0; t < 9; ++t)
    dst[(size_t)t * OCin + gid] = f2b(ldsel(src, gid * 9 + t, bf));
}

// ---------- depthwise 3x3 conv (ALPF stage A) -> bf16 [C][HW] ----------
__global__ __launch_bounds__(256)
void dwconv_k(const void* x, const void* wt, const void* bs, u16* y,
              const float* dflag) {
  bool bf = dflag[0] > 0.5f;
  int gid = blockIdx.x * 256 + threadIdx.x;           // 802816 exact
  int c = gid / HWP, p = gid - c * HWP;
  int h = p / WWC, w = p - h * WWC;
  float acc = ldsel(bs, c, bf);
  #pragma unroll
  for (int t = 0; t < 9; ++t) {
    int dh = t / 3 - 1, dw = t % 3 - 1;
    int hh = h + dh, ww = w + dw;
    if (hh >= 0 && hh < HH && ww >= 0 && ww < WWC)
      acc += ldsel(x, c * HWP + hh * WWC + ww, bf) * ldsel(wt, c * 9 + t, bf);
  }
  y[gid] = f2b(acc);
}

// ---------- MFMA GEMM / conv-as-GEMM, 32x32 tile (all GEMM sites) ----------
// OMODE 0: fp32 Y[o][p]; 1: flag-dtype Y[o][p]; 2: bf16 Y[p][o]; 3: bf16 Y[o][p].
// xmode  0: fp32 X[Cin][HW]; 1: flag X[Cin][HW]; 2: bf16 X[p][Cin]; 3: bf16 X[Cin][HW].
// ADDIN: bf16 [o][HW]. bid swizzle: o0 = bid % NO -> per-XCD weight locality.
template<int TAPS, int ACT, bool ADDIN, int OMODE>
__global__ __launch_bounds__(256)
void mgemm32_k(const u16* __restrict__ Wp, const void* __restrict__ X,
               const void* __restrict__ bias, const u16* __restrict__ addin,
               void* __restrict__ Y, int Cin,
               const float* __restrict__ dflag, int xmode, int bias_off) {
  bool wbf = dflag[0] > 0.5f;
  bool xbf = (xmode == 1) ? wbf : false;
  __shared__ u16 Ws[32][72];   // [o][k]
  __shared__ u16 Xs[32][72];   // [p][k]
  int NO = gridDim.y;
  int O = NO * 32;
  int bid = blockIdx.x + blockIdx.y * gridDim.x;
  int p0 = (bid / NO) * 32, o0 = (bid % NO) * 32;
  int tid = threadIdx.x, lane = tid & 63, wv = tid >> 6;
  int oq = (wv & 1) * 16, pq = (wv >> 1) * 16;
  int frow = lane & 15, kgrp = (lane >> 4) * 8;
  int wol = tid >> 3, wkk = (tid & 7) * 8;       // W: 32 rows x 64 k
  int pl = tid & 31, xkk = (tid >> 5) * 8;       // X: 32 rows x 64 k
  int p = p0 + pl, h = p / WWC, w = p - h * WWC;
  f32x4 acc = {0.f, 0.f, 0.f, 0.f};
  for (int t = 0; t < TAPS; ++t) {
    int dh = t / 3 - 1, dw = t % 3 - 1;
    int hh = h + dh, ww = w + dw;
    bool rowok = (TAPS == 1) || ((hh >= 0) && (hh < HH) && (ww >= 0) && (ww < WWC));
    int xoff = (TAPS == 1) ? p : hh * WWC + ww;
    const u16* Wrow = Wp + (size_t)t * O * Cin;
    for (int kb = 0; kb < Cin; kb += 64) {
      __syncthreads();
      *(u16x8*)&Ws[wol][wkk] =
          *(const u16x8*)&Wrow[(size_t)(o0 + wol) * Cin + kb + wkk];
      {
        u16x8 xv;
        if (xmode == 2) {
          if (rowok) {
            xv = *(const u16x8*)&((const u16*)X)[(size_t)xoff * Cin + kb + xkk];
          } else {
            #pragma unroll
            for (int j = 0; j < 8; ++j) xv[j] = 0;
          }
        } else if (xmode == 3) {
          #pragma unroll
          for (int j = 0; j < 8; ++j)
            xv[j] = rowok ? ((const u16*)X)[(size_t)(kb + xkk + j) * HWP + xoff]
                          : (u16)0;
        } else {
          #pragma unroll
          for (int j = 0; j < 8; ++j) {
            int kk = xkk + j;
            float v = rowok ? ldsel(X, (size_t)(kb + kk) * HWP + xoff, xbf) : 0.f;
            xv[j] = f2b(v);
          }
        }
        *(u16x8*)&Xs[pl][xkk] = xv;
      }
      __syncthreads();
      #pragma unroll
      for (int ks = 0; ks < 2; ++ks) {
        s16x8 aw = *(const s16x8*)&Ws[oq + frow][ks * 32 + kgrp];
        s16x8 ax = *(const s16x8*)&Xs[pq + frow][ks * 32 + kgrp];
        acc = mfma16(aw, ax, acc);
      }
    }
  }
  // D mapping (verified): col = lane&15 -> p, row = (lane>>4)*4+r -> o
  int orow = (lane >> 4) * 4;
  int ogb = o0 + oq + orow;
  int pg = p0 + pq + frow;
  if (OMODE == 2) {
    u16x4 st;
    #pragma unroll
    for (int r = 0; r < 4; ++r) {
      float yv = acc[r] + ldsel(bias, bias_off + ogb + r, wbf);
      if (ACT == 1) yv = (yv >= 0.f) ? yv : 0.2f * yv;
      if (ADDIN) yv += b2f(addin[(size_t)(ogb + r) * HWP + pg]);
      st[r] = f2b(yv);
    }
    *(u16x4*)&((u16*)Y)[(size_t)pg * O + ogb] = st;
  } else {
    #pragma unroll
    for (int r = 0; r < 4; ++r) {
      int og = ogb + r;
      float yv = acc[r] + ldsel(bias, bias_off + og, wbf);
      if (ACT == 1) yv = (yv >= 0.f) ? yv : 0.2f * yv;
      if (ADDIN) yv += b2f(addin[(size_t)og * HWP + pg]);
      if (OMODE == 3) ((u16*)Y)[(size_t)og * HWP + pg] = f2b(yv);
      else stsel(Y, (size_t)og * HWP + pg, yv, (OMODE == 1) && wbf);
    }
  }
}

// ---------- 1x1 conv 128 -> 9 + softmax (bf16 hid in, bf16 out) ----------
template<bool DELTA>
__global__ __launch_bounds__(256)
void pw9_v2_k(const void* __restrict__ w2, const void* __restrict__ b2,
              const u16* __restrict__ hid, u16* __restrict__ out9,
              const float* __restrict__ dflag) {
  bool bf = dflag[0] > 0.5f;
  __shared__ float Wl[9][128];
  __shared__ float Pl[4][9][33];
  int tid = threadIdx.x;
  for (int i = tid; i < 1152; i += 256) Wl[i >> 7][i & 127] = ldsel(w2, i, bf);
  __syncthreads();
  int pix = tid & 31, cig = tid >> 5;        // 8 groups x 16 ci
  int p = blockIdx.x * 32 + pix;
  int ci0 = cig * 16;
  float acc[9] = {0.f, 0.f, 0.f, 0.f, 0.f, 0.f, 0.f, 0.f, 0.f};
  #pragma unroll
  for (int j = 0; j < 16; ++j) {
    float xv = b2f(hid[(size_t)(ci0 + j) * HWP + p]);
    #pragma unroll
    for (int t = 0; t < 9; ++t) acc[t] += Wl[t][ci0 + j] * xv;
  }
  #pragma unroll
  for (int t = 0; t < 9; ++t) acc[t] += __shfl_xor(acc[t], 32);
  int wv = tid >> 6;
  if ((tid & 63) < 32) {
    #pragma unroll
    for (int t = 0; t < 9; ++t) Pl[wv][t][pix] = acc[t];
  }
  __syncthreads();
  if (tid < 32) {
    float a[9];
    #pragma unroll
    for (int t = 0; t < 9; ++t)
      a[t] = Pl[0][t][pix] + Pl[1][t][pix] + Pl[2][t][pix] + Pl[3][t][pix] +
             ldsel(b2, t, bf);
    float mx = a[0];
    #pragma unroll
    for (int t = 1; t < 9; ++t) mx = fmaxf(mx, a[t]);
    float s = 0.f;
    #pragma unroll
    for (int t = 0; t < 9; ++t) { a[t] = __expf(a[t] - mx); s += a[t]; }
    float inv = 1.f / s;
    #pragma unroll
    for (int t = 0; t < 9; ++t) {
      float v = a[t] * inv;
      if (DELTA) v = ((t == 4) ? 1.f : 0.f) - v;
      out9[(size_t)t * HWP + p] = f2b(v);
    }
  }
}

// ---------- spatially-varying 3x3 filter (bf16 w9, bf16 out) ----------
template<bool HIGH>
__global__ __launch_bounds__(256)
void spatial_filter_k(const void* x, const u16* __restrict__ w9,
                      u16* __restrict__ y, const float* dflag) {
  bool bf = dflag[0] > 0.5f;
  int gid = blockIdx.x * 256 + threadIdx.x;
  int c = gid / HWP, p = gid - c * HWP;
  int h = p / WWC, w = p - h * WWC;
  float acc = HIGH ? ldsel(x, gid, bf) : 0.f;
  #pragma unroll
  for (int t = 0; t < 9; ++t) {
    int dh = t / 3 - 1, dw = t % 3 - 1;
    int hh = h + dh, ww = w + dw;
    if (hh >= 0 && hh < HH && ww >= 0 && ww < WWC)
      acc += ldsel(x, c * HWP + hh * WWC + ww, bf) * b2f(w9[t * HWP + p]);
  }
  y[gid] = f2b(acc);
}

// ---------- flash attention partial: direct-global fragments, ZERO barriers ----------
// Fragments load straight from global (index-identical to the prior LDS-staged
// values, verified): ak = k16[(m0+fm*16+frow)*256 + h*32+kgrp], bv =
// v16[(h*32+(16?)+frow)*HWP + m0+ks*32+kgrp], aq likewise. Only LDS use is the
// per-wave P round-trip (Ps[wv]) -> no __syncthreads anywhere; waves drift and
// TLP hides L2 latency. Swapped-QK no-max softmax as in R12.
__global__ __launch_bounds__(256)
void attn_part_k(const u16* __restrict__ Qb, const u16* __restrict__ Kb,
                 const u16* __restrict__ Vb, u16* __restrict__ Op,
                 float* __restrict__ Lb) {
  __shared__ u16 Ps[4][16][72];   // per-wave P tile [q][m]
  int h = blockIdx.y, n0 = blockIdx.x * 64, sz = blockIdx.z;
  int tid = threadIdx.x, lane = tid & 63, wv = tid >> 6;
  int frow = lane & 15, gq = lane >> 4, kgrp = gq * 8;
  const float QS = 0.17677669529663687f * 1.4426950408889634f;  // scale*log2e
  s16x8 aq;
  {
    u16x8 qv = *(const u16x8*)&Qb[(size_t)(n0 + wv * 16 + frow) * 256 + h * 32 + kgrp];
    u16x8 qs;
    #pragma unroll
    for (int j = 0; j < 8; ++j) qs[j] = f2b(b2f(qv[j]) * QS);
    aq = *(s16x8*)&qs;
  }
  const u16* Kh = Kb + h * 32 + kgrp;
  const u16* Vh0 = Vb + (size_t)(h * 32 + frow) * HWP;
  const u16* Vh1 = Vb + (size_t)(h * 32 + 16 + frow) * HWP;
  f32x4 oa0 = {0.f, 0.f, 0.f, 0.f}, oa1 = {0.f, 0.f, 0.f, 0.f};
  float lsum = 0.f;
  int t_begin = (49 * sz) / NSPLIT, t_end = (49 * (sz + 1)) / NSPLIT;
  f32x4 zero = {0.f, 0.f, 0.f, 0.f};
  for (int t = t_begin; t < t_end; ++t) {
    int m0 = t * 64;
    #pragma unroll
    for (int fm = 0; fm < 4; ++fm) {
      s16x8 ak = *(const s16x8*)&Kh[(size_t)(m0 + fm * 16 + frow) * 256];
      f32x4 s = mfma16(ak, aq, zero);       // D[m][q]: rows=m, col=q=frow
      u16x4 pe;
      #pragma unroll
      for (int r = 0; r < 4; ++r) {
        float e = exp2f(fminf(s[r], 43.f));
        lsum += e;
        pe[r] = (u16)(__float_as_uint(e) >> 16);  // trunc-to-bf16 (P in (0,1])
      }
      *(u16x4*)&Ps[wv][frow][fm * 16 + gq * 4] = pe;
    }
    #pragma unroll
    for (int ks = 0; ks < 2; ++ks) {
      s16x8 ap = *(const s16x8*)&Ps[wv][frow][ks * 32 + kgrp];
      s16x8 bv0 = *(const s16x8*)&Vh0[m0 + ks * 32 + kgrp];
      s16x8 bv1 = *(const s16x8*)&Vh1[m0 + ks * 32 + kgrp];
      oa0 = mfma16(ap, bv0, oa0);
      oa1 = mfma16(ap, bv1, oa1);
    }
  }
  lsum += __shfl_xor(lsum, 16);
  lsum += __shfl_xor(lsum, 32);
  if (lane < 16)
    Lb[(size_t)(sz * 8 + h) * HWP + n0 + wv * 16 + frow] = lsum;
  #pragma unroll
  for (int r = 0; r < 4; ++r) {
    int n = n0 + wv * 16 + gq * 4 + r;
    Op[(size_t)(sz * 256 + h * 32 + frow) * HWP + n]      = f2b(oa0[r]);
    Op[(size_t)(sz * 256 + h * 32 + 16 + frow) * HWP + n] = f2b(oa1[r]);
  }
}

// ---------- combine NSPLIT attention partials -> bf16 [C][HW] ----------
__global__ __launch_bounds__(256)
void attn_combine_k(const u16* __restrict__ Op, const float* __restrict__ Lb,
                    u16* __restrict__ A) {
  int gid = blockIdx.x * 256 + threadIdx.x;   // 802816
  int n = gid % HWP, hd = gid / HWP, h = hd >> 5;
  float L = 0.f, O = 0.f;
  #pragma unroll
  for (int s = 0; s < NSPLIT; ++s) {
    L += Lb[(size_t)(s * 8 + h) * HWP + n];
    O += b2f(Op[(size_t)(s * 256 + hd) * HWP + n]);
  }
  A[(size_t)hd * HWP + n] = f2b(O / L);
}

extern "C" void kernel_launch(void* const* d_in, const int* in_sizes, int n_in,
                              void* d_out, int out_size, void* d_ws, size_t ws_size,
                              hipStream_t stream) {
  const void* dec   = d_in[0];
  const void* enc   = d_in[1];
  const void* dw_w  = d_in[2];
  const void* dw_b  = d_in[3];
  const void* p1_w  = d_in[4];
  const void* p1_b  = d_in[5];
  const void* p2_w  = d_in[6];
  const void* p2_b  = d_in[7];
  const void* c1_w  = d_in[8];
  const void* c1_b  = d_in[9];
  const void* c2_w  = d_in[10];
  const void* c2_b  = d_in[11];
  const void* q_w   = d_in[12];
  const void* q_b   = d_in[13];
  const void* kv_w  = d_in[14];
  const void* kv_b  = d_in[15];
  const void* out_w = d_in[16];
  const void* out_b = d_in[17];
  const void* fu_w  = d_in[18];
  const void* fu_b  = d_in[19];

  const int CH = CC * HWP;     // 802816
  float* flag = (float*)d_ws;                       // 8 floats
  u16* pk     = (u16*)(flag + 8);
  u16* A      = pk;              pk += CH;            // dwconv out / attn out, bf16 [C][HW]
  u16* hid    = pk;              pk += 128 * HWP;     // bf16 [128][HW]
  u16* s9     = pk;              pk += 9 * HWP;       // bf16 [9][HW]
  u16* Bb     = pk;              pk += CH;            // f_smooth / f_high, bf16 [C][HW]
  u16* qb16   = pk;              pk += CH;            // q bf16 [n][256]; later fused_in [p][256]
  u16* k16    = pk;              pk += CH;            // K bf16 [m][256]
  u16* v16    = pk;              pk += CH;            // V bf16 [d][HWP]
  u16* wp_p1  = pk;              pk += 128 * 256;
  u16* wp_q   = pk;              pk += 256 * 256;
  u16* wp_kv  = pk;              pk += 512 * 256;
  u16* wp_out = pk;              pk += 256 * 256;
  u16* wp_c1  = pk;              pk += 128 * 256 * 9;
  u16* wp_fu  = pk;              pk += 256 * 256 * 9;
  pk += (size_t)(-(intptr_t)pk) & 7;                  // align to 4 floats
  float* Lb   = (float*)pk;                           // 32*HWP f32
  u16* Opart  = (u16*)(Lb + 32 * HWP);                // 1024*HWP u16

  dim3 blk(256);
  detect_dtype_k<<<1, blk, 0, stream>>>(dec, flag);

  // ---- pack weights to bf16 k-contiguous ----
  pack_w_k<<<128, blk, 0, stream>>>(p1_w, wp_p1, 128 * 256, flag);
  pack_w_k<<<256, blk, 0, stream>>>(q_w, wp_q, 256 * 256, flag);
  pack_w_k<<<512, blk, 0, stream>>>(kv_w, wp_kv, 512 * 256, flag);
  pack_w_k<<<256, blk, 0, stream>>>(out_w, wp_out, 256 * 256, flag);
  pack9_w_k<<<128, blk, 0, stream>>>(c1_w, wp_c1, 128 * 256, flag);
  pack9_w_k<<<256, blk, 0, stream>>>(fu_w, wp_fu, 256 * 256, flag);

  // ---- ALPF: kw = softmax(p2(lrelu(p1(dw(dec))))) ----
  dwconv_k<<<3136, blk, 0, stream>>>(dec, dw_w, dw_b, A, flag);
  mgemm32_k<1, 1, false, 3><<<dim3(98, 4), blk, 0, stream>>>(
      wp_p1, A, p1_b, nullptr, hid, 256, flag, 3, 0);
  pw9_v2_k<false><<<98, blk, 0, stream>>>(p2_w, p2_b, hid, s9, flag);
  spatial_filter_k<false><<<3136, blk, 0, stream>>>(dec, s9, Bb, flag);

  // ---- q / k / v projections ----
  mgemm32_k<1, 0, false, 2><<<dim3(98, 8), blk, 0, stream>>>(
      wp_q, Bb, q_b, nullptr, qb16, 256, flag, 3, 0);
  mgemm32_k<1, 0, false, 2><<<dim3(98, 8), blk, 0, stream>>>(
      wp_kv, enc, kv_b, nullptr, k16, 256, flag, 1, 0);
  mgemm32_k<1, 0, false, 3><<<dim3(98, 8), blk, 0, stream>>>(
      wp_kv + 256 * 256, enc, kv_b, nullptr, v16, 256, flag, 1, 256);

  // ---- attention: 4-way KV-split partials + combine ----
  attn_part_k<<<dim3(49, 8, NSPLIT), blk, 0, stream>>>(qb16, k16, v16, Opart, Lb);
  attn_combine_k<<<3136, blk, 0, stream>>>(Opart, Lb, A);

  // ---- AHPF: whp = delta - softmax(c2(lrelu(c1(enc)))) ----
  mgemm32_k<9, 1, false, 3><<<dim3(98, 4), blk, 0, stream>>>(
      wp_c1, enc, c1_b, nullptr, hid, 256, flag, 1, 0);
  pw9_v2_k<true><<<98, blk, 0, stream>>>(c2_w, c2_b, hid, s9, flag);
  spatial_filter_k<true><<<3136, blk, 0, stream>>>(enc, s9, Bb, flag);

  // ---- out proj + f_high add -> bf16 [p][256] (reuses qb16, q is dead) ----
  mgemm32_k<1, 0, true, 2><<<dim3(98, 8), blk, 0, stream>>>(
      wp_out, A, out_b, Bb, qb16, 256, flag, 3, 0);

  // ---- fusion 3x3 conv (bf16 pixel-major X) -> d_out ----
  mgemm32_k<9, 0, false, 1><<<dim3(98, 8), blk, 0, stream>>>(
      wp_fu, qb16, fu_b, nullptr, d_out, 256, flag, 2, 0);
}

// Round 15
// 188.531 us; speedup vs baseline: 1.2895x; 1.2895x over previous
//
#include <hip/hip_runtime.h>
#include <hip/hip_bf16.h>

#define HH  56
#define WWC 56
#define HWP 3136   // 56*56 = 49*64
#define CC  256
#define NSPLIT 4

typedef unsigned short u16;
typedef __attribute__((ext_vector_type(8))) u16 u16x8;
typedef __attribute__((ext_vector_type(4))) u16 u16x4;
typedef __attribute__((ext_vector_type(8))) short s16x8;   // bf16x8 MFMA frag
typedef __attribute__((ext_vector_type(4))) float f32x4;

__device__ __forceinline__ u16 f2b(float f) {
  unsigned int x = __float_as_uint(f);
  return (u16)((x + 0x7fffu + ((x >> 16) & 1u)) >> 16);
}
__device__ __forceinline__ float b2f(u16 u) {
  return __uint_as_float(((unsigned int)u) << 16);
}
__device__ __forceinline__ f32x4 mfma16(s16x8 a, s16x8 b, f32x4 c) {
  return __builtin_amdgcn_mfma_f32_16x16x32_bf16(a, b, c, 0, 0, 0);
}

// ---------- dtype-flexible load/store (flag decided on device) ----------
__device__ __forceinline__ float ldsel(const void* p, int i, bool bf) {
  if (bf) return __bfloat162float(((const __hip_bfloat16*)p)[i]);
  return ((const float*)p)[i];
}
__device__ __forceinline__ void stsel(void* p, int i, float v, bool bf) {
  if (bf) ((__hip_bfloat16*)p)[i] = __float2bfloat16(v);
  else ((float*)p)[i] = v;
}

__global__ void detect_dtype_k(const void* x, float* flag) {
  __shared__ int sh[256];
  int tid = threadIdx.x;
  const __hip_bfloat16* xb = (const __hip_bfloat16*)x;
  int ok = 0;
  for (int i = tid; i < 1024; i += 256) {
    float v = fabsf(__bfloat162float(xb[2 * i]));
    if (v > 9.5e-7f && v < 1.05e6f) ok++;
  }
  sh[tid] = ok;
  __syncthreads();
  for (int s = 128; s > 0; s >>= 1) {
    if (tid < s) sh[tid] += sh[tid + s];
    __syncthreads();
  }
  if (tid == 0) flag[0] = (sh[0] > 512) ? 1.f : 0.f;
}

// ---------- fused weight pack: all 6 weights in ONE launch ----------
// segments (blocks): p1 128 | q 256 | kv 512 | out 256 | c1(9t) 128 | fu(9t) 256
__global__ __launch_bounds__(256)
void pack_all_k(const void* __restrict__ p1, const void* __restrict__ q,
                const void* __restrict__ kv, const void* __restrict__ ow,
                const void* __restrict__ c1, const void* __restrict__ fu,
                u16* __restrict__ d_p1, u16* __restrict__ d_q,
                u16* __restrict__ d_kv, u16* __restrict__ d_ow,
                u16* __restrict__ d_c1, u16* __restrict__ d_fu,
                const float* __restrict__ dflag) {
  bool bf = dflag[0] > 0.5f;
  int b = blockIdx.x, tid = threadIdx.x;
  if (b < 128) { int g = b * 256 + tid; d_p1[g] = f2b(ldsel(p1, g, bf)); return; }
  b -= 128;
  if (b < 256) { int g = b * 256 + tid; d_q[g] = f2b(ldsel(q, g, bf)); return; }
  b -= 256;
  if (b < 512) { int g = b * 256 + tid; d_kv[g] = f2b(ldsel(kv, g, bf)); return; }
  b -= 512;
  if (b < 256) { int g = b * 256 + tid; d_ow[g] = f2b(ldsel(ow, g, bf)); return; }
  b -= 256;
  if (b < 128) {
    int g = b * 256 + tid;
    #pragma unroll
    for (int t = 0; t < 9; ++t)
      d_c1[(size_t)t * 32768 + g] = f2b(ldsel(c1, g * 9 + t, bf));
    return;
  }
  b -= 128;
  {
    int g = b * 256 + tid;
    #pragma unroll
    for (int t = 0; t < 9; ++t)
      d_fu[(size_t)t * 65536 + g] = f2b(ldsel(fu, g * 9 + t, bf));
  }
}

// ---------- depthwise 3x3 conv (ALPF stage A) -> bf16 [C][HW] ----------
__global__ __launch_bounds__(256)
void dwconv_k(const void* x, const void* wt, const void* bs, u16* y,
              const float* dflag) {
  bool bf = dflag[0] > 0.5f;
  int gid = blockIdx.x * 256 + threadIdx.x;           // 802816 exact
  int c = gid / HWP, p = gid - c * HWP;
  int h = p / WWC, w = p - h * WWC;
  float acc = ldsel(bs, c, bf);
  #pragma unroll
  for (int t = 0; t < 9; ++t) {
    int dh = t / 3 - 1, dw = t % 3 - 1;
    int hh = h + dh, ww = w + dw;
    if (hh >= 0 && hh < HH && ww >= 0 && ww < WWC)
      acc += ldsel(x, c * HWP + hh * WWC + ww, bf) * ldsel(wt, c * 9 + t, bf);
  }
  y[gid] = f2b(acc);
}

// ---------- MFMA GEMM / conv-as-GEMM, 32x32 tile (all GEMM sites) ----------
// OMODE 0: fp32 Y[o][p]; 1: flag-dtype Y[o][p]; 2: bf16 Y[p][o]; 3: bf16 Y[o][p].
// xmode  0: fp32 X[Cin][HW]; 1: flag X[Cin][HW]; 2: bf16 X[p][Cin]; 3: bf16 X[Cin][HW].
// ADDIN: bf16 [o][HW]. bid swizzle: o0 = bid % NO -> per-XCD weight locality.
template<int TAPS, int ACT, bool ADDIN, int OMODE>
__global__ __launch_bounds__(256)
void mgemm32_k(const u16* __restrict__ Wp, const void* __restrict__ X,
               const void* __restrict__ bias, const u16* __restrict__ addin,
               void* __restrict__ Y, int Cin,
               const float* __restrict__ dflag, int xmode, int bias_off) {
  bool wbf = dflag[0] > 0.5f;
  bool xbf = (xmode == 1) ? wbf : false;
  __shared__ u16 Ws[32][72];   // [o][k]
  __shared__ u16 Xs[32][72];   // [p][k]
  int NO = gridDim.y;
  int O = NO * 32;
  int bid = blockIdx.x + blockIdx.y * gridDim.x;
  int p0 = (bid / NO) * 32, o0 = (bid % NO) * 32;
  int tid = threadIdx.x, lane = tid & 63, wv = tid >> 6;
  int oq = (wv & 1) * 16, pq = (wv >> 1) * 16;
  int frow = lane & 15, kgrp = (lane >> 4) * 8;
  int wol = tid >> 3, wkk = (tid & 7) * 8;       // W: 32 rows x 64 k
  int pl = tid & 31, xkk = (tid >> 5) * 8;       // X: 32 rows x 64 k
  int p = p0 + pl, h = p / WWC, w = p - h * WWC;
  f32x4 acc = {0.f, 0.f, 0.f, 0.f};
  for (int t = 0; t < TAPS; ++t) {
    int dh = t / 3 - 1, dw = t % 3 - 1;
    int hh = h + dh, ww = w + dw;
    bool rowok = (TAPS == 1) || ((hh >= 0) && (hh < HH) && (ww >= 0) && (ww < WWC));
    int xoff = (TAPS == 1) ? p : hh * WWC + ww;
    const u16* Wrow = Wp + (size_t)t * O * Cin;
    for (int kb = 0; kb < Cin; kb += 64) {
      __syncthreads();
      *(u16x8*)&Ws[wol][wkk] =
          *(const u16x8*)&Wrow[(size_t)(o0 + wol) * Cin + kb + wkk];
      {
        u16x8 xv;
        if (xmode == 2) {
          if (rowok) {
            xv = *(const u16x8*)&((const u16*)X)[(size_t)xoff * Cin + kb + xkk];
          } else {
            #pragma unroll
            for (int j = 0; j < 8; ++j) xv[j] = 0;
          }
        } else if (xmode == 3) {
          #pragma unroll
          for (int j = 0; j < 8; ++j)
            xv[j] = rowok ? ((const u16*)X)[(size_t)(kb + xkk + j) * HWP + xoff]
                          : (u16)0;
        } else {
          #pragma unroll
          for (int j = 0; j < 8; ++j) {
            int kk = xkk + j;
            float v = rowok ? ldsel(X, (size_t)(kb + kk) * HWP + xoff, xbf) : 0.f;
            xv[j] = f2b(v);
          }
        }
        *(u16x8*)&Xs[pl][xkk] = xv;
      }
      __syncthreads();
      #pragma unroll
      for (int ks = 0; ks < 2; ++ks) {
        s16x8 aw = *(const s16x8*)&Ws[oq + frow][ks * 32 + kgrp];
        s16x8 ax = *(const s16x8*)&Xs[pq + frow][ks * 32 + kgrp];
        acc = mfma16(aw, ax, acc);
      }
    }
  }
  // D mapping (verified): col = lane&15 -> p, row = (lane>>4)*4+r -> o
  int orow = (lane >> 4) * 4;
  int ogb = o0 + oq + orow;
  int pg = p0 + pq + frow;
  if (OMODE == 2) {
    u16x4 st;
    #pragma unroll
    for (int r = 0; r < 4; ++r) {
      float yv = acc[r] + ldsel(bias, bias_off + ogb + r, wbf);
      if (ACT == 1) yv = (yv >= 0.f) ? yv : 0.2f * yv;
      if (ADDIN) yv += b2f(addin[(size_t)(ogb + r) * HWP + pg]);
      st[r] = f2b(yv);
    }
    *(u16x4*)&((u16*)Y)[(size_t)pg * O + ogb] = st;
  } else {
    #pragma unroll
    for (int r = 0; r < 4; ++r) {
      int og = ogb + r;
      float yv = acc[r] + ldsel(bias, bias_off + og, wbf);
      if (ACT == 1) yv = (yv >= 0.f) ? yv : 0.2f * yv;
      if (ADDIN) yv += b2f(addin[(size_t)og * HWP + pg]);
      if (OMODE == 3) ((u16*)Y)[(size_t)og * HWP + pg] = f2b(yv);
      else stsel(Y, (size_t)og * HWP + pg, yv, (OMODE == 1) && wbf);
    }
  }
}

// ---------- 1x1 conv 128 -> 9 + softmax (bf16 hid in, bf16 out) ----------
template<bool DELTA>
__global__ __launch_bounds__(256)
void pw9_v2_k(const void* __restrict__ w2, const void* __restrict__ b2,
              const u16* __restrict__ hid, u16* __restrict__ out9,
              const float* __restrict__ dflag) {
  bool bf = dflag[0] > 0.5f;
  __shared__ float Wl[9][128];
  __shared__ float Pl[4][9][33];
  int tid = threadIdx.x;
  for (int i = tid; i < 1152; i += 256) Wl[i >> 7][i & 127] = ldsel(w2, i, bf);
  __syncthreads();
  int pix = tid & 31, cig = tid >> 5;        // 8 groups x 16 ci
  int p = blockIdx.x * 32 + pix;
  int ci0 = cig * 16;
  float acc[9] = {0.f, 0.f, 0.f, 0.f, 0.f, 0.f, 0.f, 0.f, 0.f};
  #pragma unroll
  for (int j = 0; j < 16; ++j) {
    float xv = b2f(hid[(size_t)(ci0 + j) * HWP + p]);
    #pragma unroll
    for (int t = 0; t < 9; ++t) acc[t] += Wl[t][ci0 + j] * xv;
  }
  #pragma unroll
  for (int t = 0; t < 9; ++t) acc[t] += __shfl_xor(acc[t], 32);
  int wv = tid >> 6;
  if ((tid & 63) < 32) {
    #pragma unroll
    for (int t = 0; t < 9; ++t) Pl[wv][t][pix] = acc[t];
  }
  __syncthreads();
  if (tid < 32) {
    float a[9];
    #pragma unroll
    for (int t = 0; t < 9; ++t)
      a[t] = Pl[0][t][pix] + Pl[1][t][pix] + Pl[2][t][pix] + Pl[3][t][pix] +
             ldsel(b2, t, bf);
    float mx = a[0];
    #pragma unroll
    for (int t = 1; t < 9; ++t) mx = fmaxf(mx, a[t]);
    float s = 0.f;
    #pragma unroll
    for (int t = 0; t < 9; ++t) { a[t] = __expf(a[t] - mx); s += a[t]; }
    float inv = 1.f / s;
    #pragma unroll
    for (int t = 0; t < 9; ++t) {
      float v = a[t] * inv;
      if (DELTA) v = ((t == 4) ? 1.f : 0.f) - v;
      out9[(size_t)t * HWP + p] = f2b(v);
    }
  }
}

// ---------- spatially-varying 3x3 filter (bf16 w9, bf16 out) ----------
template<bool HIGH>
__global__ __launch_bounds__(256)
void spatial_filter_k(const void* x, const u16* __restrict__ w9,
                      u16* __restrict__ y, const float* dflag) {
  bool bf = dflag[0] > 0.5f;
  int gid = blockIdx.x * 256 + threadIdx.x;
  int c = gid / HWP, p = gid - c * HWP;
  int h = p / WWC, w = p - h * WWC;
  float acc = HIGH ? ldsel(x, gid, bf) : 0.f;
  #pragma unroll
  for (int t = 0; t < 9; ++t) {
    int dh = t / 3 - 1, dw = t % 3 - 1;
    int hh = h + dh, ww = w + dw;
    if (hh >= 0 && hh < HH && ww >= 0 && ww < WWC)
      acc += ldsel(x, c * HWP + hh * WWC + ww, bf) * b2f(w9[t * HWP + p]);
  }
  y[gid] = f2b(acc);
}

// ---------- flash attention partial (REVERTED to R13: LDS-staged K/V) ----------
// Swapped-QK no-max softmax; K/V staged via coalesced u16x8 + vector LDS
// writes with reg double-buffer prefetch (the proven 43.6us structure).
// Q fragment loads directly from global (once per kernel; Qs LDS dropped).
__global__ __launch_bounds__(256)
void attn_part_k(const u16* __restrict__ Qb, const u16* __restrict__ Kb,
                 const u16* __restrict__ Vb, u16* __restrict__ Op,
                 float* __restrict__ Lb) {
  __shared__ u16 Ks[64][40];
  __shared__ u16 Vs[32][72];      // [d][m] linear
  __shared__ u16 Ps[4][16][72];   // per-wave P tile [q][m]
  int h = blockIdx.y, n0 = blockIdx.x * 64, sz = blockIdx.z;
  int tid = threadIdx.x, lane = tid & 63, wv = tid >> 6;
  int frow = lane & 15, gq = lane >> 4, kgrp = gq * 8;
  int ml = tid >> 2, dseg = (tid & 3) * 8;     // K staging: [64 m][32 d]
  int vd = tid >> 3, vm = (tid & 7) * 8;       // V staging: [32 d][64 m]
  const float QS = 0.17677669529663687f * 1.4426950408889634f;  // scale*log2e
  s16x8 aq;
  {
    u16x8 qv = *(const u16x8*)&Qb[(size_t)(n0 + wv * 16 + frow) * 256 + h * 32 + kgrp];
    u16x8 qs;
    #pragma unroll
    for (int j = 0; j < 8; ++j) qs[j] = f2b(b2f(qv[j]) * QS);
    aq = *(s16x8*)&qs;
  }
  f32x4 oa0 = {0.f, 0.f, 0.f, 0.f}, oa1 = {0.f, 0.f, 0.f, 0.f};
  float lsum = 0.f;
  int t_begin = (49 * sz) / NSPLIT, t_end = (49 * (sz + 1)) / NSPLIT;
  u16x8 kreg = *(const u16x8*)&Kb[(size_t)(t_begin * 64 + ml) * 256 + h * 32 + dseg];
  u16x8 vreg = *(const u16x8*)&Vb[(size_t)(h * 32 + vd) * HWP + t_begin * 64 + vm];
  for (int t = t_begin; t < t_end; ++t) {
    __syncthreads();
    *(u16x8*)&Ks[ml][dseg] = kreg;
    *(u16x8*)&Vs[vd][vm] = vreg;
    if (t + 1 < t_end) {
      kreg = *(const u16x8*)&Kb[(size_t)((t + 1) * 64 + ml) * 256 + h * 32 + dseg];
      vreg = *(const u16x8*)&Vb[(size_t)(h * 32 + vd) * HWP + (t + 1) * 64 + vm];
    }
    __syncthreads();
    f32x4 zero = {0.f, 0.f, 0.f, 0.f};
    #pragma unroll
    for (int fm = 0; fm < 4; ++fm) {
      s16x8 ak = *(const s16x8*)&Ks[fm * 16 + frow][kgrp];
      f32x4 s = mfma16(ak, aq, zero);       // D[m][q]: rows=m, col=q=frow
      u16x4 pe;
      #pragma unroll
      for (int r = 0; r < 4; ++r) {
        float e = exp2f(fminf(s[r], 43.f));
        lsum += e;
        pe[r] = (u16)(__float_as_uint(e) >> 16);  // trunc-to-bf16 (P in (0,1])
      }
      *(u16x4*)&Ps[wv][frow][fm * 16 + gq * 4] = pe;
    }
    #pragma unroll
    for (int ks = 0; ks < 2; ++ks) {
      s16x8 ap = *(const s16x8*)&Ps[wv][frow][ks * 32 + kgrp];
      s16x8 bv0 = *(const s16x8*)&Vs[frow][ks * 32 + kgrp];
      s16x8 bv1 = *(const s16x8*)&Vs[16 + frow][ks * 32 + kgrp];
      oa0 = mfma16(ap, bv0, oa0);
      oa1 = mfma16(ap, bv1, oa1);
    }
  }
  lsum += __shfl_xor(lsum, 16);
  lsum += __shfl_xor(lsum, 32);
  if (lane < 16)
    Lb[(size_t)(sz * 8 + h) * HWP + n0 + wv * 16 + frow] = lsum;
  #pragma unroll
  for (int r = 0; r < 4; ++r) {
    int n = n0 + wv * 16 + gq * 4 + r;
    Op[(size_t)(sz * 256 + h * 32 + frow) * HWP + n]      = f2b(oa0[r]);
    Op[(size_t)(sz * 256 + h * 32 + 16 + frow) * HWP + n] = f2b(oa1[r]);
  }
}

// ---------- combine NSPLIT attention partials -> bf16 [C][HW] ----------
__global__ __launch_bounds__(256)
void attn_combine_k(const u16* __restrict__ Op, const float* __restrict__ Lb,
                    u16* __restrict__ A) {
  int gid = blockIdx.x * 256 + threadIdx.x;   // 802816
  int n = gid % HWP, hd = gid / HWP, h = hd >> 5;
  float L = 0.f, O = 0.f;
  #pragma unroll
  for (int s = 0; s < NSPLIT; ++s) {
    L += Lb[(size_t)(s * 8 + h) * HWP + n];
    O += b2f(Op[(size_t)(s * 256 + hd) * HWP + n]);
  }
  A[(size_t)hd * HWP + n] = f2b(O / L);
}

extern "C" void kernel_launch(void* const* d_in, const int* in_sizes, int n_in,
                              void* d_out, int out_size, void* d_ws, size_t ws_size,
                              hipStream_t stream) {
  const void* dec   = d_in[0];
  const void* enc   = d_in[1];
  const void* dw_w  = d_in[2];
  const void* dw_b  = d_in[3];
  const void* p1_w  = d_in[4];
  const void* p1_b  = d_in[5];
  const void* p2_w  = d_in[6];
  const void* p2_b  = d_in[7];
  const void* c1_w  = d_in[8];
  const void* c1_b  = d_in[9];
  const void* c2_w  = d_in[10];
  const void* c2_b  = d_in[11];
  const void* q_w   = d_in[12];
  const void* q_b   = d_in[13];
  const void* kv_w  = d_in[14];
  const void* kv_b  = d_in[15];
  const void* out_w = d_in[16];
  const void* out_b = d_in[17];
  const void* fu_w  = d_in[18];
  const void* fu_b  = d_in[19];

  const int CH = CC * HWP;     // 802816
  float* flag = (float*)d_ws;                       // 8 floats
  u16* pk     = (u16*)(flag + 8);
  u16* A      = pk;              pk += CH;            // dwconv out / attn out, bf16 [C][HW]
  u16* hid    = pk;              pk += 128 * HWP;     // bf16 [128][HW]
  u16* s9     = pk;              pk += 9 * HWP;       // bf16 [9][HW]
  u16* Bb     = pk;              pk += CH;            // f_smooth / f_high, bf16 [C][HW]
  u16* qb16   = pk;              pk += CH;            // q bf16 [n][256]; later fused_in [p][256]
  u16* k16    = pk;              pk += CH;            // K bf16 [m][256]
  u16* v16    = pk;              pk += CH;            // V bf16 [d][HWP]
  u16* wp_p1  = pk;              pk += 128 * 256;
  u16* wp_q   = pk;              pk += 256 * 256;
  u16* wp_kv  = pk;              pk += 512 * 256;
  u16* wp_out = pk;              pk += 256 * 256;
  u16* wp_c1  = pk;              pk += 128 * 256 * 9;
  u16* wp_fu  = pk;              pk += 256 * 256 * 9;
  pk += (size_t)(-(intptr_t)pk) & 7;                  // align to 4 floats
  float* Lb   = (float*)pk;                           // 32*HWP f32
  u16* Opart  = (u16*)(Lb + 32 * HWP);                // 1024*HWP u16

  dim3 blk(256);
  detect_dtype_k<<<1, blk, 0, stream>>>(dec, flag);

  // ---- pack ALL weights (one launch) ----
  pack_all_k<<<1536, blk, 0, stream>>>(p1_w, q_w, kv_w, out_w, c1_w, fu_w,
                                       wp_p1, wp_q, wp_kv, wp_out, wp_c1, wp_fu,
                                       flag);

  // ---- ALPF: kw = softmax(p2(lrelu(p1(dw(dec))))) ----
  dwconv_k<<<3136, blk, 0, stream>>>(dec, dw_w, dw_b, A, flag);
  mgemm32_k<1, 1, false, 3><<<dim3(98, 4), blk, 0, stream>>>(
      wp_p1, A, p1_b, nullptr, hid, 256, flag, 3, 0);
  pw9_v2_k<false><<<98, blk, 0, stream>>>(p2_w, p2_b, hid, s9, flag);
  spatial_filter_k<false><<<3136, blk, 0, stream>>>(dec, s9, Bb, flag);

  // ---- q / k / v projections ----
  mgemm32_k<1, 0, false, 2><<<dim3(98, 8), blk, 0, stream>>>(
      wp_q, Bb, q_b, nullptr, qb16, 256, flag, 3, 0);
  mgemm32_k<1, 0, false, 2><<<dim3(98, 8), blk, 0, stream>>>(
      wp_kv, enc, kv_b, nullptr, k16, 256, flag, 1, 0);
  mgemm32_k<1, 0, false, 3><<<dim3(98, 8), blk, 0, stream>>>(
      wp_kv + 256 * 256, enc, kv_b, nullptr, v16, 256, flag, 1, 256);

  // ---- attention: 4-way KV-split partials + combine ----
  attn_part_k<<<dim3(49, 8, NSPLIT), blk, 0, stream>>>(qb16, k16, v16, Opart, Lb);
  attn_combine_k<<<3136, blk, 0, stream>>>(Opart, Lb, A);

  // ---- AHPF: whp = delta - softmax(c2(lrelu(c1(enc)))) ----
  mgemm32_k<9, 1, false, 3><<<dim3(98, 4), blk, 0, stream>>>(
      wp_c1, enc, c1_b, nullptr, hid, 256, flag, 1, 0);
  pw9_v2_k<true><<<98, blk, 0, stream>>>(c2_w, c2_b, hid, s9, flag);
  spatial_filter_k<true><<<3136, blk, 0, stream>>>(enc, s9, Bb, flag);

  // ---- out proj + f_high add -> bf16 [p][256] (reuses qb16, q is dead) ----
  mgemm32_k<1, 0, true, 2><<<dim3(98, 8), blk, 0, stream>>>(
      wp_out, A, out_b, Bb, qb16, 256, flag, 3, 0);

  // ---- fusion 3x3 conv (bf16 pixel-major X) -> d_out ----
  mgemm32_k<9, 0, false, 1><<<dim3(98, 8), blk, 0, stream>>>(
      wp_fu, qb16, fu_b, nullptr, d_out, 256, flag, 2, 0);
}

// Round 16
// 169.037 us; speedup vs baseline: 1.4382x; 1.1153x over previous
//
#include <hip/hip_runtime.h>
#include <hip/hip_bf16.h>

#define HH  56
#define WWC 56
#define HWP 3136   // 56*56 = 49*64
#define CC  256
#define NSPLIT 4

typedef unsigned short u16;
typedef __attribute__((ext_vector_type(8))) u16 u16x8;
typedef __attribute__((ext_vector_type(4))) u16 u16x4;
typedef __attribute__((ext_vector_type(8))) short s16x8;   // bf16x8 MFMA frag
typedef __attribute__((ext_vector_type(4))) float f32x4;

__device__ __forceinline__ u16 f2b(float f) {
  unsigned int x = __float_as_uint(f);
  return (u16)((x + 0x7fffu + ((x >> 16) & 1u)) >> 16);
}
__device__ __forceinline__ float b2f(u16 u) {
  return __uint_as_float(((unsigned int)u) << 16);
}
__device__ __forceinline__ f32x4 mfma16(s16x8 a, s16x8 b, f32x4 c) {
  return __builtin_amdgcn_mfma_f32_16x16x32_bf16(a, b, c, 0, 0, 0);
}

// ---------- dtype-flexible load/store (flag decided on device) ----------
__device__ __forceinline__ float ldsel(const void* p, int i, bool bf) {
  if (bf) return __bfloat162float(((const __hip_bfloat16*)p)[i]);
  return ((const float*)p)[i];
}
__device__ __forceinline__ void stsel(void* p, int i, float v, bool bf) {
  if (bf) ((__hip_bfloat16*)p)[i] = __float2bfloat16(v);
  else ((float*)p)[i] = v;
}

__global__ void detect_dtype_k(const void* x, float* flag) {
  __shared__ int sh[256];
  int tid = threadIdx.x;
  const __hip_bfloat16* xb = (const __hip_bfloat16*)x;
  int ok = 0;
  for (int i = tid; i < 1024; i += 256) {
    float v = fabsf(__bfloat162float(xb[2 * i]));
    if (v > 9.5e-7f && v < 1.05e6f) ok++;
  }
  sh[tid] = ok;
  __syncthreads();
  for (int s = 128; s > 0; s >>= 1) {
    if (tid < s) sh[tid] += sh[tid + s];
    __syncthreads();
  }
  if (tid == 0) flag[0] = (sh[0] > 512) ? 1.f : 0.f;
}

// ---------- fused weight pack: all 6 weights in ONE launch ----------
// segments (blocks): p1 128 | q 256 | kv 512 | out 256 | c1(9t) 128 | fu(9t) 256
__global__ __launch_bounds__(256)
void pack_all_k(const void* __restrict__ p1, const void* __restrict__ q,
                const void* __restrict__ kv, const void* __restrict__ ow,
                const void* __restrict__ c1, const void* __restrict__ fu,
                u16* __restrict__ d_p1, u16* __restrict__ d_q,
                u16* __restrict__ d_kv, u16* __restrict__ d_ow,
                u16* __restrict__ d_c1, u16* __restrict__ d_fu,
                const float* __restrict__ dflag) {
  bool bf = dflag[0] > 0.5f;
  int b = blockIdx.x, tid = threadIdx.x;
  if (b < 128) { int g = b * 256 + tid; d_p1[g] = f2b(ldsel(p1, g, bf)); return; }
  b -= 128;
  if (b < 256) { int g = b * 256 + tid; d_q[g] = f2b(ldsel(q, g, bf)); return; }
  b -= 256;
  if (b < 512) { int g = b * 256 + tid; d_kv[g] = f2b(ldsel(kv, g, bf)); return; }
  b -= 512;
  if (b < 256) { int g = b * 256 + tid; d_ow[g] = f2b(ldsel(ow, g, bf)); return; }
  b -= 256;
  if (b < 128) {
    int g = b * 256 + tid;
    #pragma unroll
    for (int t = 0; t < 9; ++t)
      d_c1[(size_t)t * 32768 + g] = f2b(ldsel(c1, g * 9 + t, bf));
    return;
  }
  b -= 128;
  {
    int g = b * 256 + tid;
    #pragma unroll
    for (int t = 0; t < 9; ++t)
      d_fu[(size_t)t * 65536 + g] = f2b(ldsel(fu, g * 9 + t, bf));
  }
}

// ---------- depthwise 3x3 conv (ALPF stage A) -> bf16 [C][HW] ----------
__global__ __launch_bounds__(256)
void dwconv_k(const void* x, const void* wt, const void* bs, u16* y,
              const float* dflag) {
  bool bf = dflag[0] > 0.5f;
  int gid = blockIdx.x * 256 + threadIdx.x;           // 802816 exact
  int c = gid / HWP, p = gid - c * HWP;
  int h = p / WWC, w = p - h * WWC;
  float acc = ldsel(bs, c, bf);
  #pragma unroll
  for (int t = 0; t < 9; ++t) {
    int dh = t / 3 - 1, dw = t % 3 - 1;
    int hh = h + dh, ww = w + dw;
    if (hh >= 0 && hh < HH && ww >= 0 && ww < WWC)
      acc += ldsel(x, c * HWP + hh * WWC + ww, bf) * ldsel(wt, c * 9 + t, bf);
  }
  y[gid] = f2b(acc);
}

// ---------- MFMA GEMM / conv-as-GEMM, 32x32 tile (all GEMM sites) ----------
// OMODE 0: fp32 Y[o][p]; 1: flag-dtype Y[o][p]; 2: bf16 Y[p][o]; 3: bf16 Y[o][p];
// OMODE 4: fp32 PARTIAL Y[sz][o][p] (no bias/act; taps split over blockIdx.z).
// xmode  0: fp32 X[Cin][HW]; 1: flag X[Cin][HW]; 2: bf16 X[p][Cin]; 3: bf16 X[Cin][HW].
// ADDIN: bf16 [o][HW]. bid swizzle: o0 = bid % NO -> per-XCD weight locality.
template<int TAPS, int ACT, bool ADDIN, int OMODE>
__global__ __launch_bounds__(256)
void mgemm32_k(const u16* __restrict__ Wp, const void* __restrict__ X,
               const void* __restrict__ bias, const u16* __restrict__ addin,
               void* __restrict__ Y, int Cin,
               const float* __restrict__ dflag, int xmode, int bias_off) {
  bool wbf = dflag[0] > 0.5f;
  bool xbf = (xmode == 1) ? wbf : false;
  __shared__ u16 Ws[32][72];   // [o][k]
  __shared__ u16 Xs[32][72];   // [p][k]
  int NO = gridDim.y;
  int O = NO * 32;
  int bid = blockIdx.x + blockIdx.y * gridDim.x;
  int p0 = (bid / NO) * 32, o0 = (bid % NO) * 32;
  int sz = blockIdx.z, NZ = gridDim.z;
  int t0 = (TAPS * sz) / NZ, t1 = (TAPS * (sz + 1)) / NZ;
  int tid = threadIdx.x, lane = tid & 63, wv = tid >> 6;
  int oq = (wv & 1) * 16, pq = (wv >> 1) * 16;
  int frow = lane & 15, kgrp = (lane >> 4) * 8;
  int wol = tid >> 3, wkk = (tid & 7) * 8;       // W: 32 rows x 64 k
  int pl = tid & 31, xkk = (tid >> 5) * 8;       // X: 32 rows x 64 k
  int p = p0 + pl, h = p / WWC, w = p - h * WWC;
  f32x4 acc = {0.f, 0.f, 0.f, 0.f};
  for (int t = t0; t < t1; ++t) {
    int dh = t / 3 - 1, dw = t % 3 - 1;
    int hh = h + dh, ww = w + dw;
    bool rowok = (TAPS == 1) || ((hh >= 0) && (hh < HH) && (ww >= 0) && (ww < WWC));
    int xoff = (TAPS == 1) ? p : hh * WWC + ww;
    const u16* Wrow = Wp + (size_t)t * O * Cin;
    for (int kb = 0; kb < Cin; kb += 64) {
      __syncthreads();
      *(u16x8*)&Ws[wol][wkk] =
          *(const u16x8*)&Wrow[(size_t)(o0 + wol) * Cin + kb + wkk];
      {
        u16x8 xv;
        if (xmode == 2) {
          if (rowok) {
            xv = *(const u16x8*)&((const u16*)X)[(size_t)xoff * Cin + kb + xkk];
          } else {
            #pragma unroll
            for (int j = 0; j < 8; ++j) xv[j] = 0;
          }
        } else if (xmode == 3) {
          #pragma unroll
          for (int j = 0; j < 8; ++j)
            xv[j] = rowok ? ((const u16*)X)[(size_t)(kb + xkk + j) * HWP + xoff]
                          : (u16)0;
        } else {
          #pragma unroll
          for (int j = 0; j < 8; ++j) {
            int kk = xkk + j;
            float v = rowok ? ldsel(X, (size_t)(kb + kk) * HWP + xoff, xbf) : 0.f;
            xv[j] = f2b(v);
          }
        }
        *(u16x8*)&Xs[pl][xkk] = xv;
      }
      __syncthreads();
      #pragma unroll
      for (int ks = 0; ks < 2; ++ks) {
        s16x8 aw = *(const s16x8*)&Ws[oq + frow][ks * 32 + kgrp];
        s16x8 ax = *(const s16x8*)&Xs[pq + frow][ks * 32 + kgrp];
        acc = mfma16(aw, ax, acc);
      }
    }
  }
  // D mapping (verified): col = lane&15 -> p, row = (lane>>4)*4+r -> o
  int orow = (lane >> 4) * 4;
  int ogb = o0 + oq + orow;
  int pg = p0 + pq + frow;
  if (OMODE == 4) {
    float* Yp = (float*)Y + (size_t)sz * O * HWP;
    #pragma unroll
    for (int r = 0; r < 4; ++r)
      Yp[(size_t)(ogb + r) * HWP + pg] = acc[r];
  } else if (OMODE == 2) {
    u16x4 st;
    #pragma unroll
    for (int r = 0; r < 4; ++r) {
      float yv = acc[r] + ldsel(bias, bias_off + ogb + r, wbf);
      if (ACT == 1) yv = (yv >= 0.f) ? yv : 0.2f * yv;
      if (ADDIN) yv += b2f(addin[(size_t)(ogb + r) * HWP + pg]);
      st[r] = f2b(yv);
    }
    *(u16x4*)&((u16*)Y)[(size_t)pg * O + ogb] = st;
  } else {
    #pragma unroll
    for (int r = 0; r < 4; ++r) {
      int og = ogb + r;
      float yv = acc[r] + ldsel(bias, bias_off + og, wbf);
      if (ACT == 1) yv = (yv >= 0.f) ? yv : 0.2f * yv;
      if (ADDIN) yv += b2f(addin[(size_t)og * HWP + pg]);
      if (OMODE == 3) ((u16*)Y)[(size_t)og * HWP + pg] = f2b(yv);
      else stsel(Y, (size_t)og * HWP + pg, yv, (OMODE == 1) && wbf);
    }
  }
}

// ---------- combine 3 fp32 partials + bias + lrelu -> bf16 [128][HW] ----------
__global__ __launch_bounds__(256)
void comb3_lrelu_k(const float* __restrict__ P, const void* __restrict__ bias,
                   u16* __restrict__ Y, const float* __restrict__ dflag) {
  bool bf = dflag[0] > 0.5f;
  int gid = blockIdx.x * 256 + threadIdx.x;   // 128*HWP
  int o = gid / HWP;
  float v = P[gid] + P[gid + 128 * HWP] + P[gid + 2 * 128 * HWP] +
            ldsel(bias, o, bf);
  v = (v >= 0.f) ? v : 0.2f * v;
  Y[gid] = f2b(v);
}

// ---------- combine 2 fp32 partials + bias -> flag-dtype [256][HW] ----------
__global__ __launch_bounds__(256)
void comb2_out_k(const float* __restrict__ P, const void* __restrict__ bias,
                 void* __restrict__ Y, const float* __restrict__ dflag) {
  bool bf = dflag[0] > 0.5f;
  int gid = blockIdx.x * 256 + threadIdx.x;   // 256*HWP
  int o = gid / HWP;
  float v = P[gid] + P[gid + 256 * HWP] + ldsel(bias, o, bf);
  stsel(Y, gid, v, bf);
}

// ---------- 1x1 conv 128 -> 9 + softmax (bf16 hid in, bf16 out) ----------
template<bool DELTA>
__global__ __launch_bounds__(256)
void pw9_v2_k(const void* __restrict__ w2, const void* __restrict__ b2,
              const u16* __restrict__ hid, u16* __restrict__ out9,
              const float* __restrict__ dflag) {
  bool bf = dflag[0] > 0.5f;
  __shared__ float Wl[9][128];
  __shared__ float Pl[4][9][33];
  int tid = threadIdx.x;
  for (int i = tid; i < 1152; i += 256) Wl[i >> 7][i & 127] = ldsel(w2, i, bf);
  __syncthreads();
  int pix = tid & 31, cig = tid >> 5;        // 8 groups x 16 ci
  int p = blockIdx.x * 32 + pix;
  int ci0 = cig * 16;
  float acc[9] = {0.f, 0.f, 0.f, 0.f, 0.f, 0.f, 0.f, 0.f, 0.f};
  #pragma unroll
  for (int j = 0; j < 16; ++j) {
    float xv = b2f(hid[(size_t)(ci0 + j) * HWP + p]);
    #pragma unroll
    for (int t = 0; t < 9; ++t) acc[t] += Wl[t][ci0 + j] * xv;
  }
  #pragma unroll
  for (int t = 0; t < 9; ++t) acc[t] += __shfl_xor(acc[t], 32);
  int wv = tid >> 6;
  if ((tid & 63) < 32) {
    #pragma unroll
    for (int t = 0; t < 9; ++t) Pl[wv][t][pix] = acc[t];
  }
  __syncthreads();
  if (tid < 32) {
    float a[9];
    #pragma unroll
    for (int t = 0; t < 9; ++t)
      a[t] = Pl[0][t][pix] + Pl[1][t][pix] + Pl[2][t][pix] + Pl[3][t][pix] +
             ldsel(b2, t, bf);
    float mx = a[0];
    #pragma unroll
    for (int t = 1; t < 9; ++t) mx = fmaxf(mx, a[t]);
    float s = 0.f;
    #pragma unroll
    for (int t = 0; t < 9; ++t) { a[t] = __expf(a[t] - mx); s += a[t]; }
    float inv = 1.f / s;
    #pragma unroll
    for (int t = 0; t < 9; ++t) {
      float v = a[t] * inv;
      if (DELTA) v = ((t == 4) ? 1.f : 0.f) - v;
      out9[(size_t)t * HWP + p] = f2b(v);
    }
  }
}

// ---------- spatially-varying 3x3 filter (bf16 w9, bf16 out) ----------
template<bool HIGH>
__global__ __launch_bounds__(256)
void spatial_filter_k(const void* x, const u16* __restrict__ w9,
                      u16* __restrict__ y, const float* dflag) {
  bool bf = dflag[0] > 0.5f;
  int gid = blockIdx.x * 256 + threadIdx.x;
  int c = gid / HWP, p = gid - c * HWP;
  int h = p / WWC, w = p - h * WWC;
  float acc = HIGH ? ldsel(x, gid, bf) : 0.f;
  #pragma unroll
  for (int t = 0; t < 9; ++t) {
    int dh = t / 3 - 1, dw = t % 3 - 1;
    int hh = h + dh, ww = w + dw;
    if (hh >= 0 && hh < HH && ww >= 0 && ww < WWC)
      acc += ldsel(x, c * HWP + hh * WWC + ww, bf) * b2f(w9[t * HWP + p]);
  }
  y[gid] = f2b(acc);
}

// ---------- flash attention partial (proven R13/R15 structure) ----------
__global__ __launch_bounds__(256)
void attn_part_k(const u16* __restrict__ Qb, const u16* __restrict__ Kb,
                 const u16* __restrict__ Vb, u16* __restrict__ Op,
                 float* __restrict__ Lb) {
  __shared__ u16 Ks[64][40];
  __shared__ u16 Vs[32][72];      // [d][m] linear
  __shared__ u16 Ps[4][16][72];   // per-wave P tile [q][m]
  int h = blockIdx.y, n0 = blockIdx.x * 64, sz = blockIdx.z;
  int tid = threadIdx.x, lane = tid & 63, wv = tid >> 6;
  int frow = lane & 15, gq = lane >> 4, kgrp = gq * 8;
  int ml = tid >> 2, dseg = (tid & 3) * 8;     // K staging: [64 m][32 d]
  int vd = tid >> 3, vm = (tid & 7) * 8;       // V staging: [32 d][64 m]
  const float QS = 0.17677669529663687f * 1.4426950408889634f;  // scale*log2e
  s16x8 aq;
  {
    u16x8 qv = *(const u16x8*)&Qb[(size_t)(n0 + wv * 16 + frow) * 256 + h * 32 + kgrp];
    u16x8 qs;
    #pragma unroll
    for (int j = 0; j < 8; ++j) qs[j] = f2b(b2f(qv[j]) * QS);
    aq = *(s16x8*)&qs;
  }
  f32x4 oa0 = {0.f, 0.f, 0.f, 0.f}, oa1 = {0.f, 0.f, 0.f, 0.f};
  float lsum = 0.f;
  int t_begin = (49 * sz) / NSPLIT, t_end = (49 * (sz + 1)) / NSPLIT;
  u16x8 kreg = *(const u16x8*)&Kb[(size_t)(t_begin * 64 + ml) * 256 + h * 32 + dseg];
  u16x8 vreg = *(const u16x8*)&Vb[(size_t)(h * 32 + vd) * HWP + t_begin * 64 + vm];
  for (int t = t_begin; t < t_end; ++t) {
    __syncthreads();
    *(u16x8*)&Ks[ml][dseg] = kreg;
    *(u16x8*)&Vs[vd][vm] = vreg;
    if (t + 1 < t_end) {
      kreg = *(const u16x8*)&Kb[(size_t)((t + 1) * 64 + ml) * 256 + h * 32 + dseg];
      vreg = *(const u16x8*)&Vb[(size_t)(h * 32 + vd) * HWP + (t + 1) * 64 + vm];
    }
    __syncthreads();
    f32x4 zero = {0.f, 0.f, 0.f, 0.f};
    #pragma unroll
    for (int fm = 0; fm < 4; ++fm) {
      s16x8 ak = *(const s16x8*)&Ks[fm * 16 + frow][kgrp];
      f32x4 s = mfma16(ak, aq, zero);       // D[m][q]: rows=m, col=q=frow
      u16x4 pe;
      #pragma unroll
      for (int r = 0; r < 4; ++r) {
        float e = exp2f(fminf(s[r], 43.f));
        lsum += e;
        pe[r] = (u16)(__float_as_uint(e) >> 16);  // trunc-to-bf16 (P in (0,1])
      }
      *(u16x4*)&Ps[wv][frow][fm * 16 + gq * 4] = pe;
    }
    #pragma unroll
    for (int ks = 0; ks < 2; ++ks) {
      s16x8 ap = *(const s16x8*)&Ps[wv][frow][ks * 32 + kgrp];
      s16x8 bv0 = *(const s16x8*)&Vs[frow][ks * 32 + kgrp];
      s16x8 bv1 = *(const s16x8*)&Vs[16 + frow][ks * 32 + kgrp];
      oa0 = mfma16(ap, bv0, oa0);
      oa1 = mfma16(ap, bv1, oa1);
    }
  }
  lsum += __shfl_xor(lsum, 16);
  lsum += __shfl_xor(lsum, 32);
  if (lane < 16)
    Lb[(size_t)(sz * 8 + h) * HWP + n0 + wv * 16 + frow] = lsum;
  #pragma unroll
  for (int r = 0; r < 4; ++r) {
    int n = n0 + wv * 16 + gq * 4 + r;
    Op[(size_t)(sz * 256 + h * 32 + frow) * HWP + n]      = f2b(oa0[r]);
    Op[(size_t)(sz * 256 + h * 32 + 16 + frow) * HWP + n] = f2b(oa1[r]);
  }
}

// ---------- combine NSPLIT attention partials -> bf16 [C][HW] ----------
__global__ __launch_bounds__(256)
void attn_combine_k(const u16* __restrict__ Op, const float* __restrict__ Lb,
                    u16* __restrict__ A) {
  int gid = blockIdx.x * 256 + threadIdx.x;   // 802816
  int n = gid % HWP, hd = gid / HWP, h = hd >> 5;
  float L = 0.f, O = 0.f;
  #pragma unroll
  for (int s = 0; s < NSPLIT; ++s) {
    L += Lb[(size_t)(s * 8 + h) * HWP + n];
    O += b2f(Op[(size_t)(s * 256 + hd) * HWP + n]);
  }
  A[(size_t)hd * HWP + n] = f2b(O / L);
}

extern "C" void kernel_launch(void* const* d_in, const int* in_sizes, int n_in,
                              void* d_out, int out_size, void* d_ws, size_t ws_size,
                              hipStream_t stream) {
  const void* dec   = d_in[0];
  const void* enc   = d_in[1];
  const void* dw_w  = d_in[2];
  const void* dw_b  = d_in[3];
  const void* p1_w  = d_in[4];
  const void* p1_b  = d_in[5];
  const void* p2_w  = d_in[6];
  const void* p2_b  = d_in[7];
  const void* c1_w  = d_in[8];
  const void* c1_b  = d_in[9];
  const void* c2_w  = d_in[10];
  const void* c2_b  = d_in[11];
  const void* q_w   = d_in[12];
  const void* q_b   = d_in[13];
  const void* kv_w  = d_in[14];
  const void* kv_b  = d_in[15];
  const void* out_w = d_in[16];
  const void* out_b = d_in[17];
  const void* fu_w  = d_in[18];
  const void* fu_b  = d_in[19];

  const int CH = CC * HWP;     // 802816
  float* flag = (float*)d_ws;                       // 8 floats
  u16* pk     = (u16*)(flag + 8);
  u16* A      = pk;              pk += CH;            // dwconv out / attn out, bf16 [C][HW]
  u16* hid    = pk;              pk += 128 * HWP;     // bf16 [128][HW]
  u16* s9     = pk;              pk += 9 * HWP;       // bf16 [9][HW]
  u16* Bb     = pk;              pk += CH;            // f_smooth / f_high, bf16 [C][HW]
  u16* qb16   = pk;              pk += CH;            // q bf16 [n][256]; later fused_in [p][256]
  u16* k16    = pk;              pk += CH;            // K bf16 [m][256]
  u16* v16    = pk;              pk += CH;            // V bf16 [d][HWP]
  u16* wp_p1  = pk;              pk += 128 * 256;
  u16* wp_q   = pk;              pk += 256 * 256;
  u16* wp_kv  = pk;              pk += 512 * 256;
  u16* wp_out = pk;              pk += 256 * 256;
  u16* wp_c1  = pk;              pk += 128 * 256 * 9;
  u16* wp_fu  = pk;              pk += 256 * 256 * 9;
  pk += (size_t)(-(intptr_t)pk) & 7;                  // align to 4 floats
  float* Lb   = (float*)pk;                           // 32*HWP f32
  u16* Opart  = (u16*)(Lb + 32 * HWP);                // 1024*HWP u16
  // conv split-K partials ALIAS the attn Lb/Opart region (6.8 MB):
  //   c1: 3*128*HWP f32 = 4.8 MB (written after attn_combine consumed Lb/Opart)
  //   fu: 2*256*HWP f32 = 6.4 MB (written after comb3_lrelu consumed c1 partials)
  float* Pc = Lb;

  dim3 blk(256);
  detect_dtype_k<<<1, blk, 0, stream>>>(dec, flag);

  // ---- pack ALL weights (one launch) ----
  pack_all_k<<<1536, blk, 0, stream>>>(p1_w, q_w, kv_w, out_w, c1_w, fu_w,
                                       wp_p1, wp_q, wp_kv, wp_out, wp_c1, wp_fu,
                                       flag);

  // ---- ALPF: kw = softmax(p2(lrelu(p1(dw(dec))))) ----
  dwconv_k<<<3136, blk, 0, stream>>>(dec, dw_w, dw_b, A, flag);
  mgemm32_k<1, 1, false, 3><<<dim3(98, 4), blk, 0, stream>>>(
      wp_p1, A, p1_b, nullptr, hid, 256, flag, 3, 0);
  pw9_v2_k<false><<<98, blk, 0, stream>>>(p2_w, p2_b, hid, s9, flag);
  spatial_filter_k<false><<<3136, blk, 0, stream>>>(dec, s9, Bb, flag);

  // ---- q / k / v projections ----
  mgemm32_k<1, 0, false, 2><<<dim3(98, 8), blk, 0, stream>>>(
      wp_q, Bb, q_b, nullptr, qb16, 256, flag, 3, 0);
  mgemm32_k<1, 0, false, 2><<<dim3(98, 8), blk, 0, stream>>>(
      wp_kv, enc, kv_b, nullptr, k16, 256, flag, 1, 0);
  mgemm32_k<1, 0, false, 3><<<dim3(98, 8), blk, 0, stream>>>(
      wp_kv + 256 * 256, enc, kv_b, nullptr, v16, 256, flag, 1, 256);

  // ---- attention: 4-way KV-split partials + combine ----
  attn_part_k<<<dim3(49, 8, NSPLIT), blk, 0, stream>>>(qb16, k16, v16, Opart, Lb);
  attn_combine_k<<<3136, blk, 0, stream>>>(Opart, Lb, A);

  // ---- AHPF: c1 conv as 3-way tap-split + combine ----
  mgemm32_k<9, 1, false, 4><<<dim3(98, 4, 3), blk, 0, stream>>>(
      wp_c1, enc, nullptr, nullptr, Pc, 256, flag, 1, 0);
  comb3_lrelu_k<<<1568, blk, 0, stream>>>(Pc, c1_b, hid, flag);
  pw9_v2_k<true><<<98, blk, 0, stream>>>(c2_w, c2_b, hid, s9, flag);
  spatial_filter_k<true><<<3136, blk, 0, stream>>>(enc, s9, Bb, flag);

  // ---- out proj + f_high add -> bf16 [p][256] (reuses qb16, q is dead) ----
  mgemm32_k<1, 0, true, 2><<<dim3(98, 8), blk, 0, stream>>>(
      wp_out, A, out_b, Bb, qb16, 256, flag, 3, 0);

  // ---- fusion 3x3 conv: 2-way tap-split + combine -> d_out ----
  mgemm32_k<9, 0, false, 4><<<dim3(98, 8, 2), blk, 0, stream>>>(
      wp_fu, qb16, nullptr, nullptr, Pc, 256, flag, 2, 0);
  comb2_out_k<<<3136, blk, 0, stream>>>(Pc, fu_b, d_out, flag);
}

// Round 17
// 161.915 us; speedup vs baseline: 1.5015x; 1.0440x over previous
//
#include <hip/hip_runtime.h>
#include <hip/hip_bf16.h>

#define HH  56
#define WWC 56
#define HWP 3136   // 56*56 = 49*64
#define CC  256
#define NSPLIT 4

typedef unsigned short u16;
typedef __attribute__((ext_vector_type(8))) u16 u16x8;
typedef __attribute__((ext_vector_type(4))) u16 u16x4;
typedef __attribute__((ext_vector_type(8))) short s16x8;   // bf16x8 MFMA frag
typedef __attribute__((ext_vector_type(4))) float f32x4;

__device__ __forceinline__ u16 f2b(float f) {
  unsigned int x = __float_as_uint(f);
  return (u16)((x + 0x7fffu + ((x >> 16) & 1u)) >> 16);
}
__device__ __forceinline__ float b2f(u16 u) {
  return __uint_as_float(((unsigned int)u) << 16);
}
__device__ __forceinline__ f32x4 mfma16(s16x8 a, s16x8 b, f32x4 c) {
  return __builtin_amdgcn_mfma_f32_16x16x32_bf16(a, b, c, 0, 0, 0);
}

// ---------- dtype-flexible load/store (flag decided on device) ----------
__device__ __forceinline__ float ldsel(const void* p, int i, bool bf) {
  if (bf) return __bfloat162float(((const __hip_bfloat16*)p)[i]);
  return ((const float*)p)[i];
}
__device__ __forceinline__ void stsel(void* p, int i, float v, bool bf) {
  if (bf) ((__hip_bfloat16*)p)[i] = __float2bfloat16(v);
  else ((float*)p)[i] = v;
}

// load 8 consecutive elements (index 8-aligned) as floats, dtype per flag
__device__ __forceinline__ void ldrow8(const void* p, size_t i, bool bf,
                                       float* o) {
  if (bf) {
    u16x8 v = *(const u16x8*)((const u16*)p + i);
    #pragma unroll
    for (int j = 0; j < 8; ++j) o[j] = b2f(v[j]);
  } else {
    const float* f = (const float*)p + i;
    f32x4 a = *(const f32x4*)f;
    f32x4 b = *(const f32x4*)(f + 4);
    #pragma unroll
    for (int j = 0; j < 4; ++j) { o[j] = a[j]; o[4 + j] = b[j]; }
  }
}

__global__ void detect_dtype_k(const void* x, float* flag) {
  __shared__ int sh[256];
  int tid = threadIdx.x;
  const __hip_bfloat16* xb = (const __hip_bfloat16*)x;
  int ok = 0;
  for (int i = tid; i < 1024; i += 256) {
    float v = fabsf(__bfloat162float(xb[2 * i]));
    if (v > 9.5e-7f && v < 1.05e6f) ok++;
  }
  sh[tid] = ok;
  __syncthreads();
  for (int s = 128; s > 0; s >>= 1) {
    if (tid < s) sh[tid] += sh[tid + s];
    __syncthreads();
  }
  if (tid == 0) flag[0] = (sh[0] > 512) ? 1.f : 0.f;
}

// ---------- fused weight pack: all 6 weights in ONE launch ----------
__global__ __launch_bounds__(256)
void pack_all_k(const void* __restrict__ p1, const void* __restrict__ q,
                const void* __restrict__ kv, const void* __restrict__ ow,
                const void* __restrict__ c1, const void* __restrict__ fu,
                u16* __restrict__ d_p1, u16* __restrict__ d_q,
                u16* __restrict__ d_kv, u16* __restrict__ d_ow,
                u16* __restrict__ d_c1, u16* __restrict__ d_fu,
                const float* __restrict__ dflag) {
  bool bf = dflag[0] > 0.5f;
  int b = blockIdx.x, tid = threadIdx.x;
  if (b < 128) { int g = b * 256 + tid; d_p1[g] = f2b(ldsel(p1, g, bf)); return; }
  b -= 128;
  if (b < 256) { int g = b * 256 + tid; d_q[g] = f2b(ldsel(q, g, bf)); return; }
  b -= 256;
  if (b < 512) { int g = b * 256 + tid; d_kv[g] = f2b(ldsel(kv, g, bf)); return; }
  b -= 512;
  if (b < 256) { int g = b * 256 + tid; d_ow[g] = f2b(ldsel(ow, g, bf)); return; }
  b -= 256;
  if (b < 128) {
    int g = b * 256 + tid;
    #pragma unroll
    for (int t = 0; t < 9; ++t)
      d_c1[(size_t)t * 32768 + g] = f2b(ldsel(c1, g * 9 + t, bf));
    return;
  }
  b -= 128;
  {
    int g = b * 256 + tid;
    #pragma unroll
    for (int t = 0; t < 9; ++t)
      d_fu[(size_t)t * 65536 + g] = f2b(ldsel(fu, g * 9 + t, bf));
  }
}

// ---------- depthwise 3x3 conv, 8 pixels/thread vectorized -> bf16 [C][HW] ----------
__global__ __launch_bounds__(128)
void dwconv_v2_k(const void* __restrict__ x, const void* __restrict__ wt,
                 const void* __restrict__ bs, u16* __restrict__ y,
                 const float* __restrict__ dflag) {
  bool bf = dflag[0] > 0.5f;
  int gid = blockIdx.x * 128 + threadIdx.x;   // 100352 = C*HWP/8
  int c = gid / 392, g = gid - c * 392;
  int p0 = g * 8;
  int h = p0 / WWC, w0 = p0 - h * WWC;        // w0 in {0,8,...,48}
  float wv[9];
  #pragma unroll
  for (int t = 0; t < 9; ++t) wv[t] = ldsel(wt, c * 9 + t, bf);
  float bv = ldsel(bs, c, bf);
  float acc[8];
  #pragma unroll
  for (int j = 0; j < 8; ++j) acc[j] = bv;
  const size_t cbase = (size_t)c * HWP;
  #pragma unroll
  for (int dh = -1; dh <= 1; ++dh) {
    int hh = h + dh;
    if (hh < 0 || hh >= HH) continue;
    size_t rbase = cbase + hh * WWC + w0;
    float v[8];
    ldrow8(x, rbase, bf, v);
    float lft = (w0 > 0) ? ldsel(x, rbase - 1, bf) : 0.f;
    float rgt = (w0 < 48) ? ldsel(x, rbase + 8, bf) : 0.f;
    float wm = wv[(dh + 1) * 3 + 0], wc = wv[(dh + 1) * 3 + 1],
          wp = wv[(dh + 1) * 3 + 2];
    #pragma unroll
    for (int j = 0; j < 8; ++j) {
      float vm = (j == 0) ? lft : v[j - 1];
      float vp = (j == 7) ? rgt : v[j + 1];
      acc[j] += vm * wm + v[j] * wc + vp * wp;
    }
  }
  u16x8 st;
  #pragma unroll
  for (int j = 0; j < 8; ++j) st[j] = f2b(acc[j]);
  *(u16x8*)&y[cbase + p0] = st;
}

// ---------- MFMA GEMM / conv-as-GEMM, 32x32 tile (all GEMM sites) ----------
// OMODE 0: fp32 Y[o][p]; 1: flag-dtype Y[o][p]; 2: bf16 Y[p][o]; 3: bf16 Y[o][p];
// OMODE 4: fp32 PARTIAL Y[sz][o][p] (no bias/act; taps split over blockIdx.z).
// xmode  0: fp32 X[Cin][HW]; 1: flag X[Cin][HW]; 2: bf16 X[p][Cin]; 3: bf16 X[Cin][HW].
// ADDIN: bf16 [o][HW]. bid swizzle: o0 = bid % NO -> per-XCD weight locality.
template<int TAPS, int ACT, bool ADDIN, int OMODE>
__global__ __launch_bounds__(256)
void mgemm32_k(const u16* __restrict__ Wp, const void* __restrict__ X,
               const void* __restrict__ bias, const u16* __restrict__ addin,
               void* __restrict__ Y, int Cin,
               const float* __restrict__ dflag, int xmode, int bias_off) {
  bool wbf = dflag[0] > 0.5f;
  bool xbf = (xmode == 1) ? wbf : false;
  __shared__ u16 Ws[32][72];   // [o][k]
  __shared__ u16 Xs[32][72];   // [p][k]
  int NO = gridDim.y;
  int O = NO * 32;
  int bid = blockIdx.x + blockIdx.y * gridDim.x;
  int p0 = (bid / NO) * 32, o0 = (bid % NO) * 32;
  int sz = blockIdx.z, NZ = gridDim.z;
  int t0 = (TAPS * sz) / NZ, t1 = (TAPS * (sz + 1)) / NZ;
  int tid = threadIdx.x, lane = tid & 63, wv = tid >> 6;
  int oq = (wv & 1) * 16, pq = (wv >> 1) * 16;
  int frow = lane & 15, kgrp = (lane >> 4) * 8;
  int wol = tid >> 3, wkk = (tid & 7) * 8;       // W: 32 rows x 64 k
  int pl = tid & 31, xkk = (tid >> 5) * 8;       // X: 32 rows x 64 k
  int p = p0 + pl, h = p / WWC, w = p - h * WWC;
  f32x4 acc = {0.f, 0.f, 0.f, 0.f};
  for (int t = t0; t < t1; ++t) {
    int dh = t / 3 - 1, dw = t % 3 - 1;
    int hh = h + dh, ww = w + dw;
    bool rowok = (TAPS == 1) || ((hh >= 0) && (hh < HH) && (ww >= 0) && (ww < WWC));
    int xoff = (TAPS == 1) ? p : hh * WWC + ww;
    const u16* Wrow = Wp + (size_t)t * O * Cin;
    for (int kb = 0; kb < Cin; kb += 64) {
      __syncthreads();
      *(u16x8*)&Ws[wol][wkk] =
          *(const u16x8*)&Wrow[(size_t)(o0 + wol) * Cin + kb + wkk];
      {
        u16x8 xv;
        if (xmode == 2) {
          if (rowok) {
            xv = *(const u16x8*)&((const u16*)X)[(size_t)xoff * Cin + kb + xkk];
          } else {
            #pragma unroll
            for (int j = 0; j < 8; ++j) xv[j] = 0;
          }
        } else if (xmode == 3) {
          #pragma unroll
          for (int j = 0; j < 8; ++j)
            xv[j] = rowok ? ((const u16*)X)[(size_t)(kb + xkk + j) * HWP + xoff]
                          : (u16)0;
        } else {
          #pragma unroll
          for (int j = 0; j < 8; ++j) {
            int kk = xkk + j;
            float v = rowok ? ldsel(X, (size_t)(kb + kk) * HWP + xoff, xbf) : 0.f;
            xv[j] = f2b(v);
          }
        }
        *(u16x8*)&Xs[pl][xkk] = xv;
      }
      __syncthreads();
      #pragma unroll
      for (int ks = 0; ks < 2; ++ks) {
        s16x8 aw = *(const s16x8*)&Ws[oq + frow][ks * 32 + kgrp];
        s16x8 ax = *(const s16x8*)&Xs[pq + frow][ks * 32 + kgrp];
        acc = mfma16(aw, ax, acc);
      }
    }
  }
  // D mapping (verified): col = lane&15 -> p, row = (lane>>4)*4+r -> o
  int orow = (lane >> 4) * 4;
  int ogb = o0 + oq + orow;
  int pg = p0 + pq + frow;
  if (OMODE == 4) {
    float* Yp = (float*)Y + (size_t)sz * O * HWP;
    #pragma unroll
    for (int r = 0; r < 4; ++r)
      Yp[(size_t)(ogb + r) * HWP + pg] = acc[r];
  } else if (OMODE == 2) {
    u16x4 st;
    #pragma unroll
    for (int r = 0; r < 4; ++r) {
      float yv = acc[r] + ldsel(bias, bias_off + ogb + r, wbf);
      if (ACT == 1) yv = (yv >= 0.f) ? yv : 0.2f * yv;
      if (ADDIN) yv += b2f(addin[(size_t)(ogb + r) * HWP + pg]);
      st[r] = f2b(yv);
    }
    *(u16x4*)&((u16*)Y)[(size_t)pg * O + ogb] = st;
  } else {
    #pragma unroll
    for (int r = 0; r < 4; ++r) {
      int og = ogb + r;
      float yv = acc[r] + ldsel(bias, bias_off + og, wbf);
      if (ACT == 1) yv = (yv >= 0.f) ? yv : 0.2f * yv;
      if (ADDIN) yv += b2f(addin[(size_t)og * HWP + pg]);
      if (OMODE == 3) ((u16*)Y)[(size_t)og * HWP + pg] = f2b(yv);
      else stsel(Y, (size_t)og * HWP + pg, yv, (OMODE == 1) && wbf);
    }
  }
}

// ---------- combine 3 fp32 partials + bias + lrelu -> bf16 [128][HW] ----------
__global__ __launch_bounds__(256)
void comb3_lrelu_k(const float* __restrict__ P, const void* __restrict__ bias,
                   u16* __restrict__ Y, const float* __restrict__ dflag) {
  bool bf = dflag[0] > 0.5f;
  int gid = blockIdx.x * 256 + threadIdx.x;   // 128*HWP
  int o = gid / HWP;
  float v = P[gid] + P[gid + 128 * HWP] + P[gid + 2 * 128 * HWP] +
            ldsel(bias, o, bf);
  v = (v >= 0.f) ? v : 0.2f * v;
  Y[gid] = f2b(v);
}

// ---------- combine 2 fp32 partials + bias -> flag-dtype [256][HW] ----------
__global__ __launch_bounds__(256)
void comb2_out_k(const float* __restrict__ P, const void* __restrict__ bias,
                 void* __restrict__ Y, const float* __restrict__ dflag) {
  bool bf = dflag[0] > 0.5f;
  int gid = blockIdx.x * 256 + threadIdx.x;   // 256*HWP
  int o = gid / HWP;
  float v = P[gid] + P[gid + 256 * HWP] + ldsel(bias, o, bf);
  stsel(Y, gid, v, bf);
}

// ---------- 1x1 conv 128 -> 9 + softmax (bf16 hid in, bf16 out) ----------
template<bool DELTA>
__global__ __launch_bounds__(256)
void pw9_v2_k(const void* __restrict__ w2, const void* __restrict__ b2,
              const u16* __restrict__ hid, u16* __restrict__ out9,
              const float* __restrict__ dflag) {
  bool bf = dflag[0] > 0.5f;
  __shared__ float Wl[9][128];
  __shared__ float Pl[4][9][33];
  int tid = threadIdx.x;
  for (int i = tid; i < 1152; i += 256) Wl[i >> 7][i & 127] = ldsel(w2, i, bf);
  __syncthreads();
  int pix = tid & 31, cig = tid >> 5;        // 8 groups x 16 ci
  int p = blockIdx.x * 32 + pix;
  int ci0 = cig * 16;
  float acc[9] = {0.f, 0.f, 0.f, 0.f, 0.f, 0.f, 0.f, 0.f, 0.f};
  #pragma unroll
  for (int j = 0; j < 16; ++j) {
    float xv = b2f(hid[(size_t)(ci0 + j) * HWP + p]);
    #pragma unroll
    for (int t = 0; t < 9; ++t) acc[t] += Wl[t][ci0 + j] * xv;
  }
  #pragma unroll
  for (int t = 0; t < 9; ++t) acc[t] += __shfl_xor(acc[t], 32);
  int wv = tid >> 6;
  if ((tid & 63) < 32) {
    #pragma unroll
    for (int t = 0; t < 9; ++t) Pl[wv][t][pix] = acc[t];
  }
  __syncthreads();
  if (tid < 32) {
    float a[9];
    #pragma unroll
    for (int t = 0; t < 9; ++t)
      a[t] = Pl[0][t][pix] + Pl[1][t][pix] + Pl[2][t][pix] + Pl[3][t][pix] +
             ldsel(b2, t, bf);
    float mx = a[0];
    #pragma unroll
    for (int t = 1; t < 9; ++t) mx = fmaxf(mx, a[t]);
    float s = 0.f;
    #pragma unroll
    for (int t = 0; t < 9; ++t) { a[t] = __expf(a[t] - mx); s += a[t]; }
    float inv = 1.f / s;
    #pragma unroll
    for (int t = 0; t < 9; ++t) {
      float v = a[t] * inv;
      if (DELTA) v = ((t == 4) ? 1.f : 0.f) - v;
      out9[(size_t)t * HWP + p] = f2b(v);
    }
  }
}

// ---------- spatially-varying 3x3 filter, 8 pixels/thread vectorized ----------
template<bool HIGH>
__global__ __launch_bounds__(128)
void spatial_v2_k(const void* __restrict__ x, const u16* __restrict__ w9,
                  u16* __restrict__ y, const float* __restrict__ dflag) {
  bool bf = dflag[0] > 0.5f;
  int gid = blockIdx.x * 128 + threadIdx.x;   // 100352
  int c = gid / 392, g = gid - c * 392;
  int p0 = g * 8;
  int h = p0 / WWC, w0 = p0 - h * WWC;
  const size_t cbase = (size_t)c * HWP;
  float acc[8];
  if (HIGH) {
    ldrow8(x, cbase + p0, bf, acc);
  } else {
    #pragma unroll
    for (int j = 0; j < 8; ++j) acc[j] = 0.f;
  }
  #pragma unroll
  for (int dh = -1; dh <= 1; ++dh) {
    int hh = h + dh;
    if (hh < 0 || hh >= HH) continue;
    size_t rbase = cbase + hh * WWC + w0;
    float v[8];
    ldrow8(x, rbase, bf, v);
    float lft = (w0 > 0) ? ldsel(x, rbase - 1, bf) : 0.f;
    float rgt = (w0 < 48) ? ldsel(x, rbase + 8, bf) : 0.f;
    // per-pixel weights for the three taps of this row
    float wm[8], wc[8], wp[8];
    {
      int tb = (dh + 1) * 3;
      u16x8 a = *(const u16x8*)&w9[(size_t)(tb + 0) * HWP + p0];
      u16x8 b = *(const u16x8*)&w9[(size_t)(tb + 1) * HWP + p0];
      u16x8 d = *(const u16x8*)&w9[(size_t)(tb + 2) * HWP + p0];
      #pragma unroll
      for (int j = 0; j < 8; ++j) { wm[j] = b2f(a[j]); wc[j] = b2f(b[j]); wp[j] = b2f(d[j]); }
    }
    #pragma unroll
    for (int j = 0; j < 8; ++j) {
      float vm = (j == 0) ? lft : v[j - 1];
      float vp = (j == 7) ? rgt : v[j + 1];
      acc[j] += vm * wm[j] + v[j] * wc[j] + vp * wp[j];
    }
  }
  u16x8 st;
  #pragma unroll
  for (int j = 0; j < 8; ++j) st[j] = f2b(acc[j]);
  *(u16x8*)&y[cbase + p0] = st;
}

// ---------- flash attention partial (proven R13/R15 structure) ----------
__global__ __launch_bounds__(256)
void attn_part_k(const u16* __restrict__ Qb, const u16* __restrict__ Kb,
                 const u16* __restrict__ Vb, u16* __restrict__ Op,
                 float* __restrict__ Lb) {
  __shared__ u16 Ks[64][40];
  __shared__ u16 Vs[32][72];      // [d][m] linear
  __shared__ u16 Ps[4][16][72];   // per-wave P tile [q][m]
  int h = blockIdx.y, n0 = blockIdx.x * 64, sz = blockIdx.z;
  int tid = threadIdx.x, lane = tid & 63, wv = tid >> 6;
  int frow = lane & 15, gq = lane >> 4, kgrp = gq * 8;
  int ml = tid >> 2, dseg = (tid & 3) * 8;     // K staging: [64 m][32 d]
  int vd = tid >> 3, vm = (tid & 7) * 8;       // V staging: [32 d][64 m]
  const float QS = 0.17677669529663687f * 1.4426950408889634f;  // scale*log2e
  s16x8 aq;
  {
    u16x8 qv = *(const u16x8*)&Qb[(size_t)(n0 + wv * 16 + frow) * 256 + h * 32 + kgrp];
    u16x8 qs;
    #pragma unroll
    for (int j = 0; j < 8; ++j) qs[j] = f2b(b2f(qv[j]) * QS);
    aq = *(s16x8*)&qs;
  }
  f32x4 oa0 = {0.f, 0.f, 0.f, 0.f}, oa1 = {0.f, 0.f, 0.f, 0.f};
  float lsum = 0.f;
  int t_begin = (49 * sz) / NSPLIT, t_end = (49 * (sz + 1)) / NSPLIT;
  u16x8 kreg = *(const u16x8*)&Kb[(size_t)(t_begin * 64 + ml) * 256 + h * 32 + dseg];
  u16x8 vreg = *(const u16x8*)&Vb[(size_t)(h * 32 + vd) * HWP + t_begin * 64 + vm];
  for (int t = t_begin; t < t_end; ++t) {
    __syncthreads();
    *(u16x8*)&Ks[ml][dseg] = kreg;
    *(u16x8*)&Vs[vd][vm] = vreg;
    if (t + 1 < t_end) {
      kreg = *(const u16x8*)&Kb[(size_t)((t + 1) * 64 + ml) * 256 + h * 32 + dseg];
      vreg = *(const u16x8*)&Vb[(size_t)(h * 32 + vd) * HWP + (t + 1) * 64 + vm];
    }
    __syncthreads();
    f32x4 zero = {0.f, 0.f, 0.f, 0.f};
    #pragma unroll
    for (int fm = 0; fm < 4; ++fm) {
      s16x8 ak = *(const s16x8*)&Ks[fm * 16 + frow][kgrp];
      f32x4 s = mfma16(ak, aq, zero);       // D[m][q]: rows=m, col=q=frow
      u16x4 pe;
      #pragma unroll
      for (int r = 0; r < 4; ++r) {
        float e = exp2f(fminf(s[r], 43.f));
        lsum += e;
        pe[r] = (u16)(__float_as_uint(e) >> 16);  // trunc-to-bf16 (P in (0,1])
      }
      *(u16x4*)&Ps[wv][frow][fm * 16 + gq * 4] = pe;
    }
    #pragma unroll
    for (int ks = 0; ks < 2; ++ks) {
      s16x8 ap = *(const s16x8*)&Ps[wv][frow][ks * 32 + kgrp];
      s16x8 bv0 = *(const s16x8*)&Vs[frow][ks * 32 + kgrp];
      s16x8 bv1 = *(const s16x8*)&Vs[16 + frow][ks * 32 + kgrp];
      oa0 = mfma16(ap, bv0, oa0);
      oa1 = mfma16(ap, bv1, oa1);
    }
  }
  lsum += __shfl_xor(lsum, 16);
  lsum += __shfl_xor(lsum, 32);
  if (lane < 16)
    Lb[(size_t)(sz * 8 + h) * HWP + n0 + wv * 16 + frow] = lsum;
  #pragma unroll
  for (int r = 0; r < 4; ++r) {
    int n = n0 + wv * 16 + gq * 4 + r;
    Op[(size_t)(sz * 256 + h * 32 + frow) * HWP + n]      = f2b(oa0[r]);
    Op[(size_t)(sz * 256 + h * 32 + 16 + frow) * HWP + n] = f2b(oa1[r]);
  }
}

// ---------- combine NSPLIT attention partials -> bf16 [C][HW] ----------
__global__ __launch_bounds__(256)
void attn_combine_k(const u16* __restrict__ Op, const float* __restrict__ Lb,
                    u16* __restrict__ A) {
  int gid = blockIdx.x * 256 + threadIdx.x;   // 802816
  int n = gid % HWP, hd = gid / HWP, h = hd >> 5;
  float L = 0.f, O = 0.f;
  #pragma unroll
  for (int s = 0; s < NSPLIT; ++s) {
    L += Lb[(size_t)(s * 8 + h) * HWP + n];
    O += b2f(Op[(size_t)(s * 256 + hd) * HWP + n]);
  }
  A[(size_t)hd * HWP + n] = f2b(O / L);
}

extern "C" void kernel_launch(void* const* d_in, const int* in_sizes, int n_in,
                              void* d_out, int out_size, void* d_ws, size_t ws_size,
                              hipStream_t stream) {
  const void* dec   = d_in[0];
  const void* enc   = d_in[1];
  const void* dw_w  = d_in[2];
  const void* dw_b  = d_in[3];
  const void* p1_w  = d_in[4];
  const void* p1_b  = d_in[5];
  const void* p2_w  = d_in[6];
  const void* p2_b  = d_in[7];
  const void* c1_w  = d_in[8];
  const void* c1_b  = d_in[9];
  const void* c2_w  = d_in[10];
  const void* c2_b  = d_in[11];
  const void* q_w   = d_in[12];
  const void* q_b   = d_in[13];
  const void* kv_w  = d_in[14];
  const void* kv_b  = d_in[15];
  const void* out_w = d_in[16];
  const void* out_b = d_in[17];
  const void* fu_w  = d_in[18];
  const void* fu_b  = d_in[19];

  const int CH = CC * HWP;     // 802816
  float* flag = (float*)d_ws;                       // 8 floats
  u16* pk     = (u16*)(flag + 8);
  u16* A      = pk;              pk += CH;            // dwconv out / attn out, bf16 [C][HW]
  u16* hid    = pk;              pk += 128 * HWP;     // bf16 [128][HW]
  u16* s9     = pk;              pk += 9 * HWP;       // bf16 [9][HW]
  u16* Bb     = pk;              pk += CH;            // f_smooth / f_high, bf16 [C][HW]
  u16* qb16   = pk;              pk += CH;            // q bf16 [n][256]; later fused_in [p][256]
  u16* k16    = pk;              pk += CH;            // K bf16 [m][256]
  u16* v16    = pk;              pk += CH;            // V bf16 [d][HWP]
  u16* wp_p1  = pk;              pk += 128 * 256;
  u16* wp_q   = pk;              pk += 256 * 256;
  u16* wp_kv  = pk;              pk += 512 * 256;
  u16* wp_out = pk;              pk += 256 * 256;
  u16* wp_c1  = pk;              pk += 128 * 256 * 9;
  u16* wp_fu  = pk;              pk += 256 * 256 * 9;
  pk += (size_t)(-(intptr_t)pk) & 7;                  // align to 4 floats
  float* Lb   = (float*)pk;                           // 32*HWP f32
  u16* Opart  = (u16*)(Lb + 32 * HWP);                // 1024*HWP u16
  // conv split-K partials ALIAS the attn Lb/Opart region (6.8 MB):
  //   c1: 3*128*HWP f32 = 4.8 MB (after attn_combine consumed Lb/Opart)
  //   fu: 2*256*HWP f32 = 6.4 MB (after comb3_lrelu consumed c1 partials)
  float* Pc = Lb;

  dim3 blk(256);
  detect_dtype_k<<<1, blk, 0, stream>>>(dec, flag);

  // ---- pack ALL weights (one launch) ----
  pack_all_k<<<1536, blk, 0, stream>>>(p1_w, q_w, kv_w, out_w, c1_w, fu_w,
                                       wp_p1, wp_q, wp_kv, wp_out, wp_c1, wp_fu,
                                       flag);

  // ---- ALPF: kw = softmax(p2(lrelu(p1(dw(dec))))) ----
  dwconv_v2_k<<<784, dim3(128), 0, stream>>>(dec, dw_w, dw_b, A, flag);
  mgemm32_k<1, 1, false, 3><<<dim3(98, 4), blk, 0, stream>>>(
      wp_p1, A, p1_b, nullptr, hid, 256, flag, 3, 0);
  pw9_v2_k<false><<<98, blk, 0, stream>>>(p2_w, p2_b, hid, s9, flag);
  spatial_v2_k<false><<<784, dim3(128), 0, stream>>>(dec, s9, Bb, flag);

  // ---- q / k / v projections ----
  mgemm32_k<1, 0, false, 2><<<dim3(98, 8), blk, 0, stream>>>(
      wp_q, Bb, q_b, nullptr, qb16, 256, flag, 3, 0);
  mgemm32_k<1, 0, false, 2><<<dim3(98, 8), blk, 0, stream>>>(
      wp_kv, enc, kv_b, nullptr, k16, 256, flag, 1, 0);
  mgemm32_k<1, 0, false, 3><<<dim3(98, 8), blk, 0, stream>>>(
      wp_kv + 256 * 256, enc, kv_b, nullptr, v16, 256, flag, 1, 256);

  // ---- attention: 4-way KV-split partials + combine ----
  attn_part_k<<<dim3(49, 8, NSPLIT), blk, 0, stream>>>(qb16, k16, v16, Opart, Lb);
  attn_combine_k<<<3136, blk, 0, stream>>>(Opart, Lb, A);

  // ---- AHPF: c1 conv as 3-way tap-split + combine ----
  mgemm32_k<9, 1, false, 4><<<dim3(98, 4, 3), blk, 0, stream>>>(
      wp_c1, enc, nullptr, nullptr, Pc, 256, flag, 1, 0);
  comb3_lrelu_k<<<1568, blk, 0, stream>>>(Pc, c1_b, hid, flag);
  pw9_v2_k<true><<<98, blk, 0, stream>>>(c2_w, c2_b, hid, s9, flag);
  spatial_v2_k<true><<<784, dim3(128), 0, stream>>>(enc, s9, Bb, flag);

  // ---- out proj + f_high add -> bf16 [p][256] (reuses qb16, q is dead) ----
  mgemm32_k<1, 0, true, 2><<<dim3(98, 8), blk, 0, stream>>>(
      wp_out, A, out_b, Bb, qb16, 256, flag, 3, 0);

  // ---- fusion 3x3 conv: 2-way tap-split + combine -> d_out ----
  mgemm32_k<9, 0, false, 4><<<dim3(98, 8, 2), blk, 0, stream>>>(
      wp_fu, qb16, nullptr, nullptr, Pc, 256, flag, 2, 0);
  comb2_out_k<<<3136, blk, 0, stream>>>(Pc, fu_b, d_out, flag);
}

// Round 18
// 154.154 us; speedup vs baseline: 1.5771x; 1.0503x over previous
//
#include <hip/hip_runtime.h>
#include <hip/hip_bf16.h>

#define HH  56
#define WWC 56
#define HWP 3136   // 56*56 = 49*64
#define CC  256
#define NSPLIT 6

typedef unsigned short u16;
typedef __attribute__((ext_vector_type(8))) u16 u16x8;
typedef __attribute__((ext_vector_type(4))) u16 u16x4;
typedef __attribute__((ext_vector_type(8))) short s16x8;   // bf16x8 MFMA frag
typedef __attribute__((ext_vector_type(4))) float f32x4;

__device__ __forceinline__ u16 f2b(float f) {
  unsigned int x = __float_as_uint(f);
  return (u16)((x + 0x7fffu + ((x >> 16) & 1u)) >> 16);
}
__device__ __forceinline__ float b2f(u16 u) {
  return __uint_as_float(((unsigned int)u) << 16);
}
__device__ __forceinline__ f32x4 mfma16(s16x8 a, s16x8 b, f32x4 c) {
  return __builtin_amdgcn_mfma_f32_16x16x32_bf16(a, b, c, 0, 0, 0);
}

// ---------- dtype-flexible load/store (flag decided on device) ----------
__device__ __forceinline__ float ldsel(const void* p, int i, bool bf) {
  if (bf) return __bfloat162float(((const __hip_bfloat16*)p)[i]);
  return ((const float*)p)[i];
}
__device__ __forceinline__ void stsel(void* p, int i, float v, bool bf) {
  if (bf) ((__hip_bfloat16*)p)[i] = __float2bfloat16(v);
  else ((float*)p)[i] = v;
}

// load 8 consecutive elements (index 8-aligned) as floats, dtype per flag
__device__ __forceinline__ void ldrow8(const void* p, size_t i, bool bf,
                                       float* o) {
  if (bf) {
    u16x8 v = *(const u16x8*)((const u16*)p + i);
    #pragma unroll
    for (int j = 0; j < 8; ++j) o[j] = b2f(v[j]);
  } else {
    const float* f = (const float*)p + i;
    f32x4 a = *(const f32x4*)f;
    f32x4 b = *(const f32x4*)(f + 4);
    #pragma unroll
    for (int j = 0; j < 4; ++j) { o[j] = a[j]; o[4 + j] = b[j]; }
  }
}

__global__ void detect_dtype_k(const void* x, float* flag) {
  __shared__ int sh[256];
  int tid = threadIdx.x;
  const __hip_bfloat16* xb = (const __hip_bfloat16*)x;
  int ok = 0;
  for (int i = tid; i < 1024; i += 256) {
    float v = fabsf(__bfloat162float(xb[2 * i]));
    if (v > 9.5e-7f && v < 1.05e6f) ok++;
  }
  sh[tid] = ok;
  __syncthreads();
  for (int s = 128; s > 0; s >>= 1) {
    if (tid < s) sh[tid] += sh[tid + s];
    __syncthreads();
  }
  if (tid == 0) flag[0] = (sh[0] > 512) ? 1.f : 0.f;
}

// ---------- fused weight pack: all 6 weights in ONE launch ----------
__global__ __launch_bounds__(256)
void pack_all_k(const void* __restrict__ p1, const void* __restrict__ q,
                const void* __restrict__ kv, const void* __restrict__ ow,
                const void* __restrict__ c1, const void* __restrict__ fu,
                u16* __restrict__ d_p1, u16* __restrict__ d_q,
                u16* __restrict__ d_kv, u16* __restrict__ d_ow,
                u16* __restrict__ d_c1, u16* __restrict__ d_fu,
                const float* __restrict__ dflag) {
  bool bf = dflag[0] > 0.5f;
  int b = blockIdx.x, tid = threadIdx.x;
  if (b < 128) { int g = b * 256 + tid; d_p1[g] = f2b(ldsel(p1, g, bf)); return; }
  b -= 128;
  if (b < 256) { int g = b * 256 + tid; d_q[g] = f2b(ldsel(q, g, bf)); return; }
  b -= 256;
  if (b < 512) { int g = b * 256 + tid; d_kv[g] = f2b(ldsel(kv, g, bf)); return; }
  b -= 512;
  if (b < 256) { int g = b * 256 + tid; d_ow[g] = f2b(ldsel(ow, g, bf)); return; }
  b -= 256;
  if (b < 128) {
    int g = b * 256 + tid;
    #pragma unroll
    for (int t = 0; t < 9; ++t)
      d_c1[(size_t)t * 32768 + g] = f2b(ldsel(c1, g * 9 + t, bf));
    return;
  }
  b -= 128;
  {
    int g = b * 256 + tid;
    #pragma unroll
    for (int t = 0; t < 9; ++t)
      d_fu[(size_t)t * 65536 + g] = f2b(ldsel(fu, g * 9 + t, bf));
  }
}

// ---------- depthwise 3x3 conv, 8 pixels/thread vectorized -> bf16 [C][HW] ----------
__global__ __launch_bounds__(128)
void dwconv_v2_k(const void* __restrict__ x, const void* __restrict__ wt,
                 const void* __restrict__ bs, u16* __restrict__ y,
                 const float* __restrict__ dflag) {
  bool bf = dflag[0] > 0.5f;
  int gid = blockIdx.x * 128 + threadIdx.x;   // 100352 = C*HWP/8
  int c = gid / 392, g = gid - c * 392;
  int p0 = g * 8;
  int h = p0 / WWC, w0 = p0 - h * WWC;        // w0 in {0,8,...,48}
  float wv[9];
  #pragma unroll
  for (int t = 0; t < 9; ++t) wv[t] = ldsel(wt, c * 9 + t, bf);
  float bv = ldsel(bs, c, bf);
  float acc[8];
  #pragma unroll
  for (int j = 0; j < 8; ++j) acc[j] = bv;
  const size_t cbase = (size_t)c * HWP;
  #pragma unroll
  for (int dh = -1; dh <= 1; ++dh) {
    int hh = h + dh;
    if (hh < 0 || hh >= HH) continue;
    size_t rbase = cbase + hh * WWC + w0;
    float v[8];
    ldrow8(x, rbase, bf, v);
    float lft = (w0 > 0) ? ldsel(x, rbase - 1, bf) : 0.f;
    float rgt = (w0 < 48) ? ldsel(x, rbase + 8, bf) : 0.f;
    float wm = wv[(dh + 1) * 3 + 0], wc = wv[(dh + 1) * 3 + 1],
          wp = wv[(dh + 1) * 3 + 2];
    #pragma unroll
    for (int j = 0; j < 8; ++j) {
      float vm = (j == 0) ? lft : v[j - 1];
      float vp = (j == 7) ? rgt : v[j + 1];
      acc[j] += vm * wm + v[j] * wc + vp * wp;
    }
  }
  u16x8 st;
  #pragma unroll
  for (int j = 0; j < 8; ++j) st[j] = f2b(acc[j]);
  *(u16x8*)&y[cbase + p0] = st;
}

// ---------- MFMA GEMM / conv-as-GEMM, 32x32 tile (all GEMM sites) ----------
// OMODE 0: fp32 Y[o][p]; 1: flag-dtype Y[o][p]; 2: bf16 Y[p][o]; 3: bf16 Y[o][p];
// OMODE 4: fp32 PARTIAL Y[sz][o][p]; OMODE 5: dual KV (o<256 -> bf16 K[p][256]
// at Y; o>=256 -> bf16 V[d][HWP] at Y+CC*HWP).
// xmode  0: fp32 X[Cin][HW]; 1: flag X[Cin][HW]; 2: bf16 X[p][Cin]; 3: bf16 X[Cin][HW].
// ADDIN: bf16 [o][HW]. bid swizzle: o0 = bid % NO -> per-XCD weight locality.
template<int TAPS, int ACT, bool ADDIN, int OMODE>
__global__ __launch_bounds__(256)
void mgemm32_k(const u16* __restrict__ Wp, const void* __restrict__ X,
               const void* __restrict__ bias, const u16* __restrict__ addin,
               void* __restrict__ Y, int Cin,
               const float* __restrict__ dflag, int xmode, int bias_off) {
  bool wbf = dflag[0] > 0.5f;
  bool xbf = (xmode == 1) ? wbf : false;
  __shared__ u16 Ws[32][72];   // [o][k]
  __shared__ u16 Xs[32][72];   // [p][k]
  int NO = gridDim.y;
  int O = NO * 32;
  int bid = blockIdx.x + blockIdx.y * gridDim.x;
  int p0 = (bid / NO) * 32, o0 = (bid % NO) * 32;
  int sz = blockIdx.z, NZ = gridDim.z;
  int t0 = (TAPS * sz) / NZ, t1 = (TAPS * (sz + 1)) / NZ;
  int tid = threadIdx.x, lane = tid & 63, wv = tid >> 6;
  int oq = (wv & 1) * 16, pq = (wv >> 1) * 16;
  int frow = lane & 15, kgrp = (lane >> 4) * 8;
  int wol = tid >> 3, wkk = (tid & 7) * 8;       // W: 32 rows x 64 k
  int pl = tid & 31, xkk = (tid >> 5) * 8;       // X: 32 rows x 64 k
  int p = p0 + pl, h = p / WWC, w = p - h * WWC;
  f32x4 acc = {0.f, 0.f, 0.f, 0.f};
  for (int t = t0; t < t1; ++t) {
    int dh = t / 3 - 1, dw = t % 3 - 1;
    int hh = h + dh, ww = w + dw;
    bool rowok = (TAPS == 1) || ((hh >= 0) && (hh < HH) && (ww >= 0) && (ww < WWC));
    int xoff = (TAPS == 1) ? p : hh * WWC + ww;
    const u16* Wrow = Wp + (size_t)t * O * Cin;
    for (int kb = 0; kb < Cin; kb += 64) {
      __syncthreads();
      *(u16x8*)&Ws[wol][wkk] =
          *(const u16x8*)&Wrow[(size_t)(o0 + wol) * Cin + kb + wkk];
      {
        u16x8 xv;
        if (xmode == 2) {
          if (rowok) {
            xv = *(const u16x8*)&((const u16*)X)[(size_t)xoff * Cin + kb + xkk];
          } else {
            #pragma unroll
            for (int j = 0; j < 8; ++j) xv[j] = 0;
          }
        } else if (xmode == 3) {
          #pragma unroll
          for (int j = 0; j < 8; ++j)
            xv[j] = rowok ? ((const u16*)X)[(size_t)(kb + xkk + j) * HWP + xoff]
                          : (u16)0;
        } else {
          #pragma unroll
          for (int j = 0; j < 8; ++j) {
            int kk = xkk + j;
            float v = rowok ? ldsel(X, (size_t)(kb + kk) * HWP + xoff, xbf) : 0.f;
            xv[j] = f2b(v);
          }
        }
        *(u16x8*)&Xs[pl][xkk] = xv;
      }
      __syncthreads();
      #pragma unroll
      for (int ks = 0; ks < 2; ++ks) {
        s16x8 aw = *(const s16x8*)&Ws[oq + frow][ks * 32 + kgrp];
        s16x8 ax = *(const s16x8*)&Xs[pq + frow][ks * 32 + kgrp];
        acc = mfma16(aw, ax, acc);
      }
    }
  }
  // D mapping (verified): col = lane&15 -> p, row = (lane>>4)*4+r -> o
  int orow = (lane >> 4) * 4;
  int ogb = o0 + oq + orow;
  int pg = p0 + pq + frow;
  if (OMODE == 4) {
    float* Yp = (float*)Y + (size_t)sz * O * HWP;
    #pragma unroll
    for (int r = 0; r < 4; ++r)
      Yp[(size_t)(ogb + r) * HWP + pg] = acc[r];
  } else if (OMODE == 5) {
    if (ogb < 256) {
      u16x4 st;
      #pragma unroll
      for (int r = 0; r < 4; ++r)
        st[r] = f2b(acc[r] + ldsel(bias, ogb + r, wbf));
      *(u16x4*)&((u16*)Y)[(size_t)pg * 256 + ogb] = st;
    } else {
      u16* V = (u16*)Y + (size_t)CC * HWP;
      #pragma unroll
      for (int r = 0; r < 4; ++r)
        V[(size_t)(ogb + r - 256) * HWP + pg] =
            f2b(acc[r] + ldsel(bias, ogb + r, wbf));
    }
  } else if (OMODE == 2) {
    u16x4 st;
    #pragma unroll
    for (int r = 0; r < 4; ++r) {
      float yv = acc[r] + ldsel(bias, bias_off + ogb + r, wbf);
      if (ACT == 1) yv = (yv >= 0.f) ? yv : 0.2f * yv;
      if (ADDIN) yv += b2f(addin[(size_t)(ogb + r) * HWP + pg]);
      st[r] = f2b(yv);
    }
    *(u16x4*)&((u16*)Y)[(size_t)pg * O + ogb] = st;
  } else {
    #pragma unroll
    for (int r = 0; r < 4; ++r) {
      int og = ogb + r;
      float yv = acc[r] + ldsel(bias, bias_off + og, wbf);
      if (ACT == 1) yv = (yv >= 0.f) ? yv : 0.2f * yv;
      if (ADDIN) yv += b2f(addin[(size_t)og * HWP + pg]);
      if (OMODE == 3) ((u16*)Y)[(size_t)og * HWP + pg] = f2b(yv);
      else stsel(Y, (size_t)og * HWP + pg, yv, (OMODE == 1) && wbf);
    }
  }
}

// ---------- combine 3 fp32 partials + bias + lrelu -> bf16 [128][HW] ----------
__global__ __launch_bounds__(256)
void comb3_lrelu_k(const float* __restrict__ P, const void* __restrict__ bias,
                   u16* __restrict__ Y, const float* __restrict__ dflag) {
  bool bf = dflag[0] > 0.5f;
  int gid = blockIdx.x * 256 + threadIdx.x;   // 128*HWP
  int o = gid / HWP;
  float v = P[gid] + P[gid + 128 * HWP] + P[gid + 2 * 128 * HWP] +
            ldsel(bias, o, bf);
  v = (v >= 0.f) ? v : 0.2f * v;
  Y[gid] = f2b(v);
}

// ---------- combine 2 fp32 partials + bias -> flag-dtype [256][HW] ----------
__global__ __launch_bounds__(256)
void comb2_out_k(const float* __restrict__ P, const void* __restrict__ bias,
                 void* __restrict__ Y, const float* __restrict__ dflag) {
  bool bf = dflag[0] > 0.5f;
  int gid = blockIdx.x * 256 + threadIdx.x;   // 256*HWP
  int o = gid / HWP;
  float v = P[gid] + P[gid + 256 * HWP] + ldsel(bias, o, bf);
  stsel(Y, gid, v, bf);
}

// ---------- 1x1 conv 128 -> 9 + softmax (bf16 hid in, bf16 out) ----------
template<bool DELTA>
__global__ __launch_bounds__(256)
void pw9_v2_k(const void* __restrict__ w2, const void* __restrict__ b2,
              const u16* __restrict__ hid, u16* __restrict__ out9,
              const float* __restrict__ dflag) {
  bool bf = dflag[0] > 0.5f;
  __shared__ float Wl[9][128];
  __shared__ float Pl[4][9][33];
  int tid = threadIdx.x;
  for (int i = tid; i < 1152; i += 256) Wl[i >> 7][i & 127] = ldsel(w2, i, bf);
  __syncthreads();
  int pix = tid & 31, cig = tid >> 5;        // 8 groups x 16 ci
  int p = blockIdx.x * 32 + pix;
  int ci0 = cig * 16;
  float acc[9] = {0.f, 0.f, 0.f, 0.f, 0.f, 0.f, 0.f, 0.f, 0.f};
  #pragma unroll
  for (int j = 0; j < 16; ++j) {
    float xv = b2f(hid[(size_t)(ci0 + j) * HWP + p]);
    #pragma unroll
    for (int t = 0; t < 9; ++t) acc[t] += Wl[t][ci0 + j] * xv;
  }
  #pragma unroll
  for (int t = 0; t < 9; ++t) acc[t] += __shfl_xor(acc[t], 32);
  int wv = tid >> 6;
  if ((tid & 63) < 32) {
    #pragma unroll
    for (int t = 0; t < 9; ++t) Pl[wv][t][pix] = acc[t];
  }
  __syncthreads();
  if (tid < 32) {
    float a[9];
    #pragma unroll
    for (int t = 0; t < 9; ++t)
      a[t] = Pl[0][t][pix] + Pl[1][t][pix] + Pl[2][t][pix] + Pl[3][t][pix] +
             ldsel(b2, t, bf);
    float mx = a[0];
    #pragma unroll
    for (int t = 1; t < 9; ++t) mx = fmaxf(mx, a[t]);
    float s = 0.f;
    #pragma unroll
    for (int t = 0; t < 9; ++t) { a[t] = __expf(a[t] - mx); s += a[t]; }
    float inv = 1.f / s;
    #pragma unroll
    for (int t = 0; t < 9; ++t) {
      float v = a[t] * inv;
      if (DELTA) v = ((t == 4) ? 1.f : 0.f) - v;
      out9[(size_t)t * HWP + p] = f2b(v);
    }
  }
}

// ---------- spatially-varying 3x3 filter, 8 pixels/thread vectorized ----------
template<bool HIGH>
__global__ __launch_bounds__(128)
void spatial_v2_k(const void* __restrict__ x, const u16* __restrict__ w9,
                  u16* __restrict__ y, const float* __restrict__ dflag) {
  bool bf = dflag[0] > 0.5f;
  int gid = blockIdx.x * 128 + threadIdx.x;   // 100352
  int c = gid / 392, g = gid - c * 392;
  int p0 = g * 8;
  int h = p0 / WWC, w0 = p0 - h * WWC;
  const size_t cbase = (size_t)c * HWP;
  float acc[8];
  if (HIGH) {
    ldrow8(x, cbase + p0, bf, acc);
  } else {
    #pragma unroll
    for (int j = 0; j < 8; ++j) acc[j] = 0.f;
  }
  #pragma unroll
  for (int dh = -1; dh <= 1; ++dh) {
    int hh = h + dh;
    if (hh < 0 || hh >= HH) continue;
    size_t rbase = cbase + hh * WWC + w0;
    float v[8];
    ldrow8(x, rbase, bf, v);
    float lft = (w0 > 0) ? ldsel(x, rbase - 1, bf) : 0.f;
    float rgt = (w0 < 48) ? ldsel(x, rbase + 8, bf) : 0.f;
    float wm[8], wc[8], wp[8];
    {
      int tb = (dh + 1) * 3;
      u16x8 a = *(const u16x8*)&w9[(size_t)(tb + 0) * HWP + p0];
      u16x8 b = *(const u16x8*)&w9[(size_t)(tb + 1) * HWP + p0];
      u16x8 d = *(const u16x8*)&w9[(size_t)(tb + 2) * HWP + p0];
      #pragma unroll
      for (int j = 0; j < 8; ++j) { wm[j] = b2f(a[j]); wc[j] = b2f(b[j]); wp[j] = b2f(d[j]); }
    }
    #pragma unroll
    for (int j = 0; j < 8; ++j) {
      float vm = (j == 0) ? lft : v[j - 1];
      float vp = (j == 7) ? rgt : v[j + 1];
      acc[j] += vm * wm[j] + v[j] * wc[j] + vp * wp[j];
    }
  }
  u16x8 st;
  #pragma unroll
  for (int j = 0; j < 8; ++j) st[j] = f2b(acc[j]);
  *(u16x8*)&y[cbase + p0] = st;
}

// ---------- flash attention partial (proven structure, NSPLIT=6) ----------
__global__ __launch_bounds__(256)
void attn_part_k(const u16* __restrict__ Qb, const u16* __restrict__ Kb,
                 const u16* __restrict__ Vb, u16* __restrict__ Op,
                 float* __restrict__ Lb) {
  __shared__ u16 Ks[64][40];
  __shared__ u16 Vs[32][72];      // [d][m] linear
  __shared__ u16 Ps[4][16][72];   // per-wave P tile [q][m]
  int h = blockIdx.y, n0 = blockIdx.x * 64, sz = blockIdx.z;
  int tid = threadIdx.x, lane = tid & 63, wv = tid >> 6;
  int frow = lane & 15, gq = lane >> 4, kgrp = gq * 8;
  int ml = tid >> 2, dseg = (tid & 3) * 8;     // K staging: [64 m][32 d]
  int vd = tid >> 3, vm = (tid & 7) * 8;       // V staging: [32 d][64 m]
  const float QS = 0.17677669529663687f * 1.4426950408889634f;  // scale*log2e
  s16x8 aq;
  {
    u16x8 qv = *(const u16x8*)&Qb[(size_t)(n0 + wv * 16 + frow) * 256 + h * 32 + kgrp];
    u16x8 qs;
    #pragma unroll
    for (int j = 0; j < 8; ++j) qs[j] = f2b(b2f(qv[j]) * QS);
    aq = *(s16x8*)&qs;
  }
  f32x4 oa0 = {0.f, 0.f, 0.f, 0.f}, oa1 = {0.f, 0.f, 0.f, 0.f};
  float lsum = 0.f;
  int t_begin = (49 * sz) / NSPLIT, t_end = (49 * (sz + 1)) / NSPLIT;
  u16x8 kreg = *(const u16x8*)&Kb[(size_t)(t_begin * 64 + ml) * 256 + h * 32 + dseg];
  u16x8 vreg = *(const u16x8*)&Vb[(size_t)(h * 32 + vd) * HWP + t_begin * 64 + vm];
  for (int t = t_begin; t < t_end; ++t) {
    __syncthreads();
    *(u16x8*)&Ks[ml][dseg] = kreg;
    *(u16x8*)&Vs[vd][vm] = vreg;
    if (t + 1 < t_end) {
      kreg = *(const u16x8*)&Kb[(size_t)((t + 1) * 64 + ml) * 256 + h * 32 + dseg];
      vreg = *(const u16x8*)&Vb[(size_t)(h * 32 + vd) * HWP + (t + 1) * 64 + vm];
    }
    __syncthreads();
    f32x4 zero = {0.f, 0.f, 0.f, 0.f};
    #pragma unroll
    for (int fm = 0; fm < 4; ++fm) {
      s16x8 ak = *(const s16x8*)&Ks[fm * 16 + frow][kgrp];
      f32x4 s = mfma16(ak, aq, zero);       // D[m][q]: rows=m, col=q=frow
      u16x4 pe;
      #pragma unroll
      for (int r = 0; r < 4; ++r) {
        float e = exp2f(fminf(s[r], 43.f));
        lsum += e;
        pe[r] = (u16)(__float_as_uint(e) >> 16);  // trunc-to-bf16 (P in (0,1])
      }
      *(u16x4*)&Ps[wv][frow][fm * 16 + gq * 4] = pe;
    }
    #pragma unroll
    for (int ks = 0; ks < 2; ++ks) {
      s16x8 ap = *(const s16x8*)&Ps[wv][frow][ks * 32 + kgrp];
      s16x8 bv0 = *(const s16x8*)&Vs[frow][ks * 32 + kgrp];
      s16x8 bv1 = *(const s16x8*)&Vs[16 + frow][ks * 32 + kgrp];
      oa0 = mfma16(ap, bv0, oa0);
      oa1 = mfma16(ap, bv1, oa1);
    }
  }
  lsum += __shfl_xor(lsum, 16);
  lsum += __shfl_xor(lsum, 32);
  if (lane < 16)
    Lb[(size_t)(sz * 8 + h) * HWP + n0 + wv * 16 + frow] = lsum;
  #pragma unroll
  for (int r = 0; r < 4; ++r) {
    int n = n0 + wv * 16 + gq * 4 + r;
    Op[(size_t)(sz * 256 + h * 32 + frow) * HWP + n]      = f2b(oa0[r]);
    Op[(size_t)(sz * 256 + h * 32 + 16 + frow) * HWP + n] = f2b(oa1[r]);
  }
}

// ---------- combine NSPLIT attention partials -> bf16 [C][HW] ----------
__global__ __launch_bounds__(256)
void attn_combine_k(const u16* __restrict__ Op, const float* __restrict__ Lb,
                    u16* __restrict__ A) {
  int gid = blockIdx.x * 256 + threadIdx.x;   // 802816
  int n = gid % HWP, hd = gid / HWP, h = hd >> 5;
  float L = 0.f, O = 0.f;
  #pragma unroll
  for (int s = 0; s < NSPLIT; ++s) {
    L += Lb[(size_t)(s * 8 + h) * HWP + n];
    O += b2f(Op[(size_t)(s * 256 + hd) * HWP + n]);
  }
  A[(size_t)hd * HWP + n] = f2b(O / L);
}

extern "C" void kernel_launch(void* const* d_in, const int* in_sizes, int n_in,
                              void* d_out, int out_size, void* d_ws, size_t ws_size,
                              hipStream_t stream) {
  const void* dec   = d_in[0];
  const void* enc   = d_in[1];
  const void* dw_w  = d_in[2];
  const void* dw_b  = d_in[3];
  const void* p1_w  = d_in[4];
  const void* p1_b  = d_in[5];
  const void* p2_w  = d_in[6];
  const void* p2_b  = d_in[7];
  const void* c1_w  = d_in[8];
  const void* c1_b  = d_in[9];
  const void* c2_w  = d_in[10];
  const void* c2_b  = d_in[11];
  const void* q_w   = d_in[12];
  const void* q_b   = d_in[13];
  const void* kv_w  = d_in[14];
  const void* kv_b  = d_in[15];
  const void* out_w = d_in[16];
  const void* out_b = d_in[17];
  const void* fu_w  = d_in[18];
  const void* fu_b  = d_in[19];

  const int CH = CC * HWP;     // 802816
  float* flag = (float*)d_ws;                       // 8 floats
  u16* pk     = (u16*)(flag + 8);
  u16* A      = pk;              pk += CH;            // dwconv out / attn out, bf16 [C][HW]
  u16* hid    = pk;              pk += 128 * HWP;     // bf16 [128][HW]
  u16* s9     = pk;              pk += 9 * HWP;       // bf16 [9][HW]
  u16* Bb     = pk;              pk += CH;            // f_smooth / f_high, bf16 [C][HW]
  u16* qb16   = pk;              pk += CH;            // q bf16 [n][256]; later fused_in [p][256]
  u16* k16    = pk;              pk += CH;            // K bf16 [m][256]
  u16* v16    = pk;              pk += CH;            // V bf16 [d][HWP] (contiguous after k16!)
  u16* wp_p1  = pk;              pk += 128 * 256;
  u16* wp_q   = pk;              pk += 256 * 256;
  u16* wp_kv  = pk;              pk += 512 * 256;
  u16* wp_out = pk;              pk += 256 * 256;
  u16* wp_c1  = pk;              pk += 128 * 256 * 9;
  u16* wp_fu  = pk;              pk += 256 * 256 * 9;
  pk += (size_t)(-(intptr_t)pk) & 7;                  // align to 4 floats
  float* Lb   = (float*)pk;                           // 48*HWP f32
  u16* Opart  = (u16*)(Lb + 48 * HWP);                // 1536*HWP u16
  // conv split-K partials ALIAS the attn Lb/Opart region (10.2 MB):
  //   c1: 3*128*HWP f32 = 4.8 MB (after attn_combine consumed Lb/Opart)
  //   fu: 2*256*HWP f32 = 6.4 MB (after comb3_lrelu consumed c1 partials)
  float* Pc = Lb;

  dim3 blk(256);
  detect_dtype_k<<<1, blk, 0, stream>>>(dec, flag);

  // ---- pack ALL weights (one launch) ----
  pack_all_k<<<1536, blk, 0, stream>>>(p1_w, q_w, kv_w, out_w, c1_w, fu_w,
                                       wp_p1, wp_q, wp_kv, wp_out, wp_c1, wp_fu,
                                       flag);

  // ---- ALPF: kw = softmax(p2(lrelu(p1(dw(dec))))) ----
  dwconv_v2_k<<<784, dim3(128), 0, stream>>>(dec, dw_w, dw_b, A, flag);
  mgemm32_k<1, 1, false, 3><<<dim3(98, 4), blk, 0, stream>>>(
      wp_p1, A, p1_b, nullptr, hid, 256, flag, 3, 0);
  pw9_v2_k<false><<<98, blk, 0, stream>>>(p2_w, p2_b, hid, s9, flag);
  spatial_v2_k<false><<<784, dim3(128), 0, stream>>>(dec, s9, Bb, flag);

  // ---- q proj + merged k/v proj (dual-output, one dispatch) ----
  mgemm32_k<1, 0, false, 2><<<dim3(98, 8), blk, 0, stream>>>(
      wp_q, Bb, q_b, nullptr, qb16, 256, flag, 3, 0);
  mgemm32_k<1, 0, false, 5><<<dim3(98, 16), blk, 0, stream>>>(
      wp_kv, enc, kv_b, nullptr, k16, 256, flag, 1, 0);

  // ---- attention: 6-way KV-split partials + combine ----
  attn_part_k<<<dim3(49, 8, NSPLIT), blk, 0, stream>>>(qb16, k16, v16, Opart, Lb);
  attn_combine_k<<<3136, blk, 0, stream>>>(Opart, Lb, A);

  // ---- AHPF: c1 conv as 3-way tap-split + combine ----
  mgemm32_k<9, 1, false, 4><<<dim3(98, 4, 3), blk, 0, stream>>>(
      wp_c1, enc, nullptr, nullptr, Pc, 256, flag, 1, 0);
  comb3_lrelu_k<<<1568, blk, 0, stream>>>(Pc, c1_b, hid, flag);
  pw9_v2_k<true><<<98, blk, 0, stream>>>(c2_w, c2_b, hid, s9, flag);
  spatial_v2_k<true><<<784, dim3(128), 0, stream>>>(enc, s9, Bb, flag);

  // ---- out proj + f_high add -> bf16 [p][256] (reuses qb16, q is dead) ----
  mgemm32_k<1, 0, true, 2><<<dim3(98, 8), blk, 0, stream>>>(
      wp_out, A, out_b, Bb, qb16, 256, flag, 3, 0);

  // ---- fusion 3x3 conv: 2-way tap-split + combine -> d_out ----
  mgemm32_k<9, 0, false, 4><<<dim3(98, 8, 2), blk, 0, stream>>>(
      wp_fu, qb16, nullptr, nullptr, Pc, 256, flag, 2, 0);
  comb2_out_k<<<3136, blk, 0, stream>>>(Pc, fu_b, d_out, flag);
}

// Round 19
// 145.952 us; speedup vs baseline: 1.6657x; 1.0562x over previous
//
#include <hip/hip_runtime.h>
#include <hip/hip_bf16.h>

#define HH  56
#define WWC 56
#define HWP 3136   // 56*56 = 49*64
#define CC  256
#define NSPLIT 6

typedef unsigned short u16;
typedef __attribute__((ext_vector_type(8))) u16 u16x8;
typedef __attribute__((ext_vector_type(4))) u16 u16x4;
typedef __attribute__((ext_vector_type(8))) short s16x8;   // bf16x8 MFMA frag
typedef __attribute__((ext_vector_type(4))) float f32x4;

__device__ __forceinline__ u16 f2b(float f) {
  unsigned int x = __float_as_uint(f);
  return (u16)((x + 0x7fffu + ((x >> 16) & 1u)) >> 16);
}
__device__ __forceinline__ float b2f(u16 u) {
  return __uint_as_float(((unsigned int)u) << 16);
}
__device__ __forceinline__ f32x4 mfma16(s16x8 a, s16x8 b, f32x4 c) {
  return __builtin_amdgcn_mfma_f32_16x16x32_bf16(a, b, c, 0, 0, 0);
}

// ---------- dtype-flexible load/store (flag decided on device) ----------
__device__ __forceinline__ float ldsel(const void* p, int i, bool bf) {
  if (bf) return __bfloat162float(((const __hip_bfloat16*)p)[i]);
  return ((const float*)p)[i];
}
__device__ __forceinline__ void stsel(void* p, int i, float v, bool bf) {
  if (bf) ((__hip_bfloat16*)p)[i] = __float2bfloat16(v);
  else ((float*)p)[i] = v;
}

// load 8 consecutive elements (index 8-aligned) as floats, dtype per flag
__device__ __forceinline__ void ldrow8(const void* p, size_t i, bool bf,
                                       float* o) {
  if (bf) {
    u16x8 v = *(const u16x8*)((const u16*)p + i);
    #pragma unroll
    for (int j = 0; j < 8; ++j) o[j] = b2f(v[j]);
  } else {
    const float* f = (const float*)p + i;
    f32x4 a = *(const f32x4*)f;
    f32x4 b = *(const f32x4*)(f + 4);
    #pragma unroll
    for (int j = 0; j < 4; ++j) { o[j] = a[j]; o[4 + j] = b[j]; }
  }
}

__global__ void detect_dtype_k(const void* x, float* flag) {
  __shared__ int sh[256];
  int tid = threadIdx.x;
  const __hip_bfloat16* xb = (const __hip_bfloat16*)x;
  int ok = 0;
  for (int i = tid; i < 1024; i += 256) {
    float v = fabsf(__bfloat162float(xb[2 * i]));
    if (v > 9.5e-7f && v < 1.05e6f) ok++;
  }
  sh[tid] = ok;
  __syncthreads();
  for (int s = 128; s > 0; s >>= 1) {
    if (tid < s) sh[tid] += sh[tid + s];
    __syncthreads();
  }
  if (tid == 0) flag[0] = (sh[0] > 512) ? 1.f : 0.f;
}

// ---------- fused weight pack: all 6 weights in ONE launch ----------
__global__ __launch_bounds__(256)
void pack_all_k(const void* __restrict__ p1, const void* __restrict__ q,
                const void* __restrict__ kv, const void* __restrict__ ow,
                const void* __restrict__ c1, const void* __restrict__ fu,
                u16* __restrict__ d_p1, u16* __restrict__ d_q,
                u16* __restrict__ d_kv, u16* __restrict__ d_ow,
                u16* __restrict__ d_c1, u16* __restrict__ d_fu,
                const float* __restrict__ dflag) {
  bool bf = dflag[0] > 0.5f;
  int b = blockIdx.x, tid = threadIdx.x;
  if (b < 128) { int g = b * 256 + tid; d_p1[g] = f2b(ldsel(p1, g, bf)); return; }
  b -= 128;
  if (b < 256) { int g = b * 256 + tid; d_q[g] = f2b(ldsel(q, g, bf)); return; }
  b -= 256;
  if (b < 512) { int g = b * 256 + tid; d_kv[g] = f2b(ldsel(kv, g, bf)); return; }
  b -= 512;
  if (b < 256) { int g = b * 256 + tid; d_ow[g] = f2b(ldsel(ow, g, bf)); return; }
  b -= 256;
  if (b < 128) {
    int g = b * 256 + tid;
    #pragma unroll
    for (int t = 0; t < 9; ++t)
      d_c1[(size_t)t * 32768 + g] = f2b(ldsel(c1, g * 9 + t, bf));
    return;
  }
  b -= 128;
  {
    int g = b * 256 + tid;
    #pragma unroll
    for (int t = 0; t < 9; ++t)
      d_fu[(size_t)t * 65536 + g] = f2b(ldsel(fu, g * 9 + t, bf));
  }
}

// ---------- dwconv body: 8 pixels/thread (gid over 100352) ----------
__device__ __forceinline__ void dwconv_body(int gid, const void* x,
                                            const void* wt, const void* bs,
                                            u16* y, bool bf) {
  int c = gid / 392, g = gid - c * 392;
  int p0 = g * 8;
  int h = p0 / WWC, w0 = p0 - h * WWC;
  float wv[9];
  #pragma unroll
  for (int t = 0; t < 9; ++t) wv[t] = ldsel(wt, c * 9 + t, bf);
  float bv = ldsel(bs, c, bf);
  float acc[8];
  #pragma unroll
  for (int j = 0; j < 8; ++j) acc[j] = bv;
  const size_t cbase = (size_t)c * HWP;
  #pragma unroll
  for (int dh = -1; dh <= 1; ++dh) {
    int hh = h + dh;
    if (hh < 0 || hh >= HH) continue;
    size_t rbase = cbase + hh * WWC + w0;
    float v[8];
    ldrow8(x, rbase, bf, v);
    float lft = (w0 > 0) ? ldsel(x, rbase - 1, bf) : 0.f;
    float rgt = (w0 < 48) ? ldsel(x, rbase + 8, bf) : 0.f;
    float wm = wv[(dh + 1) * 3 + 0], wc = wv[(dh + 1) * 3 + 1],
          wp = wv[(dh + 1) * 3 + 2];
    #pragma unroll
    for (int j = 0; j < 8; ++j) {
      float vm = (j == 0) ? lft : v[j - 1];
      float vp = (j == 7) ? rgt : v[j + 1];
      acc[j] += vm * wm + v[j] * wc + vp * wp;
    }
  }
  u16x8 st;
  #pragma unroll
  for (int j = 0; j < 8; ++j) st[j] = f2b(acc[j]);
  *(u16x8*)&y[cbase + p0] = st;
}

// ---------- MFMA GEMM body, 32x32 tile ----------
// OMODE 0 fp32 [o][p]; 1 flag [o][p]; 2 bf16 [p][o](+ACT/ADDIN); 3 bf16 [o][p];
// OMODE 4 fp32 partial [sz][o][p]; OMODE 5 dual KV.
// xmode 0 fp32 [Cin][HW]; 1 flag [Cin][HW]; 2 bf16 [p][Cin]; 3 bf16 [Cin][HW].
template<int TAPS, int ACT, bool ADDIN, int OMODE>
__device__ __forceinline__ void mgemm_body(
    int bid, int sz, int NZ, int NO, int O,
    const u16* __restrict__ Wp, const void* __restrict__ X,
    const void* __restrict__ bias, const u16* __restrict__ addin,
    void* __restrict__ Y, int Cin, bool wbf, bool xbf, int xmode,
    int bias_off, u16 (*Ws)[72], u16 (*Xs)[72]) {
  int p0 = (bid / NO) * 32, o0 = (bid % NO) * 32;
  int t0 = (TAPS * sz) / NZ, t1 = (TAPS * (sz + 1)) / NZ;
  int tid = threadIdx.x, lane = tid & 63, wv = tid >> 6;
  int oq = (wv & 1) * 16, pq = (wv >> 1) * 16;
  int frow = lane & 15, kgrp = (lane >> 4) * 8;
  int wol = tid >> 3, wkk = (tid & 7) * 8;
  int pl = tid & 31, xkk = (tid >> 5) * 8;
  int p = p0 + pl, h = p / WWC, w = p - h * WWC;
  f32x4 acc = {0.f, 0.f, 0.f, 0.f};
  for (int t = t0; t < t1; ++t) {
    int dh = t / 3 - 1, dw = t % 3 - 1;
    int hh = h + dh, ww = w + dw;
    bool rowok = (TAPS == 1) || ((hh >= 0) && (hh < HH) && (ww >= 0) && (ww < WWC));
    int xoff = (TAPS == 1) ? p : hh * WWC + ww;
    const u16* Wrow = Wp + (size_t)t * O * Cin;
    for (int kb = 0; kb < Cin; kb += 64) {
      __syncthreads();
      *(u16x8*)&Ws[wol][wkk] =
          *(const u16x8*)&Wrow[(size_t)(o0 + wol) * Cin + kb + wkk];
      {
        u16x8 xv;
        if (xmode == 2) {
          if (rowok) {
            xv = *(const u16x8*)&((const u16*)X)[(size_t)xoff * Cin + kb + xkk];
          } else {
            #pragma unroll
            for (int j = 0; j < 8; ++j) xv[j] = 0;
          }
        } else if (xmode == 3) {
          #pragma unroll
          for (int j = 0; j < 8; ++j)
            xv[j] = rowok ? ((const u16*)X)[(size_t)(kb + xkk + j) * HWP + xoff]
                          : (u16)0;
        } else {
          #pragma unroll
          for (int j = 0; j < 8; ++j) {
            int kk = xkk + j;
            float v = rowok ? ldsel(X, (size_t)(kb + kk) * HWP + xoff, xbf) : 0.f;
            xv[j] = f2b(v);
          }
        }
        *(u16x8*)&Xs[pl][xkk] = xv;
      }
      __syncthreads();
      #pragma unroll
      for (int ks = 0; ks < 2; ++ks) {
        s16x8 aw = *(const s16x8*)&Ws[oq + frow][ks * 32 + kgrp];
        s16x8 ax = *(const s16x8*)&Xs[pq + frow][ks * 32 + kgrp];
        acc = mfma16(aw, ax, acc);
      }
    }
  }
  // D mapping (verified): col = lane&15 -> p, row = (lane>>4)*4+r -> o
  int orow = (lane >> 4) * 4;
  int ogb = o0 + oq + orow;
  int pg = p0 + pq + frow;
  if (OMODE == 4) {
    float* Yp = (float*)Y + (size_t)sz * O * HWP;
    #pragma unroll
    for (int r = 0; r < 4; ++r)
      Yp[(size_t)(ogb + r) * HWP + pg] = acc[r];
  } else if (OMODE == 5) {
    if (ogb < 256) {
      u16x4 st;
      #pragma unroll
      for (int r = 0; r < 4; ++r)
        st[r] = f2b(acc[r] + ldsel(bias, ogb + r, wbf));
      *(u16x4*)&((u16*)Y)[(size_t)pg * 256 + ogb] = st;
    } else {
      u16* V = (u16*)Y + (size_t)CC * HWP;
      #pragma unroll
      for (int r = 0; r < 4; ++r)
        V[(size_t)(ogb + r - 256) * HWP + pg] =
            f2b(acc[r] + ldsel(bias, ogb + r, wbf));
    }
  } else if (OMODE == 2) {
    u16x4 st;
    #pragma unroll
    for (int r = 0; r < 4; ++r) {
      float yv = acc[r] + ldsel(bias, bias_off + ogb + r, wbf);
      if (ACT == 1) yv = (yv >= 0.f) ? yv : 0.2f * yv;
      if (ADDIN) yv += b2f(addin[(size_t)(ogb + r) * HWP + pg]);
      st[r] = f2b(yv);
    }
    *(u16x4*)&((u16*)Y)[(size_t)pg * O + ogb] = st;
  } else {
    #pragma unroll
    for (int r = 0; r < 4; ++r) {
      int og = ogb + r;
      float yv = acc[r] + ldsel(bias, bias_off + og, wbf);
      if (ACT == 1) yv = (yv >= 0.f) ? yv : 0.2f * yv;
      if (ADDIN) yv += b2f(addin[(size_t)og * HWP + pg]);
      if (OMODE == 3) ((u16*)Y)[(size_t)og * HWP + pg] = f2b(yv);
      else stsel(Y, (size_t)og * HWP + pg, yv, (OMODE == 1) && wbf);
    }
  }
}

// ---------- standalone mgemm kernel (unchanged call sites) ----------
template<int TAPS, int ACT, bool ADDIN, int OMODE>
__global__ __launch_bounds__(256)
void mgemm32_k(const u16* __restrict__ Wp, const void* __restrict__ X,
               const void* __restrict__ bias, const u16* __restrict__ addin,
               void* __restrict__ Y, int Cin,
               const float* __restrict__ dflag, int xmode, int bias_off) {
  __shared__ u16 Ws[32][72];
  __shared__ u16 Xs[32][72];
  bool wbf = dflag[0] > 0.5f;
  bool xbf = (xmode == 1) ? wbf : false;
  int NO = gridDim.y;
  int bid = blockIdx.x + blockIdx.y * gridDim.x;
  mgemm_body<TAPS, ACT, ADDIN, OMODE>(bid, blockIdx.z, gridDim.z, NO, NO * 32,
                                      Wp, X, bias, addin, Y, Cin, wbf, xbf,
                                      xmode, bias_off, Ws, Xs);
}

// ---------- stage1: dwconv (blocks 0..391) + merged kv proj (392..1959) ----------
__global__ __launch_bounds__(256)
void stage1_k(const void* __restrict__ dec, const void* __restrict__ dw_w,
              const void* __restrict__ dw_b, u16* __restrict__ A,
              const u16* __restrict__ wp_kv, const void* __restrict__ enc,
              const void* __restrict__ kv_b, u16* __restrict__ k16,
              const float* __restrict__ dflag) {
  __shared__ u16 Ws[32][72];
  __shared__ u16 Xs[32][72];
  bool bf = dflag[0] > 0.5f;
  int b = blockIdx.x;
  if (b < 392) {
    dwconv_body(b * 256 + threadIdx.x, dec, dw_w, dw_b, A, bf);
  } else {
    mgemm_body<1, 0, false, 5>(b - 392, 0, 1, 16, 512, wp_kv, enc, kv_b,
                               nullptr, k16, 256, bf, bf, 1, 0, Ws, Xs);
  }
}

// ---------- stage2: vectorized attn_combine (0..391) + c1 partials (392..1567) ----------
__global__ __launch_bounds__(256)
void stage2_k(const u16* __restrict__ Op, const float* __restrict__ Lb,
              u16* __restrict__ A, const u16* __restrict__ wp_c1,
              const void* __restrict__ enc, float* __restrict__ Pc1,
              const float* __restrict__ dflag) {
  __shared__ u16 Ws[32][72];
  __shared__ u16 Xs[32][72];
  bool bf = dflag[0] > 0.5f;
  int b = blockIdx.x;
  if (b < 392) {
    int gid = b * 256 + threadIdx.x;           // 100352
    int hd = gid / 392, g = gid - hd * 392;
    int n0 = g * 8, h = hd >> 5;
    float L[8] = {0,0,0,0,0,0,0,0}, O[8] = {0,0,0,0,0,0,0,0};
    #pragma unroll
    for (int s = 0; s < NSPLIT; ++s) {
      const float* Lp = &Lb[(size_t)(s * 8 + h) * HWP + n0];
      f32x4 l0 = *(const f32x4*)Lp;
      f32x4 l1 = *(const f32x4*)(Lp + 4);
      u16x8 ov = *(const u16x8*)&Op[(size_t)(s * 256 + hd) * HWP + n0];
      #pragma unroll
      for (int j = 0; j < 4; ++j) { L[j] += l0[j]; L[4 + j] += l1[j]; }
      #pragma unroll
      for (int j = 0; j < 8; ++j) O[j] += b2f(ov[j]);
    }
    u16x8 st;
    #pragma unroll
    for (int j = 0; j < 8; ++j) st[j] = f2b(O[j] / L[j]);
    *(u16x8*)&A[(size_t)hd * HWP + n0] = st;
  } else {
    int rem = b - 392;              // 0..1175 = (98x4) x 3
    int sz = rem / 392, bb = rem - sz * 392;
    mgemm_body<9, 1, false, 4>(bb, sz, 3, 4, 128, wp_c1, enc, nullptr,
                               nullptr, Pc1, 256, bf, bf, 1, 0, Ws, Xs);
  }
}

// ---------- combine 3 fp32 partials + bias + lrelu -> bf16 [128][HW], x4 ----------
__global__ __launch_bounds__(256)
void comb3_v2_k(const float* __restrict__ P, const void* __restrict__ bias,
                u16* __restrict__ Y, const float* __restrict__ dflag) {
  bool bf = dflag[0] > 0.5f;
  int flat = (blockIdx.x * 256 + threadIdx.x) * 4;   // 128*HWP total
  int o = flat / HWP;
  f32x4 a = *(const f32x4*)&P[flat];
  f32x4 b = *(const f32x4*)&P[flat + 128 * HWP];
  f32x4 c = *(const f32x4*)&P[flat + 2 * 128 * HWP];
  float bv = ldsel(bias, o, bf);
  u16x4 st;
  #pragma unroll
  for (int j = 0; j < 4; ++j) {
    float v = a[j] + b[j] + c[j] + bv;
    v = (v >= 0.f) ? v : 0.2f * v;
    st[j] = f2b(v);
  }
  *(u16x4*)&Y[flat] = st;
}

// ---------- combine 2 fp32 partials + bias -> flag-dtype [256][HW], x4 ----------
__global__ __launch_bounds__(256)
void comb2_v2_k(const float* __restrict__ P, const void* __restrict__ bias,
                void* __restrict__ Y, const float* __restrict__ dflag) {
  bool bf = dflag[0] > 0.5f;
  int flat = (blockIdx.x * 256 + threadIdx.x) * 4;   // 256*HWP total
  int o = flat / HWP;
  f32x4 a = *(const f32x4*)&P[flat];
  f32x4 b = *(const f32x4*)&P[flat + 256 * HWP];
  float bv = ldsel(bias, o, bf);
  if (bf) {
    u16x4 st;
    #pragma unroll
    for (int j = 0; j < 4; ++j) st[j] = f2b(a[j] + b[j] + bv);
    *(u16x4*)&((u16*)Y)[flat] = st;
  } else {
    f32x4 st;
    #pragma unroll
    for (int j = 0; j < 4; ++j) st[j] = a[j] + b[j] + bv;
    *(f32x4*)&((float*)Y)[flat] = st;
  }
}

// ---------- 1x1 conv 128 -> 9 + softmax (bf16 hid in, bf16 out) ----------
template<bool DELTA>
__global__ __launch_bounds__(256)
void pw9_v2_k(const void* __restrict__ w2, const void* __restrict__ b2,
              const u16* __restrict__ hid, u16* __restrict__ out9,
              const float* __restrict__ dflag) {
  bool bf = dflag[0] > 0.5f;
  __shared__ float Wl[9][128];
  __shared__ float Pl[4][9][33];
  int tid = threadIdx.x;
  for (int i = tid; i < 1152; i += 256) Wl[i >> 7][i & 127] = ldsel(w2, i, bf);
  __syncthreads();
  int pix = tid & 31, cig = tid >> 5;
  int p = blockIdx.x * 32 + pix;
  int ci0 = cig * 16;
  float acc[9] = {0.f, 0.f, 0.f, 0.f, 0.f, 0.f, 0.f, 0.f, 0.f};
  #pragma unroll
  for (int j = 0; j < 16; ++j) {
    float xv = b2f(hid[(size_t)(ci0 + j) * HWP + p]);
    #pragma unroll
    for (int t = 0; t < 9; ++t) acc[t] += Wl[t][ci0 + j] * xv;
  }
  #pragma unroll
  for (int t = 0; t < 9; ++t) acc[t] += __shfl_xor(acc[t], 32);
  int wv = tid >> 6;
  if ((tid & 63) < 32) {
    #pragma unroll
    for (int t = 0; t < 9; ++t) Pl[wv][t][pix] = acc[t];
  }
  __syncthreads();
  if (tid < 32) {
    float a[9];
    #pragma unroll
    for (int t = 0; t < 9; ++t)
      a[t] = Pl[0][t][pix] + Pl[1][t][pix] + Pl[2][t][pix] + Pl[3][t][pix] +
             ldsel(b2, t, bf);
    float mx = a[0];
    #pragma unroll
    for (int t = 1; t < 9; ++t) mx = fmaxf(mx, a[t]);
    float s = 0.f;
    #pragma unroll
    for (int t = 0; t < 9; ++t) { a[t] = __expf(a[t] - mx); s += a[t]; }
    float inv = 1.f / s;
    #pragma unroll
    for (int t = 0; t < 9; ++t) {
      float v = a[t] * inv;
      if (DELTA) v = ((t == 4) ? 1.f : 0.f) - v;
      out9[(size_t)t * HWP + p] = f2b(v);
    }
  }
}

// ---------- spatially-varying 3x3 filter, 8 pixels/thread vectorized ----------
template<bool HIGH>
__global__ __launch_bounds__(128)
void spatial_v2_k(const void* __restrict__ x, const u16* __restrict__ w9,
                  u16* __restrict__ y, const float* __restrict__ dflag) {
  bool bf = dflag[0] > 0.5f;
  int gid = blockIdx.x * 128 + threadIdx.x;   // 100352
  int c = gid / 392, g = gid - c * 392;
  int p0 = g * 8;
  int h = p0 / WWC, w0 = p0 - h * WWC;
  const size_t cbase = (size_t)c * HWP;
  float acc[8];
  if (HIGH) {
    ldrow8(x, cbase + p0, bf, acc);
  } else {
    #pragma unroll
    for (int j = 0; j < 8; ++j) acc[j] = 0.f;
  }
  #pragma unroll
  for (int dh = -1; dh <= 1; ++dh) {
    int hh = h + dh;
    if (hh < 0 || hh >= HH) continue;
    size_t rbase = cbase + hh * WWC + w0;
    float v[8];
    ldrow8(x, rbase, bf, v);
    float lft = (w0 > 0) ? ldsel(x, rbase - 1, bf) : 0.f;
    float rgt = (w0 < 48) ? ldsel(x, rbase + 8, bf) : 0.f;
    float wm[8], wc[8], wp[8];
    {
      int tb = (dh + 1) * 3;
      u16x8 a = *(const u16x8*)&w9[(size_t)(tb + 0) * HWP + p0];
      u16x8 b = *(const u16x8*)&w9[(size_t)(tb + 1) * HWP + p0];
      u16x8 d = *(const u16x8*)&w9[(size_t)(tb + 2) * HWP + p0];
      #pragma unroll
      for (int j = 0; j < 8; ++j) { wm[j] = b2f(a[j]); wc[j] = b2f(b[j]); wp[j] = b2f(d[j]); }
    }
    #pragma unroll
    for (int j = 0; j < 8; ++j) {
      float vm = (j == 0) ? lft : v[j - 1];
      float vp = (j == 7) ? rgt : v[j + 1];
      acc[j] += vm * wm[j] + v[j] * wc[j] + vp * wp[j];
    }
  }
  u16x8 st;
  #pragma unroll
  for (int j = 0; j < 8; ++j) st[j] = f2b(acc[j]);
  *(u16x8*)&y[cbase + p0] = st;
}

// ---------- flash attention partial (proven structure, NSPLIT=6) ----------
__global__ __launch_bounds__(256)
void attn_part_k(const u16* __restrict__ Qb, const u16* __restrict__ Kb,
                 const u16* __restrict__ Vb, u16* __restrict__ Op,
                 float* __restrict__ Lb) {
  __shared__ u16 Ks[64][40];
  __shared__ u16 Vs[32][72];      // [d][m] linear
  __shared__ u16 Ps[4][16][72];   // per-wave P tile [q][m]
  int h = blockIdx.y, n0 = blockIdx.x * 64, sz = blockIdx.z;
  int tid = threadIdx.x, lane = tid & 63, wv = tid >> 6;
  int frow = lane & 15, gq = lane >> 4, kgrp = gq * 8;
  int ml = tid >> 2, dseg = (tid & 3) * 8;
  int vd = tid >> 3, vm = (tid & 7) * 8;
  const float QS = 0.17677669529663687f * 1.4426950408889634f;  // scale*log2e
  s16x8 aq;
  {
    u16x8 qv = *(const u16x8*)&Qb[(size_t)(n0 + wv * 16 + frow) * 256 + h * 32 + kgrp];
    u16x8 qs;
    #pragma unroll
    for (int j = 0; j < 8; ++j) qs[j] = f2b(b2f(qv[j]) * QS);
    aq = *(s16x8*)&qs;
  }
  f32x4 oa0 = {0.f, 0.f, 0.f, 0.f}, oa1 = {0.f, 0.f, 0.f, 0.f};
  float lsum = 0.f;
  int t_begin = (49 * sz) / NSPLIT, t_end = (49 * (sz + 1)) / NSPLIT;
  u16x8 kreg = *(const u16x8*)&Kb[(size_t)(t_begin * 64 + ml) * 256 + h * 32 + dseg];
  u16x8 vreg = *(const u16x8*)&Vb[(size_t)(h * 32 + vd) * HWP + t_begin * 64 + vm];
  for (int t = t_begin; t < t_end; ++t) {
    __syncthreads();
    *(u16x8*)&Ks[ml][dseg] = kreg;
    *(u16x8*)&Vs[vd][vm] = vreg;
    if (t + 1 < t_end) {
      kreg = *(const u16x8*)&Kb[(size_t)((t + 1) * 64 + ml) * 256 + h * 32 + dseg];
      vreg = *(const u16x8*)&Vb[(size_t)(h * 32 + vd) * HWP + (t + 1) * 64 + vm];
    }
    __syncthreads();
    f32x4 zero = {0.f, 0.f, 0.f, 0.f};
    #pragma unroll
    for (int fm = 0; fm < 4; ++fm) {
      s16x8 ak = *(const s16x8*)&Ks[fm * 16 + frow][kgrp];
      f32x4 s = mfma16(ak, aq, zero);       // D[m][q]: rows=m, col=q=frow
      u16x4 pe;
      #pragma unroll
      for (int r = 0; r < 4; ++r) {
        float e = exp2f(fminf(s[r], 43.f));
        lsum += e;
        pe[r] = (u16)(__float_as_uint(e) >> 16);  // trunc-to-bf16 (P in (0,1])
      }
      *(u16x4*)&Ps[wv][frow][fm * 16 + gq * 4] = pe;
    }
    #pragma unroll
    for (int ks = 0; ks < 2; ++ks) {
      s16x8 ap = *(const s16x8*)&Ps[wv][frow][ks * 32 + kgrp];
      s16x8 bv0 = *(const s16x8*)&Vs[frow][ks * 32 + kgrp];
      s16x8 bv1 = *(const s16x8*)&Vs[16 + frow][ks * 32 + kgrp];
      oa0 = mfma16(ap, bv0, oa0);
      oa1 = mfma16(ap, bv1, oa1);
    }
  }
  lsum += __shfl_xor(lsum, 16);
  lsum += __shfl_xor(lsum, 32);
  if (lane < 16)
    Lb[(size_t)(sz * 8 + h) * HWP + n0 + wv * 16 + frow] = lsum;
  #pragma unroll
  for (int r = 0; r < 4; ++r) {
    int n = n0 + wv * 16 + gq * 4 + r;
    Op[(size_t)(sz * 256 + h * 32 + frow) * HWP + n]      = f2b(oa0[r]);
    Op[(size_t)(sz * 256 + h * 32 + 16 + frow) * HWP + n] = f2b(oa1[r]);
  }
}

extern "C" void kernel_launch(void* const* d_in, const int* in_sizes, int n_in,
                              void* d_out, int out_size, void* d_ws, size_t ws_size,
                              hipStream_t stream) {
  const void* dec   = d_in[0];
  const void* enc   = d_in[1];
  const void* dw_w  = d_in[2];
  const void* dw_b  = d_in[3];
  const void* p1_w  = d_in[4];
  const void* p1_b  = d_in[5];
  const void* p2_w  = d_in[6];
  const void* p2_b  = d_in[7];
  const void* c1_w  = d_in[8];
  const void* c1_b  = d_in[9];
  const void* c2_w  = d_in[10];
  const void* c2_b  = d_in[11];
  const void* q_w   = d_in[12];
  const void* q_b   = d_in[13];
  const void* kv_w  = d_in[14];
  const void* kv_b  = d_in[15];
  const void* out_w = d_in[16];
  const void* out_b = d_in[17];
  const void* fu_w  = d_in[18];
  const void* fu_b  = d_in[19];

  const int CH = CC * HWP;     // 802816
  float* flag = (float*)d_ws;                       // 8 floats
  u16* pk     = (u16*)(flag + 8);
  u16* A      = pk;              pk += CH;            // dwconv out / attn out
  u16* hid    = pk;              pk += 128 * HWP;
  u16* s9     = pk;              pk += 9 * HWP;
  u16* Bb     = pk;              pk += CH;            // f_smooth / f_high
  u16* qb16   = pk;              pk += CH;            // q; later c1-partials / fused_in
  u16* k16    = pk;              pk += CH;            // K [m][256]
  u16* v16    = pk;              pk += CH;            // V [d][HWP]
  u16* wp_p1  = pk;              pk += 128 * 256;
  u16* wp_q   = pk;              pk += 256 * 256;
  u16* wp_kv  = pk;              pk += 512 * 256;
  u16* wp_out = pk;              pk += 256 * 256;
  u16* wp_c1  = pk;              pk += 128 * 256 * 9;
  u16* wp_fu  = pk;              pk += 256 * 256 * 9;
  pk += (size_t)(-(intptr_t)pk) & 7;                  // 16B align
  float* Lb   = (float*)pk;                           // 48*HWP f32
  u16* Opart  = (u16*)(Lb + 48 * HWP);                // 1536*HWP u16
  // c1 partials: 3*128*HWP f32 = 4.8MB, aliases qb16+k16+v16 (dead after
  // attn_part; consumed by comb3 before outproj rewrites qb16).
  float* Pc1 = (float*)qb16;
  // fu partials: 2*256*HWP f32 = 6.4MB, aliases Lb/Opart (dead after stage2).
  float* Pfu = Lb;

  dim3 blk(256);
  detect_dtype_k<<<1, blk, 0, stream>>>(dec, flag);

  // ---- pack ALL weights (one launch) ----
  pack_all_k<<<1536, blk, 0, stream>>>(p1_w, q_w, kv_w, out_w, c1_w, fu_w,
                                       wp_p1, wp_q, wp_kv, wp_out, wp_c1, wp_fu,
                                       flag);

  // ---- stage1: dwconv (ALPF) + merged kv proj, one launch ----
  stage1_k<<<1960, blk, 0, stream>>>(dec, dw_w, dw_b, A, wp_kv, enc, kv_b,
                                     k16, flag);

  // ---- ALPF chain ----
  mgemm32_k<1, 1, false, 3><<<dim3(98, 4), blk, 0, stream>>>(
      wp_p1, A, p1_b, nullptr, hid, 256, flag, 3, 0);
  pw9_v2_k<false><<<98, blk, 0, stream>>>(p2_w, p2_b, hid, s9, flag);
  spatial_v2_k<false><<<784, dim3(128), 0, stream>>>(dec, s9, Bb, flag);
  mgemm32_k<1, 0, false, 2><<<dim3(98, 8), blk, 0, stream>>>(
      wp_q, Bb, q_b, nullptr, qb16, 256, flag, 3, 0);

  // ---- attention: 6-way KV-split partials ----
  attn_part_k<<<dim3(49, 8, NSPLIT), blk, 0, stream>>>(qb16, k16, v16, Opart, Lb);

  // ---- stage2: attn combine + c1 tap-split partials, one launch ----
  stage2_k<<<1568, blk, 0, stream>>>(Opart, Lb, A, wp_c1, enc, Pc1, flag);

  // ---- AHPF chain ----
  comb3_v2_k<<<392, blk, 0, stream>>>(Pc1, c1_b, hid, flag);
  pw9_v2_k<true><<<98, blk, 0, stream>>>(c2_w, c2_b, hid, s9, flag);
  spatial_v2_k<true><<<784, dim3(128), 0, stream>>>(enc, s9, Bb, flag);

  // ---- out proj + f_high add -> bf16 [p][256] (qb16 region, c1p dead) ----
  mgemm32_k<1, 0, true, 2><<<dim3(98, 8), blk, 0, stream>>>(
      wp_out, A, out_b, Bb, qb16, 256, flag, 3, 0);

  // ---- fusion 3x3 conv: 2-way tap-split + combine -> d_out ----
  mgemm32_k<9, 0, false, 4><<<dim3(98, 8, 2), blk, 0, stream>>>(
      wp_fu, qb16, nullptr, nullptr, Pfu, 256, flag, 2, 0);
  comb2_v2_k<<<784, blk, 0, stream>>>(Pfu, fu_b, d_out, flag);
}

// Round 20
// 135.295 us; speedup vs baseline: 1.7969x; 1.0788x over previous
//
#include <hip/hip_runtime.h>
#include <hip/hip_bf16.h>

#define HH  56
#define WWC 56
#define HWP 3136   // 56*56 = 49*64
#define CC  256
#define NSPLIT 6

typedef unsigned short u16;
typedef __attribute__((ext_vector_type(8))) u16 u16x8;
typedef __attribute__((ext_vector_type(4))) u16 u16x4;
typedef __attribute__((ext_vector_type(8))) short s16x8;   // bf16x8 MFMA frag
typedef __attribute__((ext_vector_type(4))) float f32x4;

__device__ __forceinline__ u16 f2b(float f) {
  unsigned int x = __float_as_uint(f);
  return (u16)((x + 0x7fffu + ((x >> 16) & 1u)) >> 16);
}
__device__ __forceinline__ float b2f(u16 u) {
  return __uint_as_float(((unsigned int)u) << 16);
}
__device__ __forceinline__ f32x4 mfma16(s16x8 a, s16x8 b, f32x4 c) {
  return __builtin_amdgcn_mfma_f32_16x16x32_bf16(a, b, c, 0, 0, 0);
}

// ---------- dtype-flexible load/store (flag decided on device) ----------
__device__ __forceinline__ float ldsel(const void* p, int i, bool bf) {
  if (bf) return __bfloat162float(((const __hip_bfloat16*)p)[i]);
  return ((const float*)p)[i];
}
__device__ __forceinline__ void stsel(void* p, int i, float v, bool bf) {
  if (bf) ((__hip_bfloat16*)p)[i] = __float2bfloat16(v);
  else ((float*)p)[i] = v;
}

// load 8 consecutive elements (index 8-aligned) as floats, dtype per flag
__device__ __forceinline__ void ldrow8(const void* p, size_t i, bool bf,
                                       float* o) {
  if (bf) {
    u16x8 v = *(const u16x8*)((const u16*)p + i);
    #pragma unroll
    for (int j = 0; j < 8; ++j) o[j] = b2f(v[j]);
  } else {
    const float* f = (const float*)p + i;
    f32x4 a = *(const f32x4*)f;
    f32x4 b = *(const f32x4*)(f + 4);
    #pragma unroll
    for (int j = 0; j < 4; ++j) { o[j] = a[j]; o[4 + j] = b[j]; }
  }
}

__global__ void detect_dtype_k(const void* x, float* flag) {
  __shared__ int sh[256];
  int tid = threadIdx.x;
  const __hip_bfloat16* xb = (const __hip_bfloat16*)x;
  int ok = 0;
  for (int i = tid; i < 1024; i += 256) {
    float v = fabsf(__bfloat162float(xb[2 * i]));
    if (v > 9.5e-7f && v < 1.05e6f) ok++;
  }
  sh[tid] = ok;
  __syncthreads();
  for (int s = 128; s > 0; s >>= 1) {
    if (tid < s) sh[tid] += sh[tid + s];
    __syncthreads();
  }
  if (tid == 0) flag[0] = (sh[0] > 512) ? 1.f : 0.f;
}

// ---------- fused weight pack: all 6 weights in ONE launch ----------
__global__ __launch_bounds__(256)
void pack_all_k(const void* __restrict__ p1, const void* __restrict__ q,
                const void* __restrict__ kv, const void* __restrict__ ow,
                const void* __restrict__ c1, const void* __restrict__ fu,
                u16* __restrict__ d_p1, u16* __restrict__ d_q,
                u16* __restrict__ d_kv, u16* __restrict__ d_ow,
                u16* __restrict__ d_c1, u16* __restrict__ d_fu,
                const float* __restrict__ dflag) {
  bool bf = dflag[0] > 0.5f;
  int b = blockIdx.x, tid = threadIdx.x;
  if (b < 128) { int g = b * 256 + tid; d_p1[g] = f2b(ldsel(p1, g, bf)); return; }
  b -= 128;
  if (b < 256) { int g = b * 256 + tid; d_q[g] = f2b(ldsel(q, g, bf)); return; }
  b -= 256;
  if (b < 512) { int g = b * 256 + tid; d_kv[g] = f2b(ldsel(kv, g, bf)); return; }
  b -= 512;
  if (b < 256) { int g = b * 256 + tid; d_ow[g] = f2b(ldsel(ow, g, bf)); return; }
  b -= 256;
  if (b < 128) {
    int g = b * 256 + tid;
    #pragma unroll
    for (int t = 0; t < 9; ++t)
      d_c1[(size_t)t * 32768 + g] = f2b(ldsel(c1, g * 9 + t, bf));
    return;
  }
  b -= 128;
  {
    int g = b * 256 + tid;
    #pragma unroll
    for (int t = 0; t < 9; ++t)
      d_fu[(size_t)t * 65536 + g] = f2b(ldsel(fu, g * 9 + t, bf));
  }
}

// ---------- dwconv body: 8 pixels/thread (gid over 100352) ----------
__device__ __forceinline__ void dwconv_body(int gid, const void* x,
                                            const void* wt, const void* bs,
                                            u16* y, bool bf) {
  int c = gid / 392, g = gid - c * 392;
  int p0 = g * 8;
  int h = p0 / WWC, w0 = p0 - h * WWC;
  float wv[9];
  #pragma unroll
  for (int t = 0; t < 9; ++t) wv[t] = ldsel(wt, c * 9 + t, bf);
  float bv = ldsel(bs, c, bf);
  float acc[8];
  #pragma unroll
  for (int j = 0; j < 8; ++j) acc[j] = bv;
  const size_t cbase = (size_t)c * HWP;
  #pragma unroll
  for (int dh = -1; dh <= 1; ++dh) {
    int hh = h + dh;
    if (hh < 0 || hh >= HH) continue;
    size_t rbase = cbase + hh * WWC + w0;
    float v[8];
    ldrow8(x, rbase, bf, v);
    float lft = (w0 > 0) ? ldsel(x, rbase - 1, bf) : 0.f;
    float rgt = (w0 < 48) ? ldsel(x, rbase + 8, bf) : 0.f;
    float wm = wv[(dh + 1) * 3 + 0], wc = wv[(dh + 1) * 3 + 1],
          wp = wv[(dh + 1) * 3 + 2];
    #pragma unroll
    for (int j = 0; j < 8; ++j) {
      float vm = (j == 0) ? lft : v[j - 1];
      float vp = (j == 7) ? rgt : v[j + 1];
      acc[j] += vm * wm + v[j] * wc + vp * wp;
    }
  }
  u16x8 st;
  #pragma unroll
  for (int j = 0; j < 8; ++j) st[j] = f2b(acc[j]);
  *(u16x8*)&y[cbase + p0] = st;
}

// ---------- spatial filter body: 8 pixels/thread (gid over 100352) ----------
template<bool HIGH>
__device__ __forceinline__ void spatial_body(int gid, const void* x,
                                             const u16* w9, u16* y, bool bf) {
  int c = gid / 392, g = gid - c * 392;
  int p0 = g * 8;
  int h = p0 / WWC, w0 = p0 - h * WWC;
  const size_t cbase = (size_t)c * HWP;
  float acc[8];
  if (HIGH) {
    ldrow8(x, cbase + p0, bf, acc);
  } else {
    #pragma unroll
    for (int j = 0; j < 8; ++j) acc[j] = 0.f;
  }
  #pragma unroll
  for (int dh = -1; dh <= 1; ++dh) {
    int hh = h + dh;
    if (hh < 0 || hh >= HH) continue;
    size_t rbase = cbase + hh * WWC + w0;
    float v[8];
    ldrow8(x, rbase, bf, v);
    float lft = (w0 > 0) ? ldsel(x, rbase - 1, bf) : 0.f;
    float rgt = (w0 < 48) ? ldsel(x, rbase + 8, bf) : 0.f;
    float wm[8], wc[8], wp[8];
    {
      int tb = (dh + 1) * 3;
      u16x8 a = *(const u16x8*)&w9[(size_t)(tb + 0) * HWP + p0];
      u16x8 b = *(const u16x8*)&w9[(size_t)(tb + 1) * HWP + p0];
      u16x8 d = *(const u16x8*)&w9[(size_t)(tb + 2) * HWP + p0];
      #pragma unroll
      for (int j = 0; j < 8; ++j) { wm[j] = b2f(a[j]); wc[j] = b2f(b[j]); wp[j] = b2f(d[j]); }
    }
    #pragma unroll
    for (int j = 0; j < 8; ++j) {
      float vm = (j == 0) ? lft : v[j - 1];
      float vp = (j == 7) ? rgt : v[j + 1];
      acc[j] += vm * wm[j] + v[j] * wc[j] + vp * wp[j];
    }
  }
  u16x8 st;
  #pragma unroll
  for (int j = 0; j < 8; ++j) st[j] = f2b(acc[j]);
  *(u16x8*)&y[cbase + p0] = st;
}

// ---------- pw9 body (block pblk of 98): 1x1 128->9 + softmax ----------
template<bool DELTA>
__device__ __forceinline__ void pw9_body(int pblk, const void* w2,
                                         const void* b2, const u16* hid,
                                         u16* out9, bool bf) {
  __shared__ float Wl[9][128];
  __shared__ float Pl[4][9][33];
  int tid = threadIdx.x;
  for (int i = tid; i < 1152; i += 256) Wl[i >> 7][i & 127] = ldsel(w2, i, bf);
  __syncthreads();
  int pix = tid & 31, cig = tid >> 5;
  int p = pblk * 32 + pix;
  int ci0 = cig * 16;
  float acc[9] = {0.f, 0.f, 0.f, 0.f, 0.f, 0.f, 0.f, 0.f, 0.f};
  #pragma unroll
  for (int j = 0; j < 16; ++j) {
    float xv = b2f(hid[(size_t)(ci0 + j) * HWP + p]);
    #pragma unroll
    for (int t = 0; t < 9; ++t) acc[t] += Wl[t][ci0 + j] * xv;
  }
  #pragma unroll
  for (int t = 0; t < 9; ++t) acc[t] += __shfl_xor(acc[t], 32);
  int wv = tid >> 6;
  if ((tid & 63) < 32) {
    #pragma unroll
    for (int t = 0; t < 9; ++t) Pl[wv][t][pix] = acc[t];
  }
  __syncthreads();
  if (tid < 32) {
    float a[9];
    #pragma unroll
    for (int t = 0; t < 9; ++t)
      a[t] = Pl[0][t][pix] + Pl[1][t][pix] + Pl[2][t][pix] + Pl[3][t][pix] +
             ldsel(b2, t, bf);
    float mx = a[0];
    #pragma unroll
    for (int t = 1; t < 9; ++t) mx = fmaxf(mx, a[t]);
    float s = 0.f;
    #pragma unroll
    for (int t = 0; t < 9; ++t) { a[t] = __expf(a[t] - mx); s += a[t]; }
    float inv = 1.f / s;
    #pragma unroll
    for (int t = 0; t < 9; ++t) {
      float v = a[t] * inv;
      if (DELTA) v = ((t == 4) ? 1.f : 0.f) - v;
      out9[(size_t)t * HWP + p] = f2b(v);
    }
  }
}

// ---------- MFMA GEMM body, 32x32 tile ----------
// OMODE 0 fp32 [o][p]; 1 flag [o][p]; 2 bf16 [p][o](+ACT/ADDIN); 3 bf16 [o][p];
// OMODE 4 fp32 partial [sz][o][p]; OMODE 5 dual KV.
// xmode 0 fp32 [Cin][HW]; 1 flag [Cin][HW]; 2 bf16 [p][Cin]; 3 bf16 [Cin][HW].
template<int TAPS, int ACT, bool ADDIN, int OMODE>
__device__ __forceinline__ void mgemm_body(
    int bid, int sz, int NZ, int NO, int O,
    const u16* __restrict__ Wp, const void* __restrict__ X,
    const void* __restrict__ bias, const u16* __restrict__ addin,
    void* __restrict__ Y, int Cin, bool wbf, bool xbf, int xmode,
    int bias_off, u16 (*Ws)[72], u16 (*Xs)[72]) {
  int p0 = (bid / NO) * 32, o0 = (bid % NO) * 32;
  int t0 = (TAPS * sz) / NZ, t1 = (TAPS * (sz + 1)) / NZ;
  int tid = threadIdx.x, lane = tid & 63, wv = tid >> 6;
  int oq = (wv & 1) * 16, pq = (wv >> 1) * 16;
  int frow = lane & 15, kgrp = (lane >> 4) * 8;
  int wol = tid >> 3, wkk = (tid & 7) * 8;
  int pl = tid & 31, xkk = (tid >> 5) * 8;
  int p = p0 + pl, h = p / WWC, w = p - h * WWC;
  f32x4 acc = {0.f, 0.f, 0.f, 0.f};
  for (int t = t0; t < t1; ++t) {
    int dh = t / 3 - 1, dw = t % 3 - 1;
    int hh = h + dh, ww = w + dw;
    bool rowok = (TAPS == 1) || ((hh >= 0) && (hh < HH) && (ww >= 0) && (ww < WWC));
    int xoff = (TAPS == 1) ? p : hh * WWC + ww;
    const u16* Wrow = Wp + (size_t)t * O * Cin;
    for (int kb = 0; kb < Cin; kb += 64) {
      __syncthreads();
      *(u16x8*)&Ws[wol][wkk] =
          *(const u16x8*)&Wrow[(size_t)(o0 + wol) * Cin + kb + wkk];
      {
        u16x8 xv;
        if (xmode == 2) {
          if (rowok) {
            xv = *(const u16x8*)&((const u16*)X)[(size_t)xoff * Cin + kb + xkk];
          } else {
            #pragma unroll
            for (int j = 0; j < 8; ++j) xv[j] = 0;
          }
        } else if (xmode == 3) {
          #pragma unroll
          for (int j = 0; j < 8; ++j)
            xv[j] = rowok ? ((const u16*)X)[(size_t)(kb + xkk + j) * HWP + xoff]
                          : (u16)0;
        } else {
          #pragma unroll
          for (int j = 0; j < 8; ++j) {
            int kk = xkk + j;
            float v = rowok ? ldsel(X, (size_t)(kb + kk) * HWP + xoff, xbf) : 0.f;
            xv[j] = f2b(v);
          }
        }
        *(u16x8*)&Xs[pl][xkk] = xv;
      }
      __syncthreads();
      #pragma unroll
      for (int ks = 0; ks < 2; ++ks) {
        s16x8 aw = *(const s16x8*)&Ws[oq + frow][ks * 32 + kgrp];
        s16x8 ax = *(const s16x8*)&Xs[pq + frow][ks * 32 + kgrp];
        acc = mfma16(aw, ax, acc);
      }
    }
  }
  // D mapping (verified): col = lane&15 -> p, row = (lane>>4)*4+r -> o
  int orow = (lane >> 4) * 4;
  int ogb = o0 + oq + orow;
  int pg = p0 + pq + frow;
  if (OMODE == 4) {
    float* Yp = (float*)Y + (size_t)sz * O * HWP;
    #pragma unroll
    for (int r = 0; r < 4; ++r)
      Yp[(size_t)(ogb + r) * HWP + pg] = acc[r];
  } else if (OMODE == 5) {
    if (ogb < 256) {
      u16x4 st;
      #pragma unroll
      for (int r = 0; r < 4; ++r)
        st[r] = f2b(acc[r] + ldsel(bias, ogb + r, wbf));
      *(u16x4*)&((u16*)Y)[(size_t)pg * 256 + ogb] = st;
    } else {
      u16* V = (u16*)Y + (size_t)CC * HWP;
      #pragma unroll
      for (int r = 0; r < 4; ++r)
        V[(size_t)(ogb + r - 256) * HWP + pg] =
            f2b(acc[r] + ldsel(bias, ogb + r, wbf));
    }
  } else if (OMODE == 2) {
    u16x4 st;
    #pragma unroll
    for (int r = 0; r < 4; ++r) {
      float yv = acc[r] + ldsel(bias, bias_off + ogb + r, wbf);
      if (ACT == 1) yv = (yv >= 0.f) ? yv : 0.2f * yv;
      if (ADDIN) yv += b2f(addin[(size_t)(ogb + r) * HWP + pg]);
      st[r] = f2b(yv);
    }
    *(u16x4*)&((u16*)Y)[(size_t)pg * O + ogb] = st;
  } else {
    #pragma unroll
    for (int r = 0; r < 4; ++r) {
      int og = ogb + r;
      float yv = acc[r] + ldsel(bias, bias_off + og, wbf);
      if (ACT == 1) yv = (yv >= 0.f) ? yv : 0.2f * yv;
      if (ADDIN) yv += b2f(addin[(size_t)og * HWP + pg]);
      if (OMODE == 3) ((u16*)Y)[(size_t)og * HWP + pg] = f2b(yv);
      else stsel(Y, (size_t)og * HWP + pg, yv, (OMODE == 1) && wbf);
    }
  }
}

// ---------- standalone mgemm kernel ----------
template<int TAPS, int ACT, bool ADDIN, int OMODE>
__global__ __launch_bounds__(256)
void mgemm32_k(const u16* __restrict__ Wp, const void* __restrict__ X,
               const void* __restrict__ bias, const u16* __restrict__ addin,
               void* __restrict__ Y, int Cin,
               const float* __restrict__ dflag, int xmode, int bias_off) {
  __shared__ u16 Ws[32][72];
  __shared__ u16 Xs[32][72];
  bool wbf = dflag[0] > 0.5f;
  bool xbf = (xmode == 1) ? wbf : false;
  int NO = gridDim.y;
  int bid = blockIdx.x + blockIdx.y * gridDim.x;
  mgemm_body<TAPS, ACT, ADDIN, OMODE>(bid, blockIdx.z, gridDim.z, NO, NO * 32,
                                      Wp, X, bias, addin, Y, Cin, wbf, xbf,
                                      xmode, bias_off, Ws, Xs);
}

// ---------- stage1: dwconv (0..391) + merged kv proj (392..1959) ----------
__global__ __launch_bounds__(256)
void stage1_k(const void* __restrict__ dec, const void* __restrict__ dw_w,
              const void* __restrict__ dw_b, u16* __restrict__ A,
              const u16* __restrict__ wp_kv, const void* __restrict__ enc,
              const void* __restrict__ kv_b, u16* __restrict__ k16,
              const float* __restrict__ dflag) {
  __shared__ u16 Ws[32][72];
  __shared__ u16 Xs[32][72];
  bool bf = dflag[0] > 0.5f;
  int b = blockIdx.x;
  if (b < 392) {
    dwconv_body(b * 256 + threadIdx.x, dec, dw_w, dw_b, A, bf);
  } else {
    mgemm_body<1, 0, false, 5>(b - 392, 0, 1, 16, 512, wp_kv, enc, kv_b,
                               nullptr, k16, 256, bf, bf, 1, 0, Ws, Xs);
  }
}

// ---------- stageA: p1 gemm (0..391) + c1 tap-partials (392..1567) ----------
__global__ __launch_bounds__(256)
void stageA_k(const u16* __restrict__ wp_p1, const u16* __restrict__ A,
              const void* __restrict__ p1_b, u16* __restrict__ hid,
              const u16* __restrict__ wp_c1, const void* __restrict__ enc,
              float* __restrict__ Pc1, const float* __restrict__ dflag) {
  __shared__ u16 Ws[32][72];
  __shared__ u16 Xs[32][72];
  bool bf = dflag[0] > 0.5f;
  int b = blockIdx.x;
  if (b < 392) {
    mgemm_body<1, 1, false, 3>(b, 0, 1, 4, 128, wp_p1, A, p1_b, nullptr,
                               hid, 256, bf, false, 3, 0, Ws, Xs);
  } else {
    int rem = b - 392;                 // 0..1175
    int sz = rem / 392, bb = rem - sz * 392;
    mgemm_body<9, 1, false, 4>(bb, sz, 3, 4, 128, wp_c1, enc, nullptr,
                               nullptr, Pc1, 256, bf, bf, 1, 0, Ws, Xs);
  }
}

// ---------- stageB: pw9-ALPF (0..97) + c1 combine -> hid2 (98..489) ----------
__global__ __launch_bounds__(256)
void stageB_k(const void* __restrict__ p2_w, const void* __restrict__ p2_b,
              const u16* __restrict__ hid, u16* __restrict__ s9,
              const float* __restrict__ Pc1, const void* __restrict__ c1_b,
              u16* __restrict__ hid2, const float* __restrict__ dflag) {
  bool bf = dflag[0] > 0.5f;
  int b = blockIdx.x;
  if (b < 98) {
    pw9_body<false>(b, p2_w, p2_b, hid, s9, bf);
  } else {
    int flat = ((b - 98) * 256 + threadIdx.x) * 4;   // 128*HWP
    int o = flat / HWP;
    f32x4 a = *(const f32x4*)&Pc1[flat];
    f32x4 c = *(const f32x4*)&Pc1[flat + 128 * HWP];
    f32x4 d = *(const f32x4*)&Pc1[flat + 2 * 128 * HWP];
    float bv = ldsel(c1_b, o, bf);
    u16x4 st;
    #pragma unroll
    for (int j = 0; j < 4; ++j) {
      float v = a[j] + c[j] + d[j] + bv;
      v = (v >= 0.f) ? v : 0.2f * v;
      st[j] = f2b(v);
    }
    *(u16x4*)&hid2[flat] = st;
  }
}

// ---------- stageC: spatial-ALPF (0..391) + pw9-AHPF -> s9b (392..489) ----------
__global__ __launch_bounds__(256)
void stageC_k(const void* __restrict__ dec, const u16* __restrict__ s9,
              u16* __restrict__ Bb, const void* __restrict__ c2_w,
              const void* __restrict__ c2_b, const u16* __restrict__ hid2,
              u16* __restrict__ s9b, const float* __restrict__ dflag) {
  bool bf = dflag[0] > 0.5f;
  int b = blockIdx.x;
  if (b < 392) {
    spatial_body<false>(b * 256 + threadIdx.x, dec, s9, Bb, bf);
  } else {
    pw9_body<true>(b - 392, c2_w, c2_b, hid2, s9b, bf);
  }
}

// ---------- stageD: q proj (0..783) + spatial-AHPF -> Bb2 (784..1175) ----------
__global__ __launch_bounds__(256)
void stageD_k(const u16* __restrict__ wp_q, const u16* __restrict__ Bb,
              const void* __restrict__ q_b, u16* __restrict__ qb16,
              const void* __restrict__ enc, const u16* __restrict__ s9b,
              u16* __restrict__ Bb2, const float* __restrict__ dflag) {
  __shared__ u16 Ws[32][72];
  __shared__ u16 Xs[32][72];
  bool bf = dflag[0] > 0.5f;
  int b = blockIdx.x;
  if (b < 784) {
    mgemm_body<1, 0, false, 2>(b, 0, 1, 8, 256, wp_q, Bb, q_b, nullptr,
                               qb16, 256, bf, false, 3, 0, Ws, Xs);
  } else {
    spatial_body<true>((b - 784) * 256 + threadIdx.x, enc, s9b, Bb2, bf);
  }
}

// ---------- flash attention partial (proven structure, NSPLIT=6) ----------
__global__ __launch_bounds__(256)
void attn_part_k(const u16* __restrict__ Qb, const u16* __restrict__ Kb,
                 const u16* __restrict__ Vb, u16* __restrict__ Op,
                 float* __restrict__ Lb) {
  __shared__ u16 Ks[64][40];
  __shared__ u16 Vs[32][72];      // [d][m] linear
  __shared__ u16 Ps[4][16][72];   // per-wave P tile [q][m]
  int h = blockIdx.y, n0 = blockIdx.x * 64, sz = blockIdx.z;
  int tid = threadIdx.x, lane = tid & 63, wv = tid >> 6;
  int frow = lane & 15, gq = lane >> 4, kgrp = gq * 8;
  int ml = tid >> 2, dseg = (tid & 3) * 8;
  int vd = tid >> 3, vm = (tid & 7) * 8;
  const float QS = 0.17677669529663687f * 1.4426950408889634f;  // scale*log2e
  s16x8 aq;
  {
    u16x8 qv = *(const u16x8*)&Qb[(size_t)(n0 + wv * 16 + frow) * 256 + h * 32 + kgrp];
    u16x8 qs;
    #pragma unroll
    for (int j = 0; j < 8; ++j) qs[j] = f2b(b2f(qv[j]) * QS);
    aq = *(s16x8*)&qs;
  }
  f32x4 oa0 = {0.f, 0.f, 0.f, 0.f}, oa1 = {0.f, 0.f, 0.f, 0.f};
  float lsum = 0.f;
  int t_begin = (49 * sz) / NSPLIT, t_end = (49 * (sz + 1)) / NSPLIT;
  u16x8 kreg = *(const u16x8*)&Kb[(size_t)(t_begin * 64 + ml) * 256 + h * 32 + dseg];
  u16x8 vreg = *(const u16x8*)&Vb[(size_t)(h * 32 + vd) * HWP + t_begin * 64 + vm];
  for (int t = t_begin; t < t_end; ++t) {
    __syncthreads();
    *(u16x8*)&Ks[ml][dseg] = kreg;
    *(u16x8*)&Vs[vd][vm] = vreg;
    if (t + 1 < t_end) {
      kreg = *(const u16x8*)&Kb[(size_t)((t + 1) * 64 + ml) * 256 + h * 32 + dseg];
      vreg = *(const u16x8*)&Vb[(size_t)(h * 32 + vd) * HWP + (t + 1) * 64 + vm];
    }
    __syncthreads();
    f32x4 zero = {0.f, 0.f, 0.f, 0.f};
    #pragma unroll
    for (int fm = 0; fm < 4; ++fm) {
      s16x8 ak = *(const s16x8*)&Ks[fm * 16 + frow][kgrp];
      f32x4 s = mfma16(ak, aq, zero);       // D[m][q]: rows=m, col=q=frow
      u16x4 pe;
      #pragma unroll
      for (int r = 0; r < 4; ++r) {
        float e = exp2f(fminf(s[r], 43.f));
        lsum += e;
        pe[r] = (u16)(__float_as_uint(e) >> 16);  // trunc-to-bf16 (P in (0,1])
      }
      *(u16x4*)&Ps[wv][frow][fm * 16 + gq * 4] = pe;
    }
    #pragma unroll
    for (int ks = 0; ks < 2; ++ks) {
      s16x8 ap = *(const s16x8*)&Ps[wv][frow][ks * 32 + kgrp];
      s16x8 bv0 = *(const s16x8*)&Vs[frow][ks * 32 + kgrp];
      s16x8 bv1 = *(const s16x8*)&Vs[16 + frow][ks * 32 + kgrp];
      oa0 = mfma16(ap, bv0, oa0);
      oa1 = mfma16(ap, bv1, oa1);
    }
  }
  lsum += __shfl_xor(lsum, 16);
  lsum += __shfl_xor(lsum, 32);
  if (lane < 16)
    Lb[(size_t)(sz * 8 + h) * HWP + n0 + wv * 16 + frow] = lsum;
  #pragma unroll
  for (int r = 0; r < 4; ++r) {
    int n = n0 + wv * 16 + gq * 4 + r;
    Op[(size_t)(sz * 256 + h * 32 + frow) * HWP + n]      = f2b(oa0[r]);
    Op[(size_t)(sz * 256 + h * 32 + 16 + frow) * HWP + n] = f2b(oa1[r]);
  }
}

// ---------- vectorized combine of NSPLIT attention partials -> bf16 ----------
__global__ __launch_bounds__(256)
void attn_combine_k(const u16* __restrict__ Op, const float* __restrict__ Lb,
                    u16* __restrict__ A) {
  int gid = blockIdx.x * 256 + threadIdx.x;   // 100352
  int hd = gid / 392, g = gid - hd * 392;
  int n0 = g * 8, h = hd >> 5;
  float L[8] = {0,0,0,0,0,0,0,0}, O[8] = {0,0,0,0,0,0,0,0};
  #pragma unroll
  for (int s = 0; s < NSPLIT; ++s) {
    const float* Lp = &Lb[(size_t)(s * 8 + h) * HWP + n0];
    f32x4 l0 = *(const f32x4*)Lp;
    f32x4 l1 = *(const f32x4*)(Lp + 4);
    u16x8 ov = *(const u16x8*)&Op[(size_t)(s * 256 + hd) * HWP + n0];
    #pragma unroll
    for (int j = 0; j < 4; ++j) { L[j] += l0[j]; L[4 + j] += l1[j]; }
    #pragma unroll
    for (int j = 0; j < 8; ++j) O[j] += b2f(ov[j]);
  }
  u16x8 st;
  #pragma unroll
  for (int j = 0; j < 8; ++j) st[j] = f2b(O[j] / L[j]);
  *(u16x8*)&A[(size_t)hd * HWP + n0] = st;
}

// ---------- combine 3 fu partials + bias -> flag-dtype d_out, x4 ----------
__global__ __launch_bounds__(256)
void comb3f_k(const float* __restrict__ P, const void* __restrict__ bias,
              void* __restrict__ Y, const float* __restrict__ dflag) {
  bool bf = dflag[0] > 0.5f;
  int flat = (blockIdx.x * 256 + threadIdx.x) * 4;   // 256*HWP total
  int o = flat / HWP;
  f32x4 a = *(const f32x4*)&P[flat];
  f32x4 c = *(const f32x4*)&P[flat + 256 * HWP];
  f32x4 d = *(const f32x4*)&P[flat + 2 * 256 * HWP];
  float bv = ldsel(bias, o, bf);
  if (bf) {
    u16x4 st;
    #pragma unroll
    for (int j = 0; j < 4; ++j) st[j] = f2b(a[j] + c[j] + d[j] + bv);
    *(u16x4*)&((u16*)Y)[flat] = st;
  } else {
    f32x4 st;
    #pragma unroll
    for (int j = 0; j < 4; ++j) st[j] = a[j] + c[j] + d[j] + bv;
    *(f32x4*)&((float*)Y)[flat] = st;
  }
}

extern "C" void kernel_launch(void* const* d_in, const int* in_sizes, int n_in,
                              void* d_out, int out_size, void* d_ws, size_t ws_size,
                              hipStream_t stream) {
  const void* dec   = d_in[0];
  const void* enc   = d_in[1];
  const void* dw_w  = d_in[2];
  const void* dw_b  = d_in[3];
  const void* p1_w  = d_in[4];
  const void* p1_b  = d_in[5];
  const void* p2_w  = d_in[6];
  const void* p2_b  = d_in[7];
  const void* c1_w  = d_in[8];
  const void* c1_b  = d_in[9];
  const void* c2_w  = d_in[10];
  const void* c2_b  = d_in[11];
  const void* q_w   = d_in[12];
  const void* q_b   = d_in[13];
  const void* kv_w  = d_in[14];
  const void* kv_b  = d_in[15];
  const void* out_w = d_in[16];
  const void* out_b = d_in[17];
  const void* fu_w  = d_in[18];
  const void* fu_b  = d_in[19];

  const int CH = CC * HWP;     // 802816
  float* flag = (float*)d_ws;                       // 8 floats
  u16* pk     = (u16*)(flag + 8);
  u16* A      = pk;              pk += CH;            // dwconv out / attn out
  u16* hid    = pk;              pk += 128 * HWP;     // ALPF hidden
  u16* hid2   = pk;              pk += 128 * HWP;     // AHPF hidden
  u16* s9     = pk;              pk += 9 * HWP;       // ALPF kw
  u16* s9b    = pk;              pk += 9 * HWP;       // AHPF whp
  u16* Bb     = pk;              pk += CH;            // f_smooth
  u16* Bb2    = pk;              pk += CH;            // f_high
  u16* qb16   = pk;              pk += CH;            // q; later fused_in
  u16* k16    = pk;              pk += CH;            // K [m][256]
  u16* v16    = pk;              pk += CH;            // V [d][HWP]
  u16* wp_p1  = pk;              pk += 128 * 256;
  u16* wp_q   = pk;              pk += 256 * 256;
  u16* wp_kv  = pk;              pk += 512 * 256;
  u16* wp_out = pk;              pk += 256 * 256;
  u16* wp_c1  = pk;              pk += 128 * 256 * 9;
  u16* wp_fu  = pk;              pk += 256 * 256 * 9;
  pk += (size_t)(-(intptr_t)pk) & 7;                  // 16B align
  float* Lb   = (float*)pk;                           // 48*HWP f32
  u16* Opart  = (u16*)(Lb + 48 * HWP);                // 1536*HWP u16 (10.2MB region)
  // c1 partials: 3*128*HWP f32 = 4.8MB in Lb region (free until attn_part;
  // consumed by stageB before attn_part runs).
  float* Pc1 = Lb;
  // fu partials: 3*256*HWP f32 = 9.63MB in Lb region (dead after combine).
  float* Pfu = Lb;

  dim3 blk(256);
  detect_dtype_k<<<1, blk, 0, stream>>>(dec, flag);

  // ---- pack ALL weights ----
  pack_all_k<<<1536, blk, 0, stream>>>(p1_w, q_w, kv_w, out_w, c1_w, fu_w,
                                       wp_p1, wp_q, wp_kv, wp_out, wp_c1, wp_fu,
                                       flag);

  // ---- stage1: dwconv + merged kv proj ----
  stage1_k<<<1960, blk, 0, stream>>>(dec, dw_w, dw_b, A, wp_kv, enc, kv_b,
                                     k16, flag);

  // ---- stageA: p1 gemm + c1 tap-partials ----
  stageA_k<<<1568, blk, 0, stream>>>(wp_p1, A, p1_b, hid, wp_c1, enc, Pc1, flag);

  // ---- stageB: pw9-ALPF + c1 combine -> hid2 ----
  stageB_k<<<490, blk, 0, stream>>>(p2_w, p2_b, hid, s9, Pc1, c1_b, hid2, flag);

  // ---- stageC: spatial-ALPF -> Bb + pw9-AHPF -> s9b ----
  stageC_k<<<490, blk, 0, stream>>>(dec, s9, Bb, c2_w, c2_b, hid2, s9b, flag);

  // ---- stageD: q proj -> qb16 + spatial-AHPF -> Bb2 ----
  stageD_k<<<1176, blk, 0, stream>>>(wp_q, Bb, q_b, qb16, enc, s9b, Bb2, flag);

  // ---- attention: 6-way KV-split partials + combine ----
  attn_part_k<<<dim3(49, 8, NSPLIT), blk, 0, stream>>>(qb16, k16, v16, Opart, Lb);
  attn_combine_k<<<392, blk, 0, stream>>>(Opart, Lb, A);

  // ---- out proj + f_high add -> bf16 [p][256] ----
  mgemm32_k<1, 0, true, 2><<<dim3(98, 8), blk, 0, stream>>>(
      wp_out, A, out_b, Bb2, qb16, 256, flag, 3, 0);

  // ---- fusion conv: 3-way tap-split + combine -> d_out ----
  mgemm32_k<9, 0, false, 4><<<dim3(98, 8, 3), blk, 0, stream>>>(
      wp_fu, qb16, nullptr, nullptr, Pfu, 256, flag, 2, 0);
  comb3f_k<<<784, blk, 0, stream>>>(Pfu, fu_b, d_out, flag);
}

// Round 22
// 121.342 us; speedup vs baseline: 2.0035x; 1.1150x over previous
//
#include <hip/hip_runtime.h>
#include <hip/hip_bf16.h>

#define HH  56
#define WWC 56
#define HWP 3136   // 56*56 = 49*64
#define CC  256
#define NSPLIT 6

typedef unsigned short u16;
typedef __attribute__((ext_vector_type(8))) u16 u16x8;
typedef __attribute__((ext_vector_type(4))) u16 u16x4;
typedef __attribute__((ext_vector_type(8))) short s16x8;   // bf16x8 MFMA frag
typedef __attribute__((ext_vector_type(4))) float f32x4;

__device__ __forceinline__ u16 f2b(float f) {
  unsigned int x = __float_as_uint(f);
  return (u16)((x + 0x7fffu + ((x >> 16) & 1u)) >> 16);
}
__device__ __forceinline__ float b2f(u16 u) {
  return __uint_as_float(((unsigned int)u) << 16);
}
__device__ __forceinline__ f32x4 mfma16(s16x8 a, s16x8 b, f32x4 c) {
  return __builtin_amdgcn_mfma_f32_16x16x32_bf16(a, b, c, 0, 0, 0);
}
// fp32 8-wide load (aligned)
__device__ __forceinline__ void ldrow8f(const float* p, size_t i, float* o) {
  f32x4 a = *(const f32x4*)(p + i);
  f32x4 b = *(const f32x4*)(p + i + 4);
  #pragma unroll
  for (int j = 0; j < 4; ++j) { o[j] = a[j]; o[4 + j] = b[j]; }
}

// ---------- pack ALL weights fp32 -> bf16 (1x1 copies + 3x3 tap-reorder) ----------
// segments: p1 128 | q 256 | kv 512 | out 256 | c1(9t) 128 | fu(9t) 256
__global__ __launch_bounds__(256)
void pack_all_k(const float* __restrict__ p1, const float* __restrict__ q,
                const float* __restrict__ kv, const float* __restrict__ ow,
                const float* __restrict__ c1, const float* __restrict__ fu,
                u16* __restrict__ d_p1, u16* __restrict__ d_q,
                u16* __restrict__ d_kv, u16* __restrict__ d_ow,
                u16* __restrict__ d_c1, u16* __restrict__ d_fu) {
  int b = blockIdx.x, tid = threadIdx.x;
  if (b < 128) { int g = b * 256 + tid; d_p1[g] = f2b(p1[g]); return; }
  b -= 128;
  if (b < 256) { int g = b * 256 + tid; d_q[g] = f2b(q[g]); return; }
  b -= 256;
  if (b < 512) { int g = b * 256 + tid; d_kv[g] = f2b(kv[g]); return; }
  b -= 512;
  if (b < 256) { int g = b * 256 + tid; d_ow[g] = f2b(ow[g]); return; }
  b -= 256;
  if (b < 128) {
    int g = b * 256 + tid;
    #pragma unroll
    for (int t = 0; t < 9; ++t)
      d_c1[(size_t)t * 32768 + g] = f2b(c1[g * 9 + t]);
    return;
  }
  b -= 128;
  {
    int g = b * 256 + tid;
    #pragma unroll
    for (int t = 0; t < 9; ++t)
      d_fu[(size_t)t * 65536 + g] = f2b(fu[g * 9 + t]);
  }
}

// ---------- dwconv body: fp32 in, bf16 out, 8 pixels/thread ----------
__device__ __forceinline__ void dwconv_body(int gid, const float* x,
                                            const float* wt, const float* bs,
                                            u16* y) {
  int c = gid / 392, g = gid - c * 392;
  int p0 = g * 8;
  int h = p0 / WWC, w0 = p0 - h * WWC;
  float wv[9];
  #pragma unroll
  for (int t = 0; t < 9; ++t) wv[t] = wt[c * 9 + t];
  float bv = bs[c];
  float acc[8];
  #pragma unroll
  for (int j = 0; j < 8; ++j) acc[j] = bv;
  const size_t cbase = (size_t)c * HWP;
  #pragma unroll
  for (int dh = -1; dh <= 1; ++dh) {
    int hh = h + dh;
    if (hh < 0 || hh >= HH) continue;
    size_t rbase = cbase + hh * WWC + w0;
    float v[8];
    ldrow8f(x, rbase, v);
    float lft = (w0 > 0) ? x[rbase - 1] : 0.f;
    float rgt = (w0 < 48) ? x[rbase + 8] : 0.f;
    float wm = wv[(dh + 1) * 3 + 0], wc = wv[(dh + 1) * 3 + 1],
          wp = wv[(dh + 1) * 3 + 2];
    #pragma unroll
    for (int j = 0; j < 8; ++j) {
      float vm = (j == 0) ? lft : v[j - 1];
      float vp = (j == 7) ? rgt : v[j + 1];
      acc[j] += vm * wm + v[j] * wc + vp * wp;
    }
  }
  u16x8 st;
  #pragma unroll
  for (int j = 0; j < 8; ++j) st[j] = f2b(acc[j]);
  *(u16x8*)&y[cbase + p0] = st;
}

// ---------- spatial filter body: fp32 x, bf16 w9, bf16 out ----------
template<bool HIGH>
__device__ __forceinline__ void spatial_body(int gid, const float* x,
                                             const u16* w9, u16* y) {
  int c = gid / 392, g = gid - c * 392;
  int p0 = g * 8;
  int h = p0 / WWC, w0 = p0 - h * WWC;
  const size_t cbase = (size_t)c * HWP;
  float acc[8];
  if (HIGH) {
    ldrow8f(x, cbase + p0, acc);
  } else {
    #pragma unroll
    for (int j = 0; j < 8; ++j) acc[j] = 0.f;
  }
  #pragma unroll
  for (int dh = -1; dh <= 1; ++dh) {
    int hh = h + dh;
    if (hh < 0 || hh >= HH) continue;
    size_t rbase = cbase + hh * WWC + w0;
    float v[8];
    ldrow8f(x, rbase, v);
    float lft = (w0 > 0) ? x[rbase - 1] : 0.f;
    float rgt = (w0 < 48) ? x[rbase + 8] : 0.f;
    float wm[8], wc[8], wp[8];
    {
      int tb = (dh + 1) * 3;
      u16x8 a = *(const u16x8*)&w9[(size_t)(tb + 0) * HWP + p0];
      u16x8 b = *(const u16x8*)&w9[(size_t)(tb + 1) * HWP + p0];
      u16x8 d = *(const u16x8*)&w9[(size_t)(tb + 2) * HWP + p0];
      #pragma unroll
      for (int j = 0; j < 8; ++j) { wm[j] = b2f(a[j]); wc[j] = b2f(b[j]); wp[j] = b2f(d[j]); }
    }
    #pragma unroll
    for (int j = 0; j < 8; ++j) {
      float vm = (j == 0) ? lft : v[j - 1];
      float vp = (j == 7) ? rgt : v[j + 1];
      acc[j] += vm * wm[j] + v[j] * wc[j] + vp * wp[j];
    }
  }
  u16x8 st;
  #pragma unroll
  for (int j = 0; j < 8; ++j) st[j] = f2b(acc[j]);
  *(u16x8*)&y[cbase + p0] = st;
}

// ---------- pw9 body (block pblk of 98): fp32 w2/b2, bf16 hid, bf16 out ----------
template<bool DELTA>
__device__ __forceinline__ void pw9_body(int pblk, const float* w2,
                                         const float* b2, const u16* hid,
                                         u16* out9) {
  __shared__ float Wl[9][128];
  __shared__ float Pl[4][9][33];
  int tid = threadIdx.x;
  for (int i = tid; i < 1152; i += 256) Wl[i >> 7][i & 127] = w2[i];
  __syncthreads();
  int pix = tid & 31, cig = tid >> 5;
  int p = pblk * 32 + pix;
  int ci0 = cig * 16;
  float acc[9] = {0.f, 0.f, 0.f, 0.f, 0.f, 0.f, 0.f, 0.f, 0.f};
  #pragma unroll
  for (int j = 0; j < 16; ++j) {
    float xv = b2f(hid[(size_t)(ci0 + j) * HWP + p]);
    #pragma unroll
    for (int t = 0; t < 9; ++t) acc[t] += Wl[t][ci0 + j] * xv;
  }
  #pragma unroll
  for (int t = 0; t < 9; ++t) acc[t] += __shfl_xor(acc[t], 32);
  int wv = tid >> 6;
  if ((tid & 63) < 32) {
    #pragma unroll
    for (int t = 0; t < 9; ++t) Pl[wv][t][pix] = acc[t];
  }
  __syncthreads();
  if (tid < 32) {
    float a[9];
    #pragma unroll
    for (int t = 0; t < 9; ++t)
      a[t] = Pl[0][t][pix] + Pl[1][t][pix] + Pl[2][t][pix] + Pl[3][t][pix] +
             b2[t];
    float mx = a[0];
    #pragma unroll
    for (int t = 1; t < 9; ++t) mx = fmaxf(mx, a[t]);
    float s = 0.f;
    #pragma unroll
    for (int t = 0; t < 9; ++t) { a[t] = __expf(a[t] - mx); s += a[t]; }
    float inv = 1.f / s;
    #pragma unroll
    for (int t = 0; t < 9; ++t) {
      float v = a[t] * inv;
      if (DELTA) v = ((t == 4) ? 1.f : 0.f) - v;
      out9[(size_t)t * HWP + p] = f2b(v);
    }
  }
}

// ---------- MFMA GEMM body, 32x32 tile ----------
// W: packed bf16 [t][O][Cin]. bias: fp32. addin: bf16 [o][HW].
// OMODE 2 bf16 [p][o](+ACT/ADDIN); 3 bf16 [o][p](+ACT); 4 fp32 partial; 5 dual KV.
// XMODE 0 fp32 X[Cin][HW]; 2 bf16 X[p][Cin]; 3 bf16 X[Cin][HW].
template<int TAPS, int ACT, bool ADDIN, int OMODE, int XMODE>
__device__ __forceinline__ void mgemm_body(
    int bid, int sz, int NZ, int NO, int O,
    const u16* __restrict__ Wp, const void* __restrict__ X,
    const float* __restrict__ bias, const u16* __restrict__ addin,
    void* __restrict__ Y, int Cin, u16 (*Ws)[72], u16 (*Xs)[72]) {
  int p0 = (bid / NO) * 32, o0 = (bid % NO) * 32;
  int t0 = (TAPS * sz) / NZ, t1 = (TAPS * (sz + 1)) / NZ;
  int tid = threadIdx.x, lane = tid & 63, wv = tid >> 6;
  int oq = (wv & 1) * 16, pq = (wv >> 1) * 16;
  int frow = lane & 15, kgrp = (lane >> 4) * 8;
  int wol = tid >> 3, wkk = (tid & 7) * 8;
  int pl = tid & 31, xkk = (tid >> 5) * 8;
  int p = p0 + pl, h = p / WWC, w = p - h * WWC;
  f32x4 acc = {0.f, 0.f, 0.f, 0.f};
  for (int t = t0; t < t1; ++t) {
    int dh = t / 3 - 1, dw = t % 3 - 1;
    int hh = h + dh, ww = w + dw;
    bool rowok = (TAPS == 1) || ((hh >= 0) && (hh < HH) && (ww >= 0) && (ww < WWC));
    int xoff = (TAPS == 1) ? p : hh * WWC + ww;
    const u16* Wrow = Wp + (size_t)t * O * Cin;
    for (int kb = 0; kb < Cin; kb += 64) {
      __syncthreads();
      *(u16x8*)&Ws[wol][wkk] =
          *(const u16x8*)&Wrow[(size_t)(o0 + wol) * Cin + kb + wkk];
      {
        u16x8 xv;
        if (XMODE == 2) {
          if (rowok) {
            xv = *(const u16x8*)&((const u16*)X)[(size_t)xoff * Cin + kb + xkk];
          } else {
            #pragma unroll
            for (int j = 0; j < 8; ++j) xv[j] = 0;
          }
        } else if (XMODE == 3) {
          #pragma unroll
          for (int j = 0; j < 8; ++j)
            xv[j] = rowok ? ((const u16*)X)[(size_t)(kb + xkk + j) * HWP + xoff]
                          : (u16)0;
        } else {   // XMODE 0: fp32 [Cin][HW]
          #pragma unroll
          for (int j = 0; j < 8; ++j) {
            float v = rowok ? ((const float*)X)[(size_t)(kb + xkk + j) * HWP + xoff]
                            : 0.f;
            xv[j] = f2b(v);
          }
        }
        *(u16x8*)&Xs[pl][xkk] = xv;
      }
      __syncthreads();
      #pragma unroll
      for (int ks = 0; ks < 2; ++ks) {
        s16x8 aw = *(const s16x8*)&Ws[oq + frow][ks * 32 + kgrp];
        s16x8 ax = *(const s16x8*)&Xs[pq + frow][ks * 32 + kgrp];
        acc = mfma16(aw, ax, acc);
      }
    }
  }
  // D mapping (verified): col = lane&15 -> p, row = (lane>>4)*4+r -> o
  int orow = (lane >> 4) * 4;
  int ogb = o0 + oq + orow;
  int pg = p0 + pq + frow;
  if (OMODE == 4) {
    float* Yp = (float*)Y + (size_t)sz * O * HWP;
    #pragma unroll
    for (int r = 0; r < 4; ++r)
      Yp[(size_t)(ogb + r) * HWP + pg] = acc[r];
  } else if (OMODE == 5) {
    if (ogb < 256) {
      u16x4 st;
      #pragma unroll
      for (int r = 0; r < 4; ++r) st[r] = f2b(acc[r] + bias[ogb + r]);
      *(u16x4*)&((u16*)Y)[(size_t)pg * 256 + ogb] = st;
    } else {
      u16* V = (u16*)Y + (size_t)CC * HWP;
      #pragma unroll
      for (int r = 0; r < 4; ++r)
        V[(size_t)(ogb + r - 256) * HWP + pg] = f2b(acc[r] + bias[ogb + r]);
    }
  } else if (OMODE == 2) {
    u16x4 st;
    #pragma unroll
    for (int r = 0; r < 4; ++r) {
      float yv = acc[r] + bias[ogb + r];
      if (ACT == 1) yv = (yv >= 0.f) ? yv : 0.2f * yv;
      if (ADDIN) yv += b2f(addin[(size_t)(ogb + r) * HWP + pg]);
      st[r] = f2b(yv);
    }
    *(u16x4*)&((u16*)Y)[(size_t)pg * O + ogb] = st;
  } else {   // OMODE 3: bf16 [o][p]
    #pragma unroll
    for (int r = 0; r < 4; ++r) {
      float yv = acc[r] + bias[ogb + r];
      if (ACT == 1) yv = (yv >= 0.f) ? yv : 0.2f * yv;
      ((u16*)Y)[(size_t)(ogb + r) * HWP + pg] = f2b(yv);
    }
  }
}

// ---------- standalone mgemm kernel ----------
template<int TAPS, int ACT, bool ADDIN, int OMODE, int XMODE>
__global__ __launch_bounds__(256)
void mgemm32_k(const u16* __restrict__ Wp, const void* __restrict__ X,
               const float* __restrict__ bias, const u16* __restrict__ addin,
               void* __restrict__ Y, int Cin) {
  __shared__ u16 Ws[32][72];
  __shared__ u16 Xs[32][72];
  int NO = gridDim.y;
  int bid = blockIdx.x + blockIdx.y * gridDim.x;
  mgemm_body<TAPS, ACT, ADDIN, OMODE, XMODE>(bid, blockIdx.z, gridDim.z, NO,
                                             NO * 32, Wp, X, bias, addin, Y,
                                             Cin, Ws, Xs);
}

// ---------- stage1: dwconv (0..391) + merged kv proj (392..1959) ----------
__global__ __launch_bounds__(256)
void stage1_k(const float* __restrict__ dec, const float* __restrict__ dw_w,
              const float* __restrict__ dw_b, u16* __restrict__ A,
              const u16* __restrict__ wp_kv, const float* __restrict__ enc,
              const float* __restrict__ kv_b, u16* __restrict__ k16) {
  __shared__ u16 Ws[32][72];
  __shared__ u16 Xs[32][72];
  int b = blockIdx.x;
  if (b < 392) {
    dwconv_body(b * 256 + threadIdx.x, dec, dw_w, dw_b, A);
  } else {
    mgemm_body<1, 0, false, 5, 0>(b - 392, 0, 1, 16, 512, wp_kv, enc, kv_b,
                                  nullptr, k16, 256, Ws, Xs);
  }
}

// ---------- stageA: p1 gemm (0..391) + c1 tap-partials (392..1567) ----------
__global__ __launch_bounds__(256)
void stageA_k(const u16* __restrict__ wp_p1, const u16* __restrict__ A,
              const float* __restrict__ p1_b, u16* __restrict__ hid,
              const u16* __restrict__ wp_c1, const float* __restrict__ enc,
              float* __restrict__ Pc1) {
  __shared__ u16 Ws[32][72];
  __shared__ u16 Xs[32][72];
  int b = blockIdx.x;
  if (b < 392) {
    mgemm_body<1, 1, false, 3, 3>(b, 0, 1, 4, 128, wp_p1, A, p1_b, nullptr,
                                  hid, 256, Ws, Xs);
  } else {
    int rem = b - 392;
    int sz = rem / 392, bb = rem - sz * 392;
    mgemm_body<9, 1, false, 4, 0>(bb, sz, 3, 4, 128, wp_c1, enc, nullptr,
                                  nullptr, Pc1, 256, Ws, Xs);
  }
}

// ---------- stageB: pw9-ALPF (0..97) + c1 combine -> hid2 (98..489) ----------
__global__ __launch_bounds__(256)
void stageB_k(const float* __restrict__ p2_w, const float* __restrict__ p2_b,
              const u16* __restrict__ hid, u16* __restrict__ s9,
              const float* __restrict__ Pc1, const float* __restrict__ c1_b,
              u16* __restrict__ hid2) {
  int b = blockIdx.x;
  if (b < 98) {
    pw9_body<false>(b, p2_w, p2_b, hid, s9);
  } else {
    int flat = ((b - 98) * 256 + threadIdx.x) * 4;
    int o = flat / HWP;
    f32x4 a = *(const f32x4*)&Pc1[flat];
    f32x4 c = *(const f32x4*)&Pc1[flat + 128 * HWP];
    f32x4 d = *(const f32x4*)&Pc1[flat + 2 * 128 * HWP];
    float bv = c1_b[o];
    u16x4 st;
    #pragma unroll
    for (int j = 0; j < 4; ++j) {
      float v = a[j] + c[j] + d[j] + bv;
      v = (v >= 0.f) ? v : 0.2f * v;
      st[j] = f2b(v);
    }
    *(u16x4*)&hid2[flat] = st;
  }
}

// ---------- stageC: spatial-ALPF (0..391) + pw9-AHPF -> s9b (392..489) ----------
__global__ __launch_bounds__(256)
void stageC_k(const float* __restrict__ dec, const u16* __restrict__ s9,
              u16* __restrict__ Bb, const float* __restrict__ c2_w,
              const float* __restrict__ c2_b, const u16* __restrict__ hid2,
              u16* __restrict__ s9b) {
  int b = blockIdx.x;
  if (b < 392) {
    spatial_body<false>(b * 256 + threadIdx.x, dec, s9, Bb);
  } else {
    pw9_body<true>(b - 392, c2_w, c2_b, hid2, s9b);
  }
}

// ---------- attn body (one 64-q tile, head h, split sz) ----------
__device__ __forceinline__ void attn_body(int qx, int h, int sz,
                                          const u16* Qb, const u16* Kb,
                                          const u16* Vb, u16* Op, float* Lb,
                                          u16 (*Ks)[40], u16 (*Vs)[72],
                                          u16 (*Ps)[16][72]) {
  int n0 = qx * 64;
  int tid = threadIdx.x, lane = tid & 63, wv = tid >> 6;
  int frow = lane & 15, gq = lane >> 4, kgrp = gq * 8;
  int ml = tid >> 2, dseg = (tid & 3) * 8;
  int vd = tid >> 3, vm = (tid & 7) * 8;
  const float QS = 0.17677669529663687f * 1.4426950408889634f;  // scale*log2e
  s16x8 aq;
  {
    u16x8 qv = *(const u16x8*)&Qb[(size_t)(n0 + wv * 16 + frow) * 256 + h * 32 + kgrp];
    u16x8 qs;
    #pragma unroll
    for (int j = 0; j < 8; ++j) qs[j] = f2b(b2f(qv[j]) * QS);
    aq = *(s16x8*)&qs;
  }
  f32x4 oa0 = {0.f, 0.f, 0.f, 0.f}, oa1 = {0.f, 0.f, 0.f, 0.f};
  float lsum = 0.f;
  int t_begin = (49 * sz) / NSPLIT, t_end = (49 * (sz + 1)) / NSPLIT;
  u16x8 kreg = *(const u16x8*)&Kb[(size_t)(t_begin * 64 + ml) * 256 + h * 32 + dseg];
  u16x8 vreg = *(const u16x8*)&Vb[(size_t)(h * 32 + vd) * HWP + t_begin * 64 + vm];
  for (int t = t_begin; t < t_end; ++t) {
    __syncthreads();
    *(u16x8*)&Ks[ml][dseg] = kreg;
    *(u16x8*)&Vs[vd][vm] = vreg;
    if (t + 1 < t_end) {
      kreg = *(const u16x8*)&Kb[(size_t)((t + 1) * 64 + ml) * 256 + h * 32 + dseg];
      vreg = *(const u16x8*)&Vb[(size_t)(h * 32 + vd) * HWP + (t + 1) * 64 + vm];
    }
    __syncthreads();
    f32x4 zero = {0.f, 0.f, 0.f, 0.f};
    #pragma unroll
    for (int fm = 0; fm < 4; ++fm) {
      s16x8 ak = *(const s16x8*)&Ks[fm * 16 + frow][kgrp];
      f32x4 s = mfma16(ak, aq, zero);       // D[m][q]: rows=m, col=q=frow
      u16x4 pe;
      #pragma unroll
      for (int r = 0; r < 4; ++r) {
        float e = exp2f(fminf(s[r], 43.f));
        lsum += e;
        pe[r] = (u16)(__float_as_uint(e) >> 16);  // trunc-to-bf16 (P in (0,1])
      }
      *(u16x4*)&Ps[wv][frow][fm * 16 + gq * 4] = pe;
    }
    #pragma unroll
    for (int ks = 0; ks < 2; ++ks) {
      s16x8 ap = *(const s16x8*)&Ps[wv][frow][ks * 32 + kgrp];
      s16x8 bv0 = *(const s16x8*)&Vs[frow][ks * 32 + kgrp];
      s16x8 bv1 = *(const s16x8*)&Vs[16 + frow][ks * 32 + kgrp];
      oa0 = mfma16(ap, bv0, oa0);
      oa1 = mfma16(ap, bv1, oa1);
    }
  }
  lsum += __shfl_xor(lsum, 16);
  lsum += __shfl_xor(lsum, 32);
  if (lane < 16)
    Lb[(size_t)(sz * 8 + h) * HWP + n0 + wv * 16 + frow] = lsum;
  #pragma unroll
  for (int r = 0; r < 4; ++r) {
    int n = n0 + wv * 16 + gq * 4 + r;
    Op[(size_t)(sz * 256 + h * 32 + frow) * HWP + n]      = f2b(oa0[r]);
    Op[(size_t)(sz * 256 + h * 32 + 16 + frow) * HWP + n] = f2b(oa1[r]);
  }
}

// ---------- attn (0..2351 flat) + spatial-AHPF -> Bb2 (2352..2743) ----------
__global__ __launch_bounds__(256)
void attnsp_k(const u16* __restrict__ Qb, const u16* __restrict__ Kb,
              const u16* __restrict__ Vb, u16* __restrict__ Op,
              float* __restrict__ Lb, const float* __restrict__ enc,
              const u16* __restrict__ s9b, u16* __restrict__ Bb2) {
  __shared__ u16 Ks[64][40];
  __shared__ u16 Vs[32][72];
  __shared__ u16 Ps[4][16][72];
  int b = blockIdx.x;
  if (b < 2352) {
    int qx = b % 49, h = (b / 49) % 8, sz = b / 392;
    attn_body(qx, h, sz, Qb, Kb, Vb, Op, Lb, Ks, Vs, Ps);
  } else {
    spatial_body<true>((b - 2352) * 256 + threadIdx.x, enc, s9b, Bb2);
  }
}

// ---------- vectorized combine of NSPLIT attention partials -> bf16 ----------
__global__ __launch_bounds__(256)
void attn_combine_k(const u16* __restrict__ Op, const float* __restrict__ Lb,
                    u16* __restrict__ A) {
  int gid = blockIdx.x * 256 + threadIdx.x;   // 100352
  int hd = gid / 392, g = gid - hd * 392;
  int n0 = g * 8, h = hd >> 5;
  float L[8] = {0,0,0,0,0,0,0,0}, O[8] = {0,0,0,0,0,0,0,0};
  #pragma unroll
  for (int s = 0; s < NSPLIT; ++s) {
    const float* Lp = &Lb[(size_t)(s * 8 + h) * HWP + n0];
    f32x4 l0 = *(const f32x4*)Lp;
    f32x4 l1 = *(const f32x4*)(Lp + 4);
    u16x8 ov = *(const u16x8*)&Op[(size_t)(s * 256 + hd) * HWP + n0];
    #pragma unroll
    for (int j = 0; j < 4; ++j) { L[j] += l0[j]; L[4 + j] += l1[j]; }
    #pragma unroll
    for (int j = 0; j < 8; ++j) O[j] += b2f(ov[j]);
  }
  u16x8 st;
  #pragma unroll
  for (int j = 0; j < 8; ++j) st[j] = f2b(O[j] / L[j]);
  *(u16x8*)&A[(size_t)hd * HWP + n0] = st;
}

// ---------- combine 3 fu partials + bias -> fp32 d_out, x4 ----------
__global__ __launch_bounds__(256)
void comb3f_k(const float* __restrict__ P, const float* __restrict__ bias,
              float* __restrict__ Y) {
  int flat = (blockIdx.x * 256 + threadIdx.x) * 4;   // 256*HWP total
  int o = flat / HWP;
  f32x4 a = *(const f32x4*)&P[flat];
  f32x4 c = *(const f32x4*)&P[flat + 256 * HWP];
  f32x4 d = *(const f32x4*)&P[flat + 2 * 256 * HWP];
  float bv = bias[o];
  f32x4 st;
  #pragma unroll
  for (int j = 0; j < 4; ++j) st[j] = a[j] + c[j] + d[j] + bv;
  *(f32x4*)&Y[flat] = st;
}

extern "C" void kernel_launch(void* const* d_in, const int* in_sizes, int n_in,
                              void* d_out, int out_size, void* d_ws, size_t ws_size,
                              hipStream_t stream) {
  const float* dec   = (const float*)d_in[0];
  const float* enc   = (const float*)d_in[1];
  const float* dw_w  = (const float*)d_in[2];
  const float* dw_b  = (const float*)d_in[3];
  const float* p1_w  = (const float*)d_in[4];
  const float* p1_b  = (const float*)d_in[5];
  const float* p2_w  = (const float*)d_in[6];
  const float* p2_b  = (const float*)d_in[7];
  const float* c1_w  = (const float*)d_in[8];
  const float* c1_b  = (const float*)d_in[9];
  const float* c2_w  = (const float*)d_in[10];
  const float* c2_b  = (const float*)d_in[11];
  const float* q_w   = (const float*)d_in[12];
  const float* q_b   = (const float*)d_in[13];
  const float* kv_w  = (const float*)d_in[14];
  const float* kv_b  = (const float*)d_in[15];
  const float* out_w = (const float*)d_in[16];
  const float* out_b = (const float*)d_in[17];
  const float* fu_w  = (const float*)d_in[18];
  const float* fu_b  = (const float*)d_in[19];

  const int CH = CC * HWP;     // 802816
  u16* pk     = (u16*)d_ws;
  u16* A      = pk;              pk += CH;            // dwconv out / attn out
  u16* hid    = pk;              pk += 128 * HWP;     // ALPF hidden
  u16* hid2   = pk;              pk += 128 * HWP;     // AHPF hidden
  u16* s9     = pk;              pk += 9 * HWP;       // ALPF kw
  u16* s9b    = pk;              pk += 9 * HWP;       // AHPF whp
  u16* Bb     = pk;              pk += CH;            // f_smooth
  u16* Bb2    = pk;              pk += CH;            // f_high
  u16* qb16   = pk;              pk += CH;            // q; later fused_in
  u16* k16    = pk;              pk += CH;            // K [m][256]
  u16* v16    = pk;              pk += CH;            // V [d][HWP]
  u16* wp_p1  = pk;              pk += 128 * 256;
  u16* wp_q   = pk;              pk += 256 * 256;
  u16* wp_kv  = pk;              pk += 512 * 256;
  u16* wp_out = pk;              pk += 256 * 256;
  u16* wp_c1  = pk;              pk += 128 * 256 * 9;
  u16* wp_fu  = pk;              pk += 256 * 256 * 9;
  pk += (size_t)(-(intptr_t)pk) & 7;                  // 16B align
  float* Lb   = (float*)pk;                           // 48*HWP f32
  u16* Opart  = (u16*)(Lb + 48 * HWP);                // 1536*HWP u16
  float* Pc1 = Lb;   // c1 partials (4.8MB, consumed by stageB before attn)
  float* Pfu = Lb;   // fu partials (9.63MB, attn region dead by then)

  dim3 blk(256);

  // ---- pack ALL weights fp32 -> bf16 ----
  pack_all_k<<<1536, blk, 0, stream>>>(p1_w, q_w, kv_w, out_w, c1_w, fu_w,
                                       wp_p1, wp_q, wp_kv, wp_out, wp_c1, wp_fu);

  // ---- stage1: dwconv + merged kv proj ----
  stage1_k<<<1960, blk, 0, stream>>>(dec, dw_w, dw_b, A, wp_kv, enc, kv_b, k16);

  // ---- stageA: p1 gemm + c1 tap-partials ----
  stageA_k<<<1568, blk, 0, stream>>>(wp_p1, A, p1_b, hid, wp_c1, enc, Pc1);

  // ---- stageB: pw9-ALPF + c1 combine -> hid2 ----
  stageB_k<<<490, blk, 0, stream>>>(p2_w, p2_b, hid, s9, Pc1, c1_b, hid2);

  // ---- stageC: spatial-ALPF -> Bb + pw9-AHPF -> s9b ----
  stageC_k<<<490, blk, 0, stream>>>(dec, s9, Bb, c2_w, c2_b, hid2, s9b);

  // ---- q proj -> qb16 (X = Bb bf16 [Cin][HW] -> XMODE 3) ----
  mgemm32_k<1, 0, false, 2, 3><<<dim3(98, 8), blk, 0, stream>>>(
      wp_q, Bb, q_b, nullptr, qb16, 256);

  // ---- attention (6-way split) + spatial-AHPF overlapped ----
  attnsp_k<<<2744, blk, 0, stream>>>(qb16, k16, v16, Opart, Lb, enc, s9b, Bb2);
  attn_combine_k<<<392, blk, 0, stream>>>(Opart, Lb, A);

  // ---- out proj + f_high add -> bf16 [p][256] ----
  mgemm32_k<1, 0, true, 2, 3><<<dim3(98, 8), blk, 0, stream>>>(
      wp_out, A, out_b, Bb2, qb16, 256);

  // ---- fusion conv: 3-way tap-split + combine -> fp32 d_out ----
  mgemm32_k<9, 0, false, 4, 2><<<dim3(98, 8, 3), blk, 0, stream>>>(
      wp_fu, qb16, nullptr, nullptr, Pfu, 256);
  comb3f_k<<<784, blk, 0, stream>>>(Pfu, fu_b, (float*)d_out);
}

// Round 23
// 118.954 us; speedup vs baseline: 2.0437x; 1.0201x over previous
//
#include <hip/hip_runtime.h>
#include <hip/hip_bf16.h>

#define HH  56
#define WWC 56
#define HWP 3136   // 56*56 = 49*64
#define CC  256
#define NSPLIT 6

typedef unsigned short u16;
typedef __attribute__((ext_vector_type(8))) u16 u16x8;
typedef __attribute__((ext_vector_type(4))) u16 u16x4;
typedef __attribute__((ext_vector_type(8))) short s16x8;   // bf16x8 MFMA frag
typedef __attribute__((ext_vector_type(4))) float f32x4;

__device__ __forceinline__ u16 f2b(float f) {
  unsigned int x = __float_as_uint(f);
  return (u16)((x + 0x7fffu + ((x >> 16) & 1u)) >> 16);
}
__device__ __forceinline__ float b2f(u16 u) {
  return __uint_as_float(((unsigned int)u) << 16);
}
__device__ __forceinline__ f32x4 mfma16(s16x8 a, s16x8 b, f32x4 c) {
  return __builtin_amdgcn_mfma_f32_16x16x32_bf16(a, b, c, 0, 0, 0);
}
// fp32 8-wide load (aligned)
__device__ __forceinline__ void ldrow8f(const float* p, size_t i, float* o) {
  f32x4 a = *(const f32x4*)(p + i);
  f32x4 b = *(const f32x4*)(p + i + 4);
  #pragma unroll
  for (int j = 0; j < 4; ++j) { o[j] = a[j]; o[4 + j] = b[j]; }
}

// ---------- pack 3x3 weights fp32 (O,Ci,3,3) -> bf16 [t][O][Cin] ----------
__device__ __forceinline__ void pack9_body(int b, const float* c1,
                                           const float* fu, u16* d_c1,
                                           u16* d_fu) {
  int tid = threadIdx.x;
  if (b < 128) {
    int g = b * 256 + tid;
    #pragma unroll
    for (int t = 0; t < 9; ++t)
      d_c1[(size_t)t * 32768 + g] = f2b(c1[g * 9 + t]);
  } else {
    int g = (b - 128) * 256 + tid;
    #pragma unroll
    for (int t = 0; t < 9; ++t)
      d_fu[(size_t)t * 65536 + g] = f2b(fu[g * 9 + t]);
  }
}

// ---------- dwconv body: fp32 in, bf16 out, 8 pixels/thread ----------
__device__ __forceinline__ void dwconv_body(int gid, const float* x,
                                            const float* wt, const float* bs,
                                            u16* y) {
  int c = gid / 392, g = gid - c * 392;
  int p0 = g * 8;
  int h = p0 / WWC, w0 = p0 - h * WWC;
  float wv[9];
  #pragma unroll
  for (int t = 0; t < 9; ++t) wv[t] = wt[c * 9 + t];
  float bv = bs[c];
  float acc[8];
  #pragma unroll
  for (int j = 0; j < 8; ++j) acc[j] = bv;
  const size_t cbase = (size_t)c * HWP;
  #pragma unroll
  for (int dh = -1; dh <= 1; ++dh) {
    int hh = h + dh;
    if (hh < 0 || hh >= HH) continue;
    size_t rbase = cbase + hh * WWC + w0;
    float v[8];
    ldrow8f(x, rbase, v);
    float lft = (w0 > 0) ? x[rbase - 1] : 0.f;
    float rgt = (w0 < 48) ? x[rbase + 8] : 0.f;
    float wm = wv[(dh + 1) * 3 + 0], wc = wv[(dh + 1) * 3 + 1],
          wp = wv[(dh + 1) * 3 + 2];
    #pragma unroll
    for (int j = 0; j < 8; ++j) {
      float vm = (j == 0) ? lft : v[j - 1];
      float vp = (j == 7) ? rgt : v[j + 1];
      acc[j] += vm * wm + v[j] * wc + vp * wp;
    }
  }
  u16x8 st;
  #pragma unroll
  for (int j = 0; j < 8; ++j) st[j] = f2b(acc[j]);
  *(u16x8*)&y[cbase + p0] = st;
}

// ---------- spatial filter body: fp32 x, bf16 w9, bf16 out ----------
template<bool HIGH>
__device__ __forceinline__ void spatial_body(int gid, const float* x,
                                             const u16* w9, u16* y) {
  int c = gid / 392, g = gid - c * 392;
  int p0 = g * 8;
  int h = p0 / WWC, w0 = p0 - h * WWC;
  const size_t cbase = (size_t)c * HWP;
  float acc[8];
  if (HIGH) {
    ldrow8f(x, cbase + p0, acc);
  } else {
    #pragma unroll
    for (int j = 0; j < 8; ++j) acc[j] = 0.f;
  }
  #pragma unroll
  for (int dh = -1; dh <= 1; ++dh) {
    int hh = h + dh;
    if (hh < 0 || hh >= HH) continue;
    size_t rbase = cbase + hh * WWC + w0;
    float v[8];
    ldrow8f(x, rbase, v);
    float lft = (w0 > 0) ? x[rbase - 1] : 0.f;
    float rgt = (w0 < 48) ? x[rbase + 8] : 0.f;
    float wm[8], wc[8], wp[8];
    {
      int tb = (dh + 1) * 3;
      u16x8 a = *(const u16x8*)&w9[(size_t)(tb + 0) * HWP + p0];
      u16x8 b = *(const u16x8*)&w9[(size_t)(tb + 1) * HWP + p0];
      u16x8 d = *(const u16x8*)&w9[(size_t)(tb + 2) * HWP + p0];
      #pragma unroll
      for (int j = 0; j < 8; ++j) { wm[j] = b2f(a[j]); wc[j] = b2f(b[j]); wp[j] = b2f(d[j]); }
    }
    #pragma unroll
    for (int j = 0; j < 8; ++j) {
      float vm = (j == 0) ? lft : v[j - 1];
      float vp = (j == 7) ? rgt : v[j + 1];
      acc[j] += vm * wm[j] + v[j] * wc[j] + vp * wp[j];
    }
  }
  u16x8 st;
  #pragma unroll
  for (int j = 0; j < 8; ++j) st[j] = f2b(acc[j]);
  *(u16x8*)&y[cbase + p0] = st;
}

// ---------- pw9 body (block pblk of 98): fp32 w2/b2, bf16 hid, bf16 out ----------
template<bool DELTA>
__device__ __forceinline__ void pw9_body(int pblk, const float* w2,
                                         const float* b2, const u16* hid,
                                         u16* out9) {
  __shared__ float Wl[9][128];
  __shared__ float Pl[4][9][33];
  int tid = threadIdx.x;
  for (int i = tid; i < 1152; i += 256) Wl[i >> 7][i & 127] = w2[i];
  __syncthreads();
  int pix = tid & 31, cig = tid >> 5;
  int p = pblk * 32 + pix;
  int ci0 = cig * 16;
  float acc[9] = {0.f, 0.f, 0.f, 0.f, 0.f, 0.f, 0.f, 0.f, 0.f};
  #pragma unroll
  for (int j = 0; j < 16; ++j) {
    float xv = b2f(hid[(size_t)(ci0 + j) * HWP + p]);
    #pragma unroll
    for (int t = 0; t < 9; ++t) acc[t] += Wl[t][ci0 + j] * xv;
  }
  #pragma unroll
  for (int t = 0; t < 9; ++t) acc[t] += __shfl_xor(acc[t], 32);
  int wv = tid >> 6;
  if ((tid & 63) < 32) {
    #pragma unroll
    for (int t = 0; t < 9; ++t) Pl[wv][t][pix] = acc[t];
  }
  __syncthreads();
  if (tid < 32) {
    float a[9];
    #pragma unroll
    for (int t = 0; t < 9; ++t)
      a[t] = Pl[0][t][pix] + Pl[1][t][pix] + Pl[2][t][pix] + Pl[3][t][pix] +
             b2[t];
    float mx = a[0];
    #pragma unroll
    for (int t = 1; t < 9; ++t) mx = fmaxf(mx, a[t]);
    float s = 0.f;
    #pragma unroll
    for (int t = 0; t < 9; ++t) { a[t] = __expf(a[t] - mx); s += a[t]; }
    float inv = 1.f / s;
    #pragma unroll
    for (int t = 0; t < 9; ++t) {
      float v = a[t] * inv;
      if (DELTA) v = ((t == 4) ? 1.f : 0.f) - v;
      out9[(size_t)t * HWP + p] = f2b(v);
    }
  }
}

// ---------- MFMA GEMM body, 32x32 tile ----------
// WMODE 0: W bf16 [t][O][Cin] packed; 1: W fp32 [O][Cin] (converted in staging).
// OMODE 2 bf16 [p][o](+ACT/ADDIN); 3 bf16 [o][p](+ACT); 4 fp32 partial; 5 dual KV.
// XMODE 0 fp32 X[Cin][HW]; 2 bf16 X[p][Cin]; 3 bf16 X[Cin][HW].
template<int TAPS, int ACT, bool ADDIN, int OMODE, int XMODE, int WMODE>
__device__ __forceinline__ void mgemm_body(
    int bid, int sz, int NZ, int NO, int O,
    const void* __restrict__ W, const void* __restrict__ X,
    const float* __restrict__ bias, const u16* __restrict__ addin,
    void* __restrict__ Y, int Cin, u16 (*Ws)[72], u16 (*Xs)[72]) {
  int p0 = (bid / NO) * 32, o0 = (bid % NO) * 32;
  int t0 = (TAPS * sz) / NZ, t1 = (TAPS * (sz + 1)) / NZ;
  int tid = threadIdx.x, lane = tid & 63, wv = tid >> 6;
  int oq = (wv & 1) * 16, pq = (wv >> 1) * 16;
  int frow = lane & 15, kgrp = (lane >> 4) * 8;
  int wol = tid >> 3, wkk = (tid & 7) * 8;
  int pl = tid & 31, xkk = (tid >> 5) * 8;
  int p = p0 + pl, h = p / WWC, w = p - h * WWC;
  f32x4 acc = {0.f, 0.f, 0.f, 0.f};
  for (int t = t0; t < t1; ++t) {
    int dh = t / 3 - 1, dw = t % 3 - 1;
    int hh = h + dh, ww = w + dw;
    bool rowok = (TAPS == 1) || ((hh >= 0) && (hh < HH) && (ww >= 0) && (ww < WWC));
    int xoff = (TAPS == 1) ? p : hh * WWC + ww;
    for (int kb = 0; kb < Cin; kb += 64) {
      __syncthreads();
      if (WMODE == 0) {
        const u16* Wrow = (const u16*)W + (size_t)t * O * Cin;
        *(u16x8*)&Ws[wol][wkk] =
            *(const u16x8*)&Wrow[(size_t)(o0 + wol) * Cin + kb + wkk];
      } else {
        const float* Wrow = (const float*)W + (size_t)t * O * Cin;
        size_t base = (size_t)(o0 + wol) * Cin + kb + wkk;
        f32x4 wa = *(const f32x4*)&Wrow[base];
        f32x4 wb = *(const f32x4*)&Wrow[base + 4];
        u16x8 wv8;
        #pragma unroll
        for (int j = 0; j < 4; ++j) { wv8[j] = f2b(wa[j]); wv8[4 + j] = f2b(wb[j]); }
        *(u16x8*)&Ws[wol][wkk] = wv8;
      }
      {
        u16x8 xv;
        if (XMODE == 2) {
          if (rowok) {
            xv = *(const u16x8*)&((const u16*)X)[(size_t)xoff * Cin + kb + xkk];
          } else {
            #pragma unroll
            for (int j = 0; j < 8; ++j) xv[j] = 0;
          }
        } else if (XMODE == 3) {
          #pragma unroll
          for (int j = 0; j < 8; ++j)
            xv[j] = rowok ? ((const u16*)X)[(size_t)(kb + xkk + j) * HWP + xoff]
                          : (u16)0;
        } else {   // XMODE 0: fp32 [Cin][HW]
          #pragma unroll
          for (int j = 0; j < 8; ++j) {
            float v = rowok ? ((const float*)X)[(size_t)(kb + xkk + j) * HWP + xoff]
                            : 0.f;
            xv[j] = f2b(v);
          }
        }
        *(u16x8*)&Xs[pl][xkk] = xv;
      }
      __syncthreads();
      #pragma unroll
      for (int ks = 0; ks < 2; ++ks) {
        s16x8 aw = *(const s16x8*)&Ws[oq + frow][ks * 32 + kgrp];
        s16x8 ax = *(const s16x8*)&Xs[pq + frow][ks * 32 + kgrp];
        acc = mfma16(aw, ax, acc);
      }
    }
  }
  // D mapping (verified): col = lane&15 -> p, row = (lane>>4)*4+r -> o
  int orow = (lane >> 4) * 4;
  int ogb = o0 + oq + orow;
  int pg = p0 + pq + frow;
  if (OMODE == 4) {
    float* Yp = (float*)Y + (size_t)sz * O * HWP;
    #pragma unroll
    for (int r = 0; r < 4; ++r)
      Yp[(size_t)(ogb + r) * HWP + pg] = acc[r];
  } else if (OMODE == 5) {
    if (ogb < 256) {
      u16x4 st;
      #pragma unroll
      for (int r = 0; r < 4; ++r) st[r] = f2b(acc[r] + bias[ogb + r]);
      *(u16x4*)&((u16*)Y)[(size_t)pg * 256 + ogb] = st;
    } else {
      u16* V = (u16*)Y + (size_t)CC * HWP;
      #pragma unroll
      for (int r = 0; r < 4; ++r)
        V[(size_t)(ogb + r - 256) * HWP + pg] = f2b(acc[r] + bias[ogb + r]);
    }
  } else if (OMODE == 2) {
    u16x4 st;
    #pragma unroll
    for (int r = 0; r < 4; ++r) {
      float yv = acc[r] + bias[ogb + r];
      if (ACT == 1) yv = (yv >= 0.f) ? yv : 0.2f * yv;
      if (ADDIN) yv += b2f(addin[(size_t)(ogb + r) * HWP + pg]);
      st[r] = f2b(yv);
    }
    *(u16x4*)&((u16*)Y)[(size_t)pg * O + ogb] = st;
  } else {   // OMODE 3: bf16 [o][p]
    #pragma unroll
    for (int r = 0; r < 4; ++r) {
      float yv = acc[r] + bias[ogb + r];
      if (ACT == 1) yv = (yv >= 0.f) ? yv : 0.2f * yv;
      ((u16*)Y)[(size_t)(ogb + r) * HWP + pg] = f2b(yv);
    }
  }
}

// ---------- standalone mgemm kernel ----------
template<int TAPS, int ACT, bool ADDIN, int OMODE, int XMODE, int WMODE>
__global__ __launch_bounds__(256)
void mgemm32_k(const void* __restrict__ W, const void* __restrict__ X,
               const float* __restrict__ bias, const u16* __restrict__ addin,
               void* __restrict__ Y, int Cin) {
  __shared__ u16 Ws[32][72];
  __shared__ u16 Xs[32][72];
  int NO = gridDim.y;
  int bid = blockIdx.x + blockIdx.y * gridDim.x;
  mgemm_body<TAPS, ACT, ADDIN, OMODE, XMODE, WMODE>(
      bid, blockIdx.z, gridDim.z, NO, NO * 32, W, X, bias, addin, Y, Cin,
      Ws, Xs);
}

// ---------- stage1: pack9 (0..383) + dwconv (384..775) + kv proj (776..2343) ----------
__global__ __launch_bounds__(256)
void stage1_k(const float* __restrict__ c1_w, const float* __restrict__ fu_w,
              u16* __restrict__ wp_c1, u16* __restrict__ wp_fu,
              const float* __restrict__ dec, const float* __restrict__ dw_w,
              const float* __restrict__ dw_b, u16* __restrict__ A,
              const float* __restrict__ kv_w, const float* __restrict__ enc,
              const float* __restrict__ kv_b, u16* __restrict__ k16) {
  __shared__ u16 Ws[32][72];
  __shared__ u16 Xs[32][72];
  int b = blockIdx.x;
  if (b < 384) {
    pack9_body(b, c1_w, fu_w, wp_c1, wp_fu);
  } else if (b < 776) {
    dwconv_body((b - 384) * 256 + threadIdx.x, dec, dw_w, dw_b, A);
  } else {
    mgemm_body<1, 0, false, 5, 0, 1>(b - 776, 0, 1, 16, 512, kv_w, enc, kv_b,
                                     nullptr, k16, 256, Ws, Xs);
  }
}

// ---------- stageA: p1 gemm (0..391) + c1 tap-partials (392..1567) ----------
__global__ __launch_bounds__(256)
void stageA_k(const float* __restrict__ p1_w, const u16* __restrict__ A,
              const float* __restrict__ p1_b, u16* __restrict__ hid,
              const u16* __restrict__ wp_c1, const float* __restrict__ enc,
              float* __restrict__ Pc1) {
  __shared__ u16 Ws[32][72];
  __shared__ u16 Xs[32][72];
  int b = blockIdx.x;
  if (b < 392) {
    mgemm_body<1, 1, false, 3, 3, 1>(b, 0, 1, 4, 128, p1_w, A, p1_b, nullptr,
                                     hid, 256, Ws, Xs);
  } else {
    int rem = b - 392;
    int sz = rem / 392, bb = rem - sz * 392;
    mgemm_body<9, 1, false, 4, 0, 0>(bb, sz, 3, 4, 128, wp_c1, enc, nullptr,
                                     nullptr, Pc1, 256, Ws, Xs);
  }
}

// ---------- stageB: pw9-ALPF (0..97) + c1 combine -> hid2 (98..489) ----------
__global__ __launch_bounds__(256)
void stageB_k(const float* __restrict__ p2_w, const float* __restrict__ p2_b,
              const u16* __restrict__ hid, u16* __restrict__ s9,
              const float* __restrict__ Pc1, const float* __restrict__ c1_b,
              u16* __restrict__ hid2) {
  int b = blockIdx.x;
  if (b < 98) {
    pw9_body<false>(b, p2_w, p2_b, hid, s9);
  } else {
    int flat = ((b - 98) * 256 + threadIdx.x) * 4;
    int o = flat / HWP;
    f32x4 a = *(const f32x4*)&Pc1[flat];
    f32x4 c = *(const f32x4*)&Pc1[flat + 128 * HWP];
    f32x4 d = *(const f32x4*)&Pc1[flat + 2 * 128 * HWP];
    float bv = c1_b[o];
    u16x4 st;
    #pragma unroll
    for (int j = 0; j < 4; ++j) {
      float v = a[j] + c[j] + d[j] + bv;
      v = (v >= 0.f) ? v : 0.2f * v;
      st[j] = f2b(v);
    }
    *(u16x4*)&hid2[flat] = st;
  }
}

// ---------- stageC: spatial-ALPF (0..391) + pw9-AHPF -> s9b (392..489) ----------
__global__ __launch_bounds__(256)
void stageC_k(const float* __restrict__ dec, const u16* __restrict__ s9,
              u16* __restrict__ Bb, const float* __restrict__ c2_w,
              const float* __restrict__ c2_b, const u16* __restrict__ hid2,
              u16* __restrict__ s9b) {
  int b = blockIdx.x;
  if (b < 392) {
    spatial_body<false>(b * 256 + threadIdx.x, dec, s9, Bb);
  } else {
    pw9_body<true>(b - 392, c2_w, c2_b, hid2, s9b);
  }
}

// ---------- attn body (one 64-q tile, head h, split sz) ----------
__device__ __forceinline__ void attn_body(int qx, int h, int sz,
                                          const u16* Qb, const u16* Kb,
                                          const u16* Vb, u16* Op, float* Lb,
                                          u16 (*Ks)[40], u16 (*Vs)[72],
                                          u16 (*Ps)[16][72]) {
  int n0 = qx * 64;
  int tid = threadIdx.x, lane = tid & 63, wv = tid >> 6;
  int frow = lane & 15, gq = lane >> 4, kgrp = gq * 8;
  int ml = tid >> 2, dseg = (tid & 3) * 8;
  int vd = tid >> 3, vm = (tid & 7) * 8;
  const float QS = 0.17677669529663687f * 1.4426950408889634f;  // scale*log2e
  s16x8 aq;
  {
    u16x8 qv = *(const u16x8*)&Qb[(size_t)(n0 + wv * 16 + frow) * 256 + h * 32 + kgrp];
    u16x8 qs;
    #pragma unroll
    for (int j = 0; j < 8; ++j) qs[j] = f2b(b2f(qv[j]) * QS);
    aq = *(s16x8*)&qs;
  }
  f32x4 oa0 = {0.f, 0.f, 0.f, 0.f}, oa1 = {0.f, 0.f, 0.f, 0.f};
  float lsum = 0.f;
  int t_begin = (49 * sz) / NSPLIT, t_end = (49 * (sz + 1)) / NSPLIT;
  u16x8 kreg = *(const u16x8*)&Kb[(size_t)(t_begin * 64 + ml) * 256 + h * 32 + dseg];
  u16x8 vreg = *(const u16x8*)&Vb[(size_t)(h * 32 + vd) * HWP + t_begin * 64 + vm];
  for (int t = t_begin; t < t_end; ++t) {
    __syncthreads();
    *(u16x8*)&Ks[ml][dseg] = kreg;
    *(u16x8*)&Vs[vd][vm] = vreg;
    if (t + 1 < t_end) {
      kreg = *(const u16x8*)&Kb[(size_t)((t + 1) * 64 + ml) * 256 + h * 32 + dseg];
      vreg = *(const u16x8*)&Vb[(size_t)(h * 32 + vd) * HWP + (t + 1) * 64 + vm];
    }
    __syncthreads();
    f32x4 zero = {0.f, 0.f, 0.f, 0.f};
    #pragma unroll
    for (int fm = 0; fm < 4; ++fm) {
      s16x8 ak = *(const s16x8*)&Ks[fm * 16 + frow][kgrp];
      f32x4 s = mfma16(ak, aq, zero);       // D[m][q]: rows=m, col=q=frow
      u16x4 pe;
      #pragma unroll
      for (int r = 0; r < 4; ++r) {
        float e = exp2f(fminf(s[r], 43.f));
        lsum += e;
        pe[r] = (u16)(__float_as_uint(e) >> 16);  // trunc-to-bf16 (P in (0,1])
      }
      *(u16x4*)&Ps[wv][frow][fm * 16 + gq * 4] = pe;
    }
    #pragma unroll
    for (int ks = 0; ks < 2; ++ks) {
      s16x8 ap = *(const s16x8*)&Ps[wv][frow][ks * 32 + kgrp];
      s16x8 bv0 = *(const s16x8*)&Vs[frow][ks * 32 + kgrp];
      s16x8 bv1 = *(const s16x8*)&Vs[16 + frow][ks * 32 + kgrp];
      oa0 = mfma16(ap, bv0, oa0);
      oa1 = mfma16(ap, bv1, oa1);
    }
  }
  lsum += __shfl_xor(lsum, 16);
  lsum += __shfl_xor(lsum, 32);
  if (lane < 16)
    Lb[(size_t)(sz * 8 + h) * HWP + n0 + wv * 16 + frow] = lsum;
  #pragma unroll
  for (int r = 0; r < 4; ++r) {
    int n = n0 + wv * 16 + gq * 4 + r;
    Op[(size_t)(sz * 256 + h * 32 + frow) * HWP + n]      = f2b(oa0[r]);
    Op[(size_t)(sz * 256 + h * 32 + 16 + frow) * HWP + n] = f2b(oa1[r]);
  }
}

// ---------- attn (0..2351 flat) + spatial-AHPF -> Bb2 (2352..2743) ----------
__global__ __launch_bounds__(256)
void attnsp_k(const u16* __restrict__ Qb, const u16* __restrict__ Kb,
              const u16* __restrict__ Vb, u16* __restrict__ Op,
              float* __restrict__ Lb, const float* __restrict__ enc,
              const u16* __restrict__ s9b, u16* __restrict__ Bb2) {
  __shared__ u16 Ks[64][40];
  __shared__ u16 Vs[32][72];
  __shared__ u16 Ps[4][16][72];
  int b = blockIdx.x;
  if (b < 2352) {
    int qx = b % 49, h = (b / 49) % 8, sz = b / 392;
    attn_body(qx, h, sz, Qb, Kb, Vb, Op, Lb, Ks, Vs, Ps);
  } else {
    spatial_body<true>((b - 2352) * 256 + threadIdx.x, enc, s9b, Bb2);
  }
}

// ---------- vectorized combine of NSPLIT attention partials -> bf16 ----------
__global__ __launch_bounds__(256)
void attn_combine_k(const u16* __restrict__ Op, const float* __restrict__ Lb,
                    u16* __restrict__ A) {
  int gid = blockIdx.x * 256 + threadIdx.x;   // 100352
  int hd = gid / 392, g = gid - hd * 392;
  int n0 = g * 8, h = hd >> 5;
  float L[8] = {0,0,0,0,0,0,0,0}, O[8] = {0,0,0,0,0,0,0,0};
  #pragma unroll
  for (int s = 0; s < NSPLIT; ++s) {
    const float* Lp = &Lb[(size_t)(s * 8 + h) * HWP + n0];
    f32x4 l0 = *(const f32x4*)Lp;
    f32x4 l1 = *(const f32x4*)(Lp + 4);
    u16x8 ov = *(const u16x8*)&Op[(size_t)(s * 256 + hd) * HWP + n0];
    #pragma unroll
    for (int j = 0; j < 4; ++j) { L[j] += l0[j]; L[4 + j] += l1[j]; }
    #pragma unroll
    for (int j = 0; j < 8; ++j) O[j] += b2f(ov[j]);
  }
  u16x8 st;
  #pragma unroll
  for (int j = 0; j < 8; ++j) st[j] = f2b(O[j] / L[j]);
  *(u16x8*)&A[(size_t)hd * HWP + n0] = st;
}

// ---------- combine 3 fu partials + bias -> fp32 d_out, x4 ----------
__global__ __launch_bounds__(256)
void comb3f_k(const float* __restrict__ P, const float* __restrict__ bias,
              float* __restrict__ Y) {
  int flat = (blockIdx.x * 256 + threadIdx.x) * 4;   // 256*HWP total
  int o = flat / HWP;
  f32x4 a = *(const f32x4*)&P[flat];
  f32x4 c = *(const f32x4*)&P[flat + 256 * HWP];
  f32x4 d = *(const f32x4*)&P[flat + 2 * 256 * HWP];
  float bv = bias[o];
  f32x4 st;
  #pragma unroll
  for (int j = 0; j < 4; ++j) st[j] = a[j] + c[j] + d[j] + bv;
  *(f32x4*)&Y[flat] = st;
}

extern "C" void kernel_launch(void* const* d_in, const int* in_sizes, int n_in,
                              void* d_out, int out_size, void* d_ws, size_t ws_size,
                              hipStream_t stream) {
  const float* dec   = (const float*)d_in[0];
  const float* enc   = (const float*)d_in[1];
  const float* dw_w  = (const float*)d_in[2];
  const float* dw_b  = (const float*)d_in[3];
  const float* p1_w  = (const float*)d_in[4];
  const float* p1_b  = (const float*)d_in[5];
  const float* p2_w  = (const float*)d_in[6];
  const float* p2_b  = (const float*)d_in[7];
  const float* c1_w  = (const float*)d_in[8];
  const float* c1_b  = (const float*)d_in[9];
  const float* c2_w  = (const float*)d_in[10];
  const float* c2_b  = (const float*)d_in[11];
  const float* q_w   = (const float*)d_in[12];
  const float* q_b   = (const float*)d_in[13];
  const float* kv_w  = (const float*)d_in[14];
  const float* kv_b  = (const float*)d_in[15];
  const float* out_w = (const float*)d_in[16];
  const float* out_b = (const float*)d_in[17];
  const float* fu_w  = (const float*)d_in[18];
  const float* fu_b  = (const float*)d_in[19];

  const int CH = CC * HWP;     // 802816
  u16* pk     = (u16*)d_ws;
  u16* A      = pk;              pk += CH;            // dwconv out / attn out
  u16* hid    = pk;              pk += 128 * HWP;     // ALPF hidden
  u16* hid2   = pk;              pk += 128 * HWP;     // AHPF hidden
  u16* s9     = pk;              pk += 9 * HWP;       // ALPF kw
  u16* s9b    = pk;              pk += 9 * HWP;       // AHPF whp
  u16* Bb     = pk;              pk += CH;            // f_smooth
  u16* Bb2    = pk;              pk += CH;            // f_high
  u16* qb16   = pk;              pk += CH;            // q; later fused_in
  u16* k16    = pk;              pk += CH;            // K [m][256]
  u16* v16    = pk;              pk += CH;            // V [d][HWP]
  u16* wp_c1  = pk;              pk += 128 * 256 * 9;
  u16* wp_fu  = pk;              pk += 256 * 256 * 9;
  pk += (size_t)(-(intptr_t)pk) & 7;                  // 16B align
  float* Lb   = (float*)pk;                           // 48*HWP f32
  u16* Opart  = (u16*)(Lb + 48 * HWP);                // 1536*HWP u16
  float* Pc1 = Lb;   // c1 partials (4.8MB, consumed by stageB before attn)
  float* Pfu = Lb;   // fu partials (9.63MB, attn region dead by then)

  dim3 blk(256);

  // ---- stage1: pack9 + dwconv + kv proj (on-the-fly W conversion) ----
  stage1_k<<<2344, blk, 0, stream>>>(c1_w, fu_w, wp_c1, wp_fu,
                                     dec, dw_w, dw_b, A, kv_w, enc, kv_b, k16);

  // ---- stageA: p1 gemm + c1 tap-partials ----
  stageA_k<<<1568, blk, 0, stream>>>(p1_w, A, p1_b, hid, wp_c1, enc, Pc1);

  // ---- stageB: pw9-ALPF + c1 combine -> hid2 ----
  stageB_k<<<490, blk, 0, stream>>>(p2_w, p2_b, hid, s9, Pc1, c1_b, hid2);

  // ---- stageC: spatial-ALPF -> Bb + pw9-AHPF -> s9b ----
  stageC_k<<<490, blk, 0, stream>>>(dec, s9, Bb, c2_w, c2_b, hid2, s9b);

  // ---- q proj -> qb16 (W fp32 on-the-fly; X = Bb bf16 [Cin][HW]) ----
  mgemm32_k<1, 0, false, 2, 3, 1><<<dim3(98, 8), blk, 0, stream>>>(
      q_w, Bb, q_b, nullptr, qb16, 256);

  // ---- attention (6-way split) + spatial-AHPF overlapped ----
  attnsp_k<<<2744, blk, 0, stream>>>(qb16, k16, v16, Opart, Lb, enc, s9b, Bb2);
  attn_combine_k<<<392, blk, 0, stream>>>(Opart, Lb, A);

  // ---- out proj + f_high add -> bf16 [p][256] ----
  mgemm32_k<1, 0, true, 2, 3, 1><<<dim3(98, 8), blk, 0, stream>>>(
      out_w, A, out_b, Bb2, qb16, 256);

  // ---- fusion conv: 3-way tap-split + combine -> fp32 d_out ----
  mgemm32_k<9, 0, false, 4, 2, 0><<<dim3(98, 8, 3), blk, 0, stream>>>(
      wp_fu, qb16, nullptr, nullptr, Pfu, 256);
  comb3f_k<<<784, blk, 0, stream>>>(Pfu, fu_b, (float*)d_out);
}